// Round 1
// baseline (1697.097 us; speedup 1.0000x reference)
//
#include <hip/hip_runtime.h>
#include <cmath>

typedef _Float16 f16;
typedef __attribute__((ext_vector_type(8))) _Float16 f16x8;
typedef __attribute__((ext_vector_type(4))) _Float16 f16x4;
typedef __attribute__((ext_vector_type(4))) float f32x4;

struct TileInfo { int m0, mcnt, e, pad; };

__device__ __forceinline__ void gload16(const void* g, void* l) {
  __builtin_amdgcn_global_load_lds((const __attribute__((address_space(1))) void*)g,
                                   (__attribute__((address_space(3))) void*)l, 16, 0, 0);
}

// ---------------------------------------------------------------------------
// Unified GEMM:  C[M,N] = A[M,K] * B[K,N] (+bias, +res, +gelu), B given
// transposed (BT[N,K], row-major).  A/B in f16; NPASS==3 adds lo-planes for
// fp32-faithful results (hh+hl+lh).  MODE: 0 direct, 1 rowmap(A rows),
// 2 tile-table (MoE grouped), 3 conv (3-tap shifted A rows, K=3072).
// EPI: 0 f32=acc+bias; 1 f32=res+acc+bias; 2 f16=acc+bias; 3 f16=gelu(acc+bias)
// ---------------------------------------------------------------------------
template<int NPASS, int MODE, int EPI>
__global__ __launch_bounds__(256)
void gemm_kernel(const f16* __restrict__ Ah, const f16* __restrict__ Al, int lda,
                 const f16* __restrict__ Bh, const f16* __restrict__ Bl, int ldb,
                 const float* __restrict__ bias, const float* __restrict__ res,
                 float* __restrict__ outf, f16* __restrict__ outh, int ldo, int K,
                 const int* __restrict__ rowmap, const TileInfo* __restrict__ table) {
  constexpr int BK = (NPASS == 1) ? 64 : 32;
  constexpr int RB = BK * 2;            // bytes per LDS tile row
  constexpr int TB = 128 * RB;          // bytes per tile plane
  constexpr int ROUNDS = TB / 4096;     // staging rounds (256 thr * 16B)
  constexpr int TPR = RB / 16;          // threads per row
  constexpr int RPR = 4096 / RB;        // rows per round
  constexpr int SWM = TPR - 1;          // swizzle mask
  constexpr int LA  = 0;
  constexpr int LAL = (NPASS == 3) ? TB : 0;
  constexpr int LB  = (NPASS == 3) ? 2 * TB : TB;
  constexpr int LBL = (NPASS == 3) ? 3 * TB : 0;

  __shared__ __align__(16) char lds[32768];

  const int tid  = threadIdx.x;
  const int wave = tid >> 6;
  const int lane = tid & 63;

  int m0, mcnt, eidx = 0;
  if (MODE == 2) {
    TileInfo ti = table[blockIdx.x];
    if (ti.mcnt <= 0) return;
    m0 = ti.m0; mcnt = ti.mcnt; eidx = ti.e;
  } else { m0 = blockIdx.x * 128; mcnt = 128; }
  const int n0 = blockIdx.y * 128;

  const f16* Bh_ = Bh;
  const float* bias_ = bias;
  size_t adelta = 0, bdelta = 0;
  if (NPASS == 3) {
    adelta = (size_t)((const char*)Al - (const char*)Ah);
    bdelta = (size_t)((const char*)Bl - (const char*)Bh);
  }
  if (MODE == 2) { Bh_ += ((size_t)eidx << 20); bias_ += eidx * 1024; }

  const int sr    = tid / TPR;
  const int cbyte = (tid % TPR) * 16;

  const char* aSrc[ROUNDS];
  const char* bSrc[ROUNDS];
  int aRowC[ROUNDS]; int aCbs[ROUNDS];
  #pragma unroll
  for (int r = 0; r < ROUNDS; ++r) {
    const int mr  = sr + r * RPR;
    const int cbs = cbyte ^ ((mr & SWM) << 4);
    int gi = m0 + ((mr < mcnt) ? mr : (mcnt - 1));
    if (MODE == 1 || MODE == 2) gi = rowmap[gi];
    if (MODE == 3) { aRowC[r] = gi; aCbs[r] = cbs; aSrc[r] = nullptr; }
    else           { aSrc[r] = (const char*)Ah + (size_t)gi * lda * 2 + cbs; aRowC[r] = 0; aCbs[r] = 0; }
    const int nr   = sr + r * RPR;
    const int ncbs = cbyte ^ ((nr & SWM) << 4);
    bSrc[r] = (const char*)Bh_ + (size_t)(n0 + nr) * ldb * 2 + ncbs;
  }

  f32x4 acc[4][4] = {};
  const int wm  = (wave >> 1) * 64;
  const int wn  = (wave & 1) * 64;
  const int fr  = lane & 15;
  const int kgb = (lane >> 4) * 16;

  for (int k0 = 0; k0 < K; k0 += BK) {
    #pragma unroll
    for (int r = 0; r < ROUNDS; ++r) {
      const char* as;
      if (MODE == 3) {
        const int tap = k0 >> 10;
        const int kc  = k0 & 1023;
        int grow = aRowC[r] + (tap - 1) * 2;
        grow = (grow < 0) ? 0 : (grow > 8191 ? 8191 : grow);
        as = (const char*)Ah + (size_t)grow * 2048 + kc * 2 + aCbs[r];
      } else {
        as = aSrc[r] + (size_t)k0 * 2;
      }
      gload16(as, lds + LA + r * 4096 + wave * 1024);
      if (NPASS == 3) gload16(as + adelta, lds + LAL + r * 4096 + wave * 1024);
      const char* bs = bSrc[r] + (size_t)k0 * 2;
      gload16(bs, lds + LB + r * 4096 + wave * 1024);
      if (NPASS == 3) gload16(bs + bdelta, lds + LBL + r * 4096 + wave * 1024);
    }
    __syncthreads();
    #pragma unroll
    for (int kk = 0; kk < BK / 32; ++kk) {
      f16x8 ah[4], bh[4], al[4], bl[4];
      #pragma unroll
      for (int i = 0; i < 4; ++i) {
        const int ar = wm + i * 16 + fr;
        const int ao = ar * RB + ((kk * 64 + kgb) ^ ((ar & SWM) << 4));
        ah[i] = *(const f16x8*)(lds + LA + ao);
        if (NPASS == 3) al[i] = *(const f16x8*)(lds + LAL + ao);
        const int br = wn + i * 16 + fr;
        const int bo = br * RB + ((kk * 64 + kgb) ^ ((br & SWM) << 4));
        bh[i] = *(const f16x8*)(lds + LB + bo);
        if (NPASS == 3) bl[i] = *(const f16x8*)(lds + LBL + bo);
      }
      #pragma unroll
      for (int i = 0; i < 4; ++i) {
        #pragma unroll
        for (int j = 0; j < 4; ++j) {
          acc[i][j] = __builtin_amdgcn_mfma_f32_16x16x32_f16(ah[i], bh[j], acc[i][j], 0, 0, 0);
          if (NPASS == 3) {
            acc[i][j] = __builtin_amdgcn_mfma_f32_16x16x32_f16(ah[i], bl[j], acc[i][j], 0, 0, 0);
            acc[i][j] = __builtin_amdgcn_mfma_f32_16x16x32_f16(al[i], bh[j], acc[i][j], 0, 0, 0);
          }
        }
      }
    }
    __syncthreads();
  }

  #pragma unroll
  for (int i = 0; i < 4; ++i) {
    const int mb = wm + i * 16 + (lane >> 4) * 4;
    #pragma unroll
    for (int j = 0; j < 4; ++j) {
      const int nc = n0 + wn + j * 16 + fr;
      const float bv = bias_[nc];
      #pragma unroll
      for (int q = 0; q < 4; ++q) {
        const int ml = mb + q;
        if (MODE == 2 && ml >= mcnt) continue;
        const size_t orow = (size_t)(m0 + ml);
        float v = acc[i][j][q] + bv;
        if (EPI == 1) v += res[orow * ldo + nc];
        if (EPI == 3) v = 0.5f * v * (1.0f + erff(v * 0.70710678118654752440f));
        if (EPI <= 1) outf[orow * ldo + nc] = v;
        else          outh[orow * ldo + nc] = (f16)v;
      }
    }
  }
}

// ---------------------------------------------------------------------------
// LayerNorm: fp32 in -> f16 hi (+optional lo plane, +optional fp32 copy)
// ---------------------------------------------------------------------------
template<int WLO, int WF32>
__global__ __launch_bounds__(256)
void ln_kernel(const float* __restrict__ x, const float* __restrict__ g, const float* __restrict__ b,
               f16* __restrict__ oh, f16* __restrict__ ol, float* __restrict__ of) {
  const int row = blockIdx.x;
  const int t = threadIdx.x;
  const float4 v = ((const float4*)(x + (size_t)row * 1024))[t];
  float s  = v.x + v.y + v.z + v.w;
  float ss = v.x * v.x + v.y * v.y + v.z * v.z + v.w * v.w;
  #pragma unroll
  for (int off = 32; off; off >>= 1) { s += __shfl_down(s, off, 64); ss += __shfl_down(ss, off, 64); }
  __shared__ float red[8];
  if ((t & 63) == 0) { red[t >> 6] = s; red[(t >> 6) + 4] = ss; }
  __syncthreads();
  s  = red[0] + red[1] + red[2] + red[3];
  ss = red[4] + red[5] + red[6] + red[7];
  const float mu  = s * (1.0f / 1024.0f);
  const float var = ss * (1.0f / 1024.0f) - mu * mu;
  const float inv = 1.0f / sqrtf(var + 1e-5f);
  const float4 gv = ((const float4*)g)[t];
  const float4 bv = ((const float4*)b)[t];
  float y[4];
  y[0] = (v.x - mu) * inv * gv.x + bv.x;
  y[1] = (v.y - mu) * inv * gv.y + bv.y;
  y[2] = (v.z - mu) * inv * gv.z + bv.z;
  y[3] = (v.w - mu) * inv * gv.w + bv.w;
  f16x4 hv;
  #pragma unroll
  for (int u = 0; u < 4; ++u) hv[u] = (f16)y[u];
  *(f16x4*)(oh + (size_t)row * 1024 + t * 4) = hv;
  if (WLO) {
    f16x4 lv;
    #pragma unroll
    for (int u = 0; u < 4; ++u) lv[u] = (f16)(y[u] - (float)hv[u]);
    *(f16x4*)(ol + (size_t)row * 1024 + t * 4) = lv;
  }
  if (WF32) {
    float4 fv; fv.x = y[0]; fv.y = y[1]; fv.z = y[2]; fv.w = y[3];
    ((float4*)(of + (size_t)row * 1024))[t] = fv;
  }
}

// ---------------------------------------------------------------------------
// Windowed "attention" (faithful to unfold bug): per (b,h,n<16):
// A[d][e]=softmax_e( (1/8) sum_s q[s,d]k[s,e] ), O[d][s]=sum_e A[d][e] v[s,e]
// output row n*256+d*4+(s>>6), channel h*64+(s&63).  All fp32.
// ---------------------------------------------------------------------------
__global__ __launch_bounds__(256)
void attn_kernel(const float* __restrict__ qkv, f16* __restrict__ oh, f16* __restrict__ ol) {
  __shared__ __align__(16) char sm[65536];
  const int bid = blockIdx.x;
  const int b = bid >> 8, h = (bid >> 4) & 15, n = bid & 15;
  const int t = threadIdx.x;
  const size_t rowbase = (size_t)(b * 2176 + n * 128);
  const float* qb = qkv + rowbase * 3072 + h * 64;
  const float* kb = qb + 1024;
  const float* vb = qb + 2048;

  const int dq = t >> 2;       // score row (hd)
  const int eg = t & 3;        // score col group
  float pacc[16];
  #pragma unroll
  for (int u = 0; u < 16; ++u) pacc[u] = 0.0f;

  const int ld0 = (t & 15) * 4;
  const int ls0 = t >> 4;

  // ---- QK over two s-chunks of 128 ----
  for (int cs = 0; cs < 2; ++cs) {
    for (int rr = 0; rr < 8; ++rr) {
      const int sp = ls0 + rr * 16;
      const int s  = cs * 128 + sp;
      const float4 qv = *(const float4*)(qb + (size_t)s * 3072 + ld0);
      const float4 kv = *(const float4*)(kb + (size_t)s * 3072 + ld0);
      float qa[4] = {qv.x, qv.y, qv.z, qv.w};
      float ka[4] = {kv.x, kv.y, kv.z, kv.w};
      #pragma unroll
      for (int j = 0; j < 4; ++j) {
        const int d = ld0 + j;
        const int off = d * 512 + ((sp * 4) ^ ((d & 7) << 4));
        *(float*)(sm + off) = qa[j];
        *(float*)(sm + 32768 + off) = ka[j];
      }
    }
    __syncthreads();
    for (int sg = 0; sg < 32; ++sg) {
      const f32x4 qv = *(const f32x4*)(sm + dq * 512 + ((sg * 16) ^ ((dq & 7) << 4)));
      #pragma unroll
      for (int j = 0; j < 16; ++j) {
        const int el = (j + eg * 4) & 15;      // address rotation (banks)
        const int e  = eg * 16 + el;
        const f32x4 kv = *(const f32x4*)(sm + 32768 + e * 512 + ((sg * 16) ^ ((e & 7) << 4)));
        pacc[j] += qv[0] * kv[0] + qv[1] * kv[1] + qv[2] * kv[2] + qv[3] * kv[3];
      }
    }
    __syncthreads();
  }

  // ---- softmax over e (row dq lives in 4 adjacent lanes) ----
  float mx = -1e30f;
  #pragma unroll
  for (int u = 0; u < 16; ++u) { pacc[u] *= 0.125f; mx = fmaxf(mx, pacc[u]); }
  mx = fmaxf(mx, __shfl_xor(mx, 1, 4));
  mx = fmaxf(mx, __shfl_xor(mx, 2, 4));
  float den = 0.0f;
  #pragma unroll
  for (int u = 0; u < 16; ++u) { pacc[u] = expf(pacc[u] - mx); den += pacc[u]; }
  den += __shfl_xor(den, 1, 4);
  den += __shfl_xor(den, 2, 4);
  const float dinv = 1.0f / den;
  #pragma unroll
  for (int u = 0; u < 16; ++u) pacc[u] *= dinv;

  // ---- PV over two s-chunks; P fetched cross-lane via shfl ----
  const int sg2 = t & 3;
  for (int vs = 0; vs < 2; ++vs) {
    for (int rr = 0; rr < 8; ++rr) {
      const int sp = ls0 + rr * 16;
      const int s  = vs * 128 + sp;
      const float4 vv = *(const float4*)(vb + (size_t)s * 3072 + ld0);
      float va[4] = {vv.x, vv.y, vv.z, vv.w};
      #pragma unroll
      for (int j = 0; j < 4; ++j) {
        const int e = ld0 + j;
        const int off = e * 512 + ((sp * 4) ^ ((e & 7) << 4));
        *(float*)(sm + 32768 + off) = va[j];
      }
    }
    __syncthreads();
    float o[32];
    #pragma unroll
    for (int u = 0; u < 32; ++u) o[u] = 0.0f;
    #pragma unroll
    for (int e = 0; e < 64; ++e) {
      const int jreg = ((e & 15) - ((e >> 4) << 2)) & 15;   // register of P[dq][e] in src lane
      const float p = __shfl(pacc[jreg], (t & 60) + (e >> 4), 64);
      #pragma unroll
      for (int k = 0; k < 8; ++k) {
        const int kk = (k + sg2 * 2) & 7;                   // address rotation
        const f32x4 vv = *(const f32x4*)(sm + 32768 + e * 512 + (((sg2 * 128) + kk * 16) ^ ((e & 7) << 4)));
        o[k * 4 + 0] += p * vv[0];
        o[k * 4 + 1] += p * vv[1];
        o[k * 4 + 2] += p * vv[2];
        o[k * 4 + 3] += p * vv[3];
      }
    }
    // write: row = b*4096 + n*256 + dq*4 + vs*2 + (sg2>>1); ch = h*64 + (sg2&1)*32 + kk*4+u
    const size_t prow = (size_t)(b * 4096 + n * 256 + dq * 4 + vs * 2 + (sg2 >> 1));
    const int cbase = h * 64 + (sg2 & 1) * 32;
    #pragma unroll
    for (int k = 0; k < 8; ++k) {
      const int kk = (k + sg2 * 2) & 7;
      f16x4 hv, lv;
      #pragma unroll
      for (int u = 0; u < 4; ++u) {
        const float val = o[k * 4 + u];
        hv[u] = (f16)val;
        lv[u] = (f16)(val - (float)hv[u]);
      }
      *(f16x4*)(oh + prow * 1024 + cbase + kk * 4) = hv;
      *(f16x4*)(ol + prow * 1024 + cbase + kk * 4) = lv;
    }
    __syncthreads();
  }
}

// ---------------------------------------------------------------------------
// weight transposes fp32 -> f16 (optional lo plane); batched over blockIdx.z
// ---------------------------------------------------------------------------
template<int SPLIT>
__global__ __launch_bounds__(256)
void transpose_kernel(const float* __restrict__ in, int R, int Cc,
                      f16* __restrict__ oh, f16* __restrict__ ol) {
  __shared__ float tile[32][33];
  const size_t mat = (size_t)blockIdx.z * R * Cc;
  in += mat; oh += mat; if (SPLIT) ol += mat;
  const int tx = threadIdx.x & 31, ty = threadIdx.x >> 5;
  const int c = blockIdx.x * 32 + tx;
  #pragma unroll
  for (int j = 0; j < 32; j += 8) {
    const int r = blockIdx.y * 32 + ty + j;
    tile[ty + j][tx] = in[(size_t)r * Cc + c];
  }
  __syncthreads();
  const int rT = blockIdx.y * 32 + tx;
  #pragma unroll
  for (int j = 0; j < 32; j += 8) {
    const int cT = blockIdx.x * 32 + ty + j;
    const float v = tile[tx][ty + j];
    const f16 hv = (f16)v;
    oh[(size_t)cT * R + rT] = hv;
    if (SPLIT) ol[(size_t)cT * R + rT] = (f16)(v - (float)hv);
  }
}

// conv weights [O,I,3] -> BT[o][tap*1024+i] hi/lo
__global__ __launch_bounds__(256)
void convw_kernel(const float* __restrict__ w, f16* __restrict__ oh, f16* __restrict__ ol) {
  const int id = blockIdx.x * 256 + threadIdx.x;  // 1024*1024
  const int o = id >> 10, i = id & 1023;
  const float* ws = w + (size_t)o * 3072 + i * 3;
  #pragma unroll
  for (int tap = 0; tap < 3; ++tap) {
    const float v = ws[tap];
    const f16 hv = (f16)v;
    const size_t oi = (size_t)o * 3072 + tap * 1024 + i;
    oh[oi] = hv;
    ol[oi] = (f16)(v - (float)hv);
  }
}

__global__ void qkvrows_kernel(int* __restrict__ rows) {
  const int r = blockIdx.x * 256 + threadIdx.x;
  if (r < 4352) rows[r] = (r >= 2176) ? (4096 + r - 2176) : r;
}

// conv boundary fixup: exact fp32 recompute of 8 rows
__global__ __launch_bounds__(256)
void conv_fixup(const f16* __restrict__ ln2h, const f16* __restrict__ ln2l,
                const float* __restrict__ cw, const float* __restrict__ cb,
                const float* __restrict__ x1, float* __restrict__ x2) {
  const int q = blockIdx.x;
  const int bb = q >> 2, w = q & 3;
  const int tok = (w < 2) ? w : (4092 + w);
  const int row = bb * 4096 + tok;
  __shared__ float xs[3][1024];
  for (int tap = 0; tap < 3; ++tap) {
    const int st = tok + 2 * (tap - 1);
    const bool valid = (st >= 0 && st < 4096);
    const int srow = bb * 4096 + (valid ? st : 0);
    for (int c = threadIdx.x; c < 1024; c += 256)
      xs[tap][c] = valid ? ((float)ln2h[(size_t)srow * 1024 + c] + (float)ln2l[(size_t)srow * 1024 + c]) : 0.0f;
  }
  __syncthreads();
  for (int o = threadIdx.x; o < 1024; o += 256) {
    float acc = cb[o];
    const float* wr = cw + (size_t)o * 3072;
    for (int i = 0; i < 1024; ++i) {
      acc += xs[0][i] * wr[i * 3] + xs[1][i] * wr[i * 3 + 1] + xs[2][i] * wr[i * 3 + 2];
    }
    x2[(size_t)row * 1024 + o] = x1[(size_t)row * 1024 + o] + acc;
  }
}

// ---------------------------------------------------------------------------
// gate: one wave per token; fp32 logits from fp32 LN3 (selection fidelity)
// ---------------------------------------------------------------------------
__global__ __launch_bounds__(256)
void gate_kernel(const float* __restrict__ ln3f, const float* __restrict__ gW,
                 const float* __restrict__ gb, float* __restrict__ top2p,
                 int* __restrict__ top2i, float* __restrict__ ent, int* __restrict__ counts) {
  const int token = (blockIdx.x << 2) + (threadIdx.x >> 6);
  const int lane = threadIdx.x & 63;
  const float* xr = ln3f + (size_t)token * 1024 + lane * 16;
  float lg[8];
  #pragma unroll
  for (int e = 0; e < 8; ++e) lg[e] = 0.0f;
  #pragma unroll
  for (int u = 0; u < 4; ++u) {
    const float4 xv = *(const float4*)(xr + u * 4);
    const float* gr = gW + (size_t)(lane * 16 + u * 4) * 8;
    float xa[4] = {xv.x, xv.y, xv.z, xv.w};
    #pragma unroll
    for (int qq = 0; qq < 4; ++qq)
      #pragma unroll
      for (int e = 0; e < 8; ++e) lg[e] += xa[qq] * gr[qq * 8 + e];
  }
  #pragma unroll
  for (int m = 1; m < 64; m <<= 1)
    #pragma unroll
    for (int e = 0; e < 8; ++e) lg[e] += __shfl_xor(lg[e], m, 64);
  if (lane == 0) {
    #pragma unroll
    for (int e = 0; e < 8; ++e) lg[e] += gb[e];
    int i0 = 0; float v0 = lg[0];
    #pragma unroll
    for (int e = 1; e < 8; ++e) if (lg[e] > v0) { v0 = lg[e]; i0 = e; }
    int i1 = 0; float v1 = -1e30f;
    #pragma unroll
    for (int e = 0; e < 8; ++e) if (e != i0 && lg[e] > v1) { v1 = lg[e]; i1 = e; }
    float den = 0.0f; float pr[8];
    #pragma unroll
    for (int e = 0; e < 8; ++e) { pr[e] = expf(lg[e] - v0); den += pr[e]; }
    const float dinv = 1.0f / den;
    float H = 0.0f, p0 = 0.0f, p1 = 0.0f;
    #pragma unroll
    for (int e = 0; e < 8; ++e) {
      const float p = pr[e] * dinv;
      H -= p * logf(p + 1e-10f);
      if (e == i0) p0 = p;
      if (e == i1) p1 = p;
    }
    ent[token] = H;
    top2p[token * 2] = p0; top2p[token * 2 + 1] = p1;
    top2i[token * 2] = i0; top2i[token * 2 + 1] = i1;
    atomicAdd(&counts[i0], 1);
    atomicAdd(&counts[i1], 1);
  }
}

// scan: entropy mean (fixed order), offsets, aux, tile table
__global__ __launch_bounds__(256)
void scan_kernel(const float* __restrict__ ent, const int* __restrict__ counts,
                 int* __restrict__ offs, TileInfo* __restrict__ table, float* __restrict__ auxout) {
  __shared__ float red[256];
  const int t = threadIdx.x;
  float s = 0.0f;
  for (int k = 0; k < 32; ++k) s += ent[t + (k << 8)];
  red[t] = s; __syncthreads();
  for (int hh = 128; hh > 0; hh >>= 1) { if (t < hh) red[t] += red[t + hh]; __syncthreads(); }
  if (t == 0) {
    const float entmean = red[0] * (1.0f / 8192.0f);
    float pen = 0.0f; int off = 0; int nt = 0;
    for (int e = 0; e < 8; ++e) {
      const int c = counts[e];
      offs[e] = off;
      for (int m = 0; m < c; m += 128) {
        table[nt].m0 = off + m;
        table[nt].mcnt = (c - m < 128) ? (c - m) : 128;
        table[nt].e = e; table[nt].pad = 0;
        ++nt;
      }
      off += c;
      const float fr = (float)c * (1.0f / 8192.0f) - 0.3f;
      pen += (fr > 0.0f) ? fr : 0.0f;
    }
    for (; nt < 160; ++nt) { table[nt].m0 = 0; table[nt].mcnt = 0; table[nt].e = 0; table[nt].pad = 0; }
    auxout[0] = 0.1f * entmean + pen;
  }
}

__global__ void scatter_kernel(const int* __restrict__ top2i, const int* __restrict__ offs,
                               int* __restrict__ fill, int* __restrict__ moe_rows,
                               int* __restrict__ row2slot) {
  const int id = blockIdx.x * 256 + threadIdx.x;  // 16384
  const int e = top2i[id];
  const int slot = atomicAdd(&fill[e], 1);
  const int row = offs[e] + slot;
  moe_rows[row] = id >> 1;
  row2slot[id] = row;
}

// x3 = x2 + p0*eo[r0] + p1*eo[r1]; also f16 copy for FF1
__global__ __launch_bounds__(256)
void combine_kernel(const float* __restrict__ x2, const f16* __restrict__ eo,
                    const float* __restrict__ top2p, const int* __restrict__ row2slot,
                    float* __restrict__ x3, f16* __restrict__ x3h) {
  const int n = blockIdx.x;
  const int t = threadIdx.x;
  const int r0 = row2slot[n * 2], r1 = row2slot[n * 2 + 1];
  const float p0 = top2p[n * 2], p1 = top2p[n * 2 + 1];
  const float4 xv = ((const float4*)(x2 + (size_t)n * 1024))[t];
  const f16x4 e0 = ((const f16x4*)(eo + (size_t)r0 * 1024))[t];
  const f16x4 e1 = ((const f16x4*)(eo + (size_t)r1 * 1024))[t];
  float4 o;
  o.x = xv.x + p0 * (float)e0[0] + p1 * (float)e1[0];
  o.y = xv.y + p0 * (float)e0[1] + p1 * (float)e1[1];
  o.z = xv.z + p0 * (float)e0[2] + p1 * (float)e1[2];
  o.w = xv.w + p0 * (float)e0[3] + p1 * (float)e1[3];
  ((float4*)(x3 + (size_t)n * 1024))[t] = o;
  f16x4 hv; hv[0] = (f16)o.x; hv[1] = (f16)o.y; hv[2] = (f16)o.z; hv[3] = (f16)o.w;
  ((f16x4*)(x3h + (size_t)n * 1024))[t] = hv;
}

// ---------------------------------------------------------------------------
extern "C" void kernel_launch(void* const* d_in, const int* in_sizes, int n_in,
                              void* d_out, int out_size, void* d_ws, size_t ws_size,
                              hipStream_t stream) {
  (void)in_sizes; (void)n_in; (void)out_size; (void)ws_size;
  const float* x     = (const float*)d_in[0];
  const float* g1    = (const float*)d_in[1];
  const float* b1    = (const float*)d_in[2];
  const float* g2    = (const float*)d_in[3];
  const float* b2    = (const float*)d_in[4];
  const float* g3    = (const float*)d_in[5];
  const float* b3    = (const float*)d_in[6];
  const float* Wqkv  = (const float*)d_in[7];
  const float* bqkv  = (const float*)d_in[8];
  const float* Wo    = (const float*)d_in[9];
  const float* bo    = (const float*)d_in[10];
  const float* convw = (const float*)d_in[11];
  const float* convb = (const float*)d_in[12];
  const float* gateW = (const float*)d_in[13];
  const float* gateb = (const float*)d_in[14];
  const float* expW  = (const float*)d_in[15];
  const float* expb  = (const float*)d_in[16];
  const float* ffW1  = (const float*)d_in[17];
  const float* ffb1  = (const float*)d_in[18];
  const float* ffW2  = (const float*)d_in[19];
  const float* ffb2  = (const float*)d_in[20];
  float* out = (float*)d_out;

  char* W = (char*)d_ws;
  f16* wqkvT_h = (f16*)(W + 0);
  f16* wqkvT_l = (f16*)(W + 6291456);
  f16* woT_h   = (f16*)(W + 12582912);
  f16* woT_l   = (f16*)(W + 14680064);
  f16* wcvT_h  = (f16*)(W + 16777216);
  f16* wcvT_l  = (f16*)(W + 23068672);
  f16* wexpT   = (f16*)(W + 29360128);
  f16* wff1T   = (f16*)(W + 46137344);
  f16* wff2T   = (f16*)(W + 54525952);
  char* META   = W + 62914560;
  int* counts    = (int*)(META);
  int* fill      = (int*)(META + 32);
  int* offs      = (int*)(META + 64);
  TileInfo* table = (TileInfo*)(META + 128);
  int* qkv_rows  = (int*)(META + 4096);
  float* ent     = (float*)(META + 24576);
  float* top2p   = (float*)(META + 57344);
  int* top2i     = (int*)(META + 122880);
  int* moe_rows  = (int*)(META + 188416);
  int* row2slot  = (int*)(META + 253952);
  char* SA = W + 63963136;    // 32 MB: ln1/ln2 hi|lo ; ln3_hi | x3_hi
  char* SB = W + 97517568;    // 64 MB: qkv f32 -> x2 f32 -> h f16
  char* SC = W + 164626432;   // 32 MB: attn hi|lo -> ln3 f32
  char* SD = W + 198180864;   // 32 MB: x1 f32 -> eo f16
  char* SE = W + 231735296;   // 32 MB: x3 f32

  f16* ln1h = (f16*)SA;            f16* ln1l = (f16*)(SA + 16777216);
  f16* ln2h = ln1h;                f16* ln2l = ln1l;
  f16* ln3h = ln1h;                f16* x3h  = (f16*)(SA + 16777216);
  float* qkvbuf = (float*)SB;
  float* x2buf  = (float*)SB;
  f16*   hbuf   = (f16*)SB;
  f16* attnh = (f16*)SC;           f16* attnl = (f16*)(SC + 16777216);
  float* ln3f = (float*)SC;
  float* x1 = (float*)SD;
  f16* eobuf = (f16*)SD;
  float* x3 = (float*)SE;

  hipMemsetAsync((void*)counts, 0, 64, stream);

  dim3 blk(256);
  // weight prep
  transpose_kernel<1><<<dim3(96, 32, 1), blk, 0, stream>>>(Wqkv, 1024, 3072, wqkvT_h, wqkvT_l);
  transpose_kernel<1><<<dim3(32, 32, 1), blk, 0, stream>>>(Wo, 1024, 1024, woT_h, woT_l);
  convw_kernel<<<4096, blk, 0, stream>>>(convw, wcvT_h, wcvT_l);
  transpose_kernel<0><<<dim3(32, 32, 8), blk, 0, stream>>>(expW, 1024, 1024, wexpT, nullptr);
  transpose_kernel<0><<<dim3(128, 32, 1), blk, 0, stream>>>(ffW1, 1024, 4096, wff1T, nullptr);
  transpose_kernel<0><<<dim3(32, 128, 1), blk, 0, stream>>>(ffW2, 4096, 1024, wff2T, nullptr);
  qkvrows_kernel<<<17, blk, 0, stream>>>(qkv_rows);

  // LN1 -> split planes
  ln_kernel<1, 0><<<8192, blk, 0, stream>>>(x, g1, b1, ln1h, ln1l, nullptr);
  // QKV (rows 0..2175 per batch), split GEMM, fp32 out
  gemm_kernel<3, 1, 0><<<dim3(34, 24), blk, 0, stream>>>(ln1h, ln1l, 1024, wqkvT_h, wqkvT_l, 1024,
      bqkv, nullptr, qkvbuf, nullptr, 3072, 1024, qkv_rows, nullptr);
  // attention
  attn_kernel<<<512, blk, 0, stream>>>(qkvbuf, attnh, attnl);
  // Wo projection + residual -> x1
  gemm_kernel<3, 0, 1><<<dim3(64, 8), blk, 0, stream>>>(attnh, attnl, 1024, woT_h, woT_l, 1024,
      bo, x, x1, nullptr, 1024, 1024, nullptr, nullptr);
  // LN2
  ln_kernel<1, 0><<<8192, blk, 0, stream>>>(x1, g2, b2, ln2h, ln2l, nullptr);
  // conv (3-tap shifted GEMM) + residual -> x2, then boundary fixup
  gemm_kernel<3, 3, 1><<<dim3(64, 8), blk, 0, stream>>>(ln2h, ln2l, 1024, wcvT_h, wcvT_l, 3072,
      convb, x1, x2buf, nullptr, 1024, 3072, nullptr, nullptr);
  conv_fixup<<<8, blk, 0, stream>>>(ln2h, ln2l, convw, convb, x1, x2buf);
  // LN3 (f16 hi for experts + fp32 for gate)
  ln_kernel<0, 1><<<8192, blk, 0, stream>>>(x2buf, g3, b3, ln3h, nullptr, ln3f);
  // gate / scan / scatter
  gate_kernel<<<2048, blk, 0, stream>>>(ln3f, gateW, gateb, top2p, top2i, ent, counts);
  scan_kernel<<<1, blk, 0, stream>>>(ent, counts, offs, table, out + 8388608);
  scatter_kernel<<<64, blk, 0, stream>>>(top2i, offs, fill, moe_rows, row2slot);
  // grouped expert GEMM -> eo (f16)
  gemm_kernel<1, 2, 2><<<dim3(136, 8), blk, 0, stream>>>(ln3h, nullptr, 1024, wexpT, nullptr, 1024,
      expb, nullptr, nullptr, eobuf, 1024, 1024, moe_rows, table);
  // combine -> x3 (+f16)
  combine_kernel<<<8192, blk, 0, stream>>>(x2buf, eobuf, top2p, row2slot, x3, x3h);
  // FF1 (gelu) -> h
  gemm_kernel<1, 0, 3><<<dim3(64, 32), blk, 0, stream>>>(x3h, nullptr, 1024, wff1T, nullptr, 1024,
      ffb1, nullptr, nullptr, hbuf, 4096, 1024, nullptr, nullptr);
  // FF2 + residual -> final output
  gemm_kernel<1, 0, 1><<<dim3(64, 8), blk, 0, stream>>>(hbuf, nullptr, 4096, wff2T, nullptr, 4096,
      ffb2, x3, out, nullptr, 1024, 4096, nullptr, nullptr);
}

// Round 2
// 1220.482 us; speedup vs baseline: 1.3905x; 1.3905x over previous
//
#include <hip/hip_runtime.h>
#include <cmath>

typedef _Float16 f16;
typedef __attribute__((ext_vector_type(8))) _Float16 f16x8;
typedef __attribute__((ext_vector_type(4))) _Float16 f16x4;
typedef __attribute__((ext_vector_type(4))) float f32x4;

struct TileInfo { int m0, mcnt, e, pad; };

__device__ __forceinline__ void gload16(const void* g, void* l) {
  __builtin_amdgcn_global_load_lds((const __attribute__((address_space(1))) void*)g,
                                   (__attribute__((address_space(3))) void*)l, 16, 0, 0);
}

// ---------------------------------------------------------------------------
// Unified GEMM:  C[M,N] = A[M,K] * B[K,N] (+bias, +res, +gelu), B given
// transposed (BT[N,K], row-major).  A/B in f16; NPASS==3 adds lo-planes for
// fp32-faithful results (hh+hl+lh).  MODE: 0 direct, 1 rowmap(A rows),
// 2 tile-table (MoE grouped), 3 conv (3-tap shifted A rows with exact
// zero-padding via zbuf, K=3072).
// EPI: 0 f32=acc+bias; 1 f32=res+acc+bias; 2 f16=acc+bias; 3 f16=gelu(acc+bias)
// ---------------------------------------------------------------------------
template<int NPASS, int MODE, int EPI>
__global__ __launch_bounds__(256)
void gemm_kernel(const f16* __restrict__ Ah, const f16* __restrict__ Al, int lda,
                 const f16* __restrict__ Bh, const f16* __restrict__ Bl, int ldb,
                 const float* __restrict__ bias, const float* __restrict__ res,
                 float* __restrict__ outf, f16* __restrict__ outh, int ldo, int K,
                 const int* __restrict__ rowmap, const TileInfo* __restrict__ table,
                 const char* __restrict__ zbuf) {
  constexpr int BK = (NPASS == 1) ? 64 : 32;
  constexpr int RB = BK * 2;            // bytes per LDS tile row
  constexpr int TB = 128 * RB;          // bytes per tile plane
  constexpr int ROUNDS = TB / 4096;     // staging rounds (256 thr * 16B)
  constexpr int TPR = RB / 16;          // threads per row
  constexpr int RPR = 4096 / RB;        // rows per round
  constexpr int SWM = TPR - 1;          // swizzle mask
  constexpr int LA  = 0;
  constexpr int LAL = (NPASS == 3) ? TB : 0;
  constexpr int LB  = (NPASS == 3) ? 2 * TB : TB;
  constexpr int LBL = (NPASS == 3) ? 3 * TB : 0;

  __shared__ __align__(16) char lds[32768];

  const int tid  = threadIdx.x;
  const int wave = tid >> 6;
  const int lane = tid & 63;

  int m0, mcnt, eidx = 0;
  if (MODE == 2) {
    TileInfo ti = table[blockIdx.x];
    if (ti.mcnt <= 0) return;
    m0 = ti.m0; mcnt = ti.mcnt; eidx = ti.e;
  } else { m0 = blockIdx.x * 128; mcnt = 128; }
  const int n0 = blockIdx.y * 128;

  const f16* Bh_ = Bh;
  const float* bias_ = bias;
  size_t adelta = 0, bdelta = 0;
  if (NPASS == 3) {
    adelta = (size_t)((const char*)Al - (const char*)Ah);
    bdelta = (size_t)((const char*)Bl - (const char*)Bh);
  }
  if (MODE == 2) { Bh_ += ((size_t)eidx << 20); bias_ += eidx * 1024; }

  const int sr    = tid / TPR;
  const int cbyte = (tid % TPR) * 16;

  const char* aSrc[ROUNDS];
  const char* bSrc[ROUNDS];
  int aRowC[ROUNDS]; int aCbs[ROUNDS];
  #pragma unroll
  for (int r = 0; r < ROUNDS; ++r) {
    const int mr  = sr + r * RPR;
    const int cbs = cbyte ^ ((mr & SWM) << 4);
    int gi = m0 + ((mr < mcnt) ? mr : (mcnt - 1));
    if (MODE == 1 || MODE == 2) gi = rowmap[gi];
    if (MODE == 3) { aRowC[r] = gi; aCbs[r] = cbs; aSrc[r] = nullptr; }
    else           { aSrc[r] = (const char*)Ah + (size_t)gi * lda * 2 + cbs; aRowC[r] = 0; aCbs[r] = 0; }
    const int nr   = sr + r * RPR;
    const int ncbs = cbyte ^ ((nr & SWM) << 4);
    bSrc[r] = (const char*)Bh_ + (size_t)(n0 + nr) * ldb * 2 + ncbs;
  }

  f32x4 acc[4][4] = {};
  const int wm  = (wave >> 1) * 64;
  const int wn  = (wave & 1) * 64;
  const int fr  = lane & 15;
  const int kgb = (lane >> 4) * 16;

  for (int k0 = 0; k0 < K; k0 += BK) {
    #pragma unroll
    for (int r = 0; r < ROUNDS; ++r) {
      const char* as;
      const char* asl = nullptr;
      if (MODE == 3) {
        // exact zero-padded dilated-conv taps: tok + 2*(tap-1) within batch
        const int tap = k0 >> 10;
        const int kc  = k0 & 1023;
        const int tok = aRowC[r] & 4095;
        const int st  = tok + (tap - 1) * 2;
        if (st >= 0 && st < 4096) {
          as  = (const char*)Ah + (size_t)(aRowC[r] + (tap - 1) * 2) * 2048 + kc * 2 + aCbs[r];
          asl = as + adelta;
        } else {
          as  = zbuf;   // 16B of zeros (all lanes broadcast-read)
          asl = zbuf;
        }
      } else {
        as = aSrc[r] + (size_t)k0 * 2;
        if (NPASS == 3) asl = as + adelta;
      }
      gload16(as, lds + LA + r * 4096 + wave * 1024);
      if (NPASS == 3) gload16(asl, lds + LAL + r * 4096 + wave * 1024);
      const char* bs = bSrc[r] + (size_t)k0 * 2;
      gload16(bs, lds + LB + r * 4096 + wave * 1024);
      if (NPASS == 3) gload16(bs + bdelta, lds + LBL + r * 4096 + wave * 1024);
    }
    __syncthreads();
    #pragma unroll
    for (int kk = 0; kk < BK / 32; ++kk) {
      f16x8 ah[4], bh[4], al[4], bl[4];
      #pragma unroll
      for (int i = 0; i < 4; ++i) {
        const int ar = wm + i * 16 + fr;
        const int ao = ar * RB + ((kk * 64 + kgb) ^ ((ar & SWM) << 4));
        ah[i] = *(const f16x8*)(lds + LA + ao);
        if (NPASS == 3) al[i] = *(const f16x8*)(lds + LAL + ao);
        const int br = wn + i * 16 + fr;
        const int bo = br * RB + ((kk * 64 + kgb) ^ ((br & SWM) << 4));
        bh[i] = *(const f16x8*)(lds + LB + bo);
        if (NPASS == 3) bl[i] = *(const f16x8*)(lds + LBL + bo);
      }
      #pragma unroll
      for (int i = 0; i < 4; ++i) {
        #pragma unroll
        for (int j = 0; j < 4; ++j) {
          acc[i][j] = __builtin_amdgcn_mfma_f32_16x16x32_f16(ah[i], bh[j], acc[i][j], 0, 0, 0);
          if (NPASS == 3) {
            acc[i][j] = __builtin_amdgcn_mfma_f32_16x16x32_f16(ah[i], bl[j], acc[i][j], 0, 0, 0);
            acc[i][j] = __builtin_amdgcn_mfma_f32_16x16x32_f16(al[i], bh[j], acc[i][j], 0, 0, 0);
          }
        }
      }
    }
    __syncthreads();
  }

  #pragma unroll
  for (int i = 0; i < 4; ++i) {
    const int mb = wm + i * 16 + (lane >> 4) * 4;
    #pragma unroll
    for (int j = 0; j < 4; ++j) {
      const int nc = n0 + wn + j * 16 + fr;
      const float bv = bias_[nc];
      #pragma unroll
      for (int q = 0; q < 4; ++q) {
        const int ml = mb + q;
        if (MODE == 2 && ml >= mcnt) continue;
        const size_t orow = (size_t)(m0 + ml);
        float v = acc[i][j][q] + bv;
        if (EPI == 1) v += res[orow * ldo + nc];
        if (EPI == 3) v = 0.5f * v * (1.0f + erff(v * 0.70710678118654752440f));
        if (EPI <= 1) outf[orow * ldo + nc] = v;
        else          outh[orow * ldo + nc] = (f16)v;
      }
    }
  }
}

// ---------------------------------------------------------------------------
// LayerNorm: fp32 in -> f16 hi (+optional lo plane, +optional fp32 copy)
// ---------------------------------------------------------------------------
template<int WLO, int WF32>
__global__ __launch_bounds__(256)
void ln_kernel(const float* __restrict__ x, const float* __restrict__ g, const float* __restrict__ b,
               f16* __restrict__ oh, f16* __restrict__ ol, float* __restrict__ of) {
  const int row = blockIdx.x;
  const int t = threadIdx.x;
  const float4 v = ((const float4*)(x + (size_t)row * 1024))[t];
  float s  = v.x + v.y + v.z + v.w;
  float ss = v.x * v.x + v.y * v.y + v.z * v.z + v.w * v.w;
  #pragma unroll
  for (int off = 32; off; off >>= 1) { s += __shfl_down(s, off, 64); ss += __shfl_down(ss, off, 64); }
  __shared__ float red[8];
  if ((t & 63) == 0) { red[t >> 6] = s; red[(t >> 6) + 4] = ss; }
  __syncthreads();
  s  = red[0] + red[1] + red[2] + red[3];
  ss = red[4] + red[5] + red[6] + red[7];
  const float mu  = s * (1.0f / 1024.0f);
  const float var = ss * (1.0f / 1024.0f) - mu * mu;
  const float inv = 1.0f / sqrtf(var + 1e-5f);
  const float4 gv = ((const float4*)g)[t];
  const float4 bv = ((const float4*)b)[t];
  float y[4];
  y[0] = (v.x - mu) * inv * gv.x + bv.x;
  y[1] = (v.y - mu) * inv * gv.y + bv.y;
  y[2] = (v.z - mu) * inv * gv.z + bv.z;
  y[3] = (v.w - mu) * inv * gv.w + bv.w;
  f16x4 hv;
  #pragma unroll
  for (int u = 0; u < 4; ++u) hv[u] = (f16)y[u];
  *(f16x4*)(oh + (size_t)row * 1024 + t * 4) = hv;
  if (WLO) {
    f16x4 lv;
    #pragma unroll
    for (int u = 0; u < 4; ++u) lv[u] = (f16)(y[u] - (float)hv[u]);
    *(f16x4*)(ol + (size_t)row * 1024 + t * 4) = lv;
  }
  if (WF32) {
    float4 fv; fv.x = y[0]; fv.y = y[1]; fv.z = y[2]; fv.w = y[3];
    ((float4*)(of + (size_t)row * 1024))[t] = fv;
  }
}

// ---------------------------------------------------------------------------
// Windowed "attention" (faithful to unfold bug): per (b,h,n<16):
// A[d][e]=softmax_e( (1/8) sum_s q[s,d]k[s,e] ), O[d][s]=sum_e A[d][e] v[s,e]
// output row n*256+d*4+(s>>6), channel h*64+(s&63).  All fp32.
// ---------------------------------------------------------------------------
__global__ __launch_bounds__(256)
void attn_kernel(const float* __restrict__ qkv, f16* __restrict__ oh, f16* __restrict__ ol) {
  __shared__ __align__(16) char sm[65536];
  const int bid = blockIdx.x;
  const int b = bid >> 8, h = (bid >> 4) & 15, n = bid & 15;
  const int t = threadIdx.x;
  const size_t rowbase = (size_t)(b * 2176 + n * 128);
  const float* qb = qkv + rowbase * 3072 + h * 64;
  const float* kb = qb + 1024;
  const float* vb = qb + 2048;

  const int dq = t >> 2;       // score row (hd)
  const int eg = t & 3;        // score col group
  float pacc[16];
  #pragma unroll
  for (int u = 0; u < 16; ++u) pacc[u] = 0.0f;

  const int ld0 = (t & 15) * 4;
  const int ls0 = t >> 4;

  // ---- QK over two s-chunks of 128 ----
  for (int cs = 0; cs < 2; ++cs) {
    for (int rr = 0; rr < 8; ++rr) {
      const int sp = ls0 + rr * 16;
      const int s  = cs * 128 + sp;
      const float4 qv = *(const float4*)(qb + (size_t)s * 3072 + ld0);
      const float4 kv = *(const float4*)(kb + (size_t)s * 3072 + ld0);
      float qa[4] = {qv.x, qv.y, qv.z, qv.w};
      float ka[4] = {kv.x, kv.y, kv.z, kv.w};
      #pragma unroll
      for (int j = 0; j < 4; ++j) {
        const int d = ld0 + j;
        const int off = d * 512 + ((sp * 4) ^ ((d & 7) << 4));
        *(float*)(sm + off) = qa[j];
        *(float*)(sm + 32768 + off) = ka[j];
      }
    }
    __syncthreads();
    for (int sg = 0; sg < 32; ++sg) {
      const f32x4 qv = *(const f32x4*)(sm + dq * 512 + ((sg * 16) ^ ((dq & 7) << 4)));
      #pragma unroll
      for (int j = 0; j < 16; ++j) {
        const int el = (j + eg * 4) & 15;      // address rotation (banks)
        const int e  = eg * 16 + el;
        const f32x4 kv = *(const f32x4*)(sm + 32768 + e * 512 + ((sg * 16) ^ ((e & 7) << 4)));
        pacc[j] += qv[0] * kv[0] + qv[1] * kv[1] + qv[2] * kv[2] + qv[3] * kv[3];
      }
    }
    __syncthreads();
  }

  // ---- softmax over e (row dq lives in 4 adjacent lanes) ----
  float mx = -1e30f;
  #pragma unroll
  for (int u = 0; u < 16; ++u) { pacc[u] *= 0.125f; mx = fmaxf(mx, pacc[u]); }
  mx = fmaxf(mx, __shfl_xor(mx, 1, 4));
  mx = fmaxf(mx, __shfl_xor(mx, 2, 4));
  float den = 0.0f;
  #pragma unroll
  for (int u = 0; u < 16; ++u) { pacc[u] = expf(pacc[u] - mx); den += pacc[u]; }
  den += __shfl_xor(den, 1, 4);
  den += __shfl_xor(den, 2, 4);
  const float dinv = 1.0f / den;
  #pragma unroll
  for (int u = 0; u < 16; ++u) pacc[u] *= dinv;

  // ---- PV over two s-chunks; P fetched cross-lane via shfl ----
  const int sg2 = t & 3;
  for (int vs = 0; vs < 2; ++vs) {
    for (int rr = 0; rr < 8; ++rr) {
      const int sp = ls0 + rr * 16;
      const int s  = vs * 128 + sp;
      const float4 vv = *(const float4*)(vb + (size_t)s * 3072 + ld0);
      float va[4] = {vv.x, vv.y, vv.z, vv.w};
      #pragma unroll
      for (int j = 0; j < 4; ++j) {
        const int e = ld0 + j;
        const int off = e * 512 + ((sp * 4) ^ ((e & 7) << 4));
        *(float*)(sm + 32768 + off) = va[j];
      }
    }
    __syncthreads();
    float o[32];
    #pragma unroll
    for (int u = 0; u < 32; ++u) o[u] = 0.0f;
    #pragma unroll
    for (int e = 0; e < 64; ++e) {
      const int jreg = ((e & 15) - ((e >> 4) << 2)) & 15;   // register of P[dq][e] in src lane
      const float p = __shfl(pacc[jreg], (t & 60) + (e >> 4), 64);
      #pragma unroll
      for (int k = 0; k < 8; ++k) {
        const int kk = (k + sg2 * 2) & 7;                   // address rotation
        const f32x4 vv = *(const f32x4*)(sm + 32768 + e * 512 + (((sg2 * 128) + kk * 16) ^ ((e & 7) << 4)));
        o[k * 4 + 0] += p * vv[0];
        o[k * 4 + 1] += p * vv[1];
        o[k * 4 + 2] += p * vv[2];
        o[k * 4 + 3] += p * vv[3];
      }
    }
    // write: row = b*4096 + n*256 + dq*4 + vs*2 + (sg2>>1); ch = h*64 + (sg2&1)*32 + kk*4+u
    const size_t prow = (size_t)(b * 4096 + n * 256 + dq * 4 + vs * 2 + (sg2 >> 1));
    const int cbase = h * 64 + (sg2 & 1) * 32;
    #pragma unroll
    for (int k = 0; k < 8; ++k) {
      const int kk = (k + sg2 * 2) & 7;
      f16x4 hv, lv;
      #pragma unroll
      for (int u = 0; u < 4; ++u) {
        const float val = o[k * 4 + u];
        hv[u] = (f16)val;
        lv[u] = (f16)(val - (float)hv[u]);
      }
      *(f16x4*)(oh + prow * 1024 + cbase + kk * 4) = hv;
      *(f16x4*)(ol + prow * 1024 + cbase + kk * 4) = lv;
    }
    __syncthreads();
  }
}

// ---------------------------------------------------------------------------
// weight transposes fp32 -> f16 (optional lo plane); batched over blockIdx.z
// ---------------------------------------------------------------------------
template<int SPLIT>
__global__ __launch_bounds__(256)
void transpose_kernel(const float* __restrict__ in, int R, int Cc,
                      f16* __restrict__ oh, f16* __restrict__ ol) {
  __shared__ float tile[32][33];
  const size_t mat = (size_t)blockIdx.z * R * Cc;
  in += mat; oh += mat; if (SPLIT) ol += mat;
  const int tx = threadIdx.x & 31, ty = threadIdx.x >> 5;
  const int c = blockIdx.x * 32 + tx;
  #pragma unroll
  for (int j = 0; j < 32; j += 8) {
    const int r = blockIdx.y * 32 + ty + j;
    tile[ty + j][tx] = in[(size_t)r * Cc + c];
  }
  __syncthreads();
  const int rT = blockIdx.y * 32 + tx;
  #pragma unroll
  for (int j = 0; j < 32; j += 8) {
    const int cT = blockIdx.x * 32 + ty + j;
    const float v = tile[tx][ty + j];
    const f16 hv = (f16)v;
    oh[(size_t)cT * R + rT] = hv;
    if (SPLIT) ol[(size_t)cT * R + rT] = (f16)(v - (float)hv);
  }
}

// conv weights [O,I,3] -> BT[o][tap*1024+i] hi/lo
__global__ __launch_bounds__(256)
void convw_kernel(const float* __restrict__ w, f16* __restrict__ oh, f16* __restrict__ ol) {
  const int id = blockIdx.x * 256 + threadIdx.x;  // 1024*1024
  const int o = id >> 10, i = id & 1023;
  const float* ws = w + (size_t)o * 3072 + i * 3;
  #pragma unroll
  for (int tap = 0; tap < 3; ++tap) {
    const float v = ws[tap];
    const f16 hv = (f16)v;
    const size_t oi = (size_t)o * 3072 + tap * 1024 + i;
    oh[oi] = hv;
    ol[oi] = (f16)(v - (float)hv);
  }
}

__global__ void qkvrows_kernel(int* __restrict__ rows) {
  const int r = blockIdx.x * 256 + threadIdx.x;
  if (r < 4352) rows[r] = (r >= 2176) ? (4096 + r - 2176) : r;
}

// ---------------------------------------------------------------------------
// gate: one wave per token; fp32 logits from fp32 LN3 (selection fidelity)
// ---------------------------------------------------------------------------
__global__ __launch_bounds__(256)
void gate_kernel(const float* __restrict__ ln3f, const float* __restrict__ gW,
                 const float* __restrict__ gb, float* __restrict__ top2p,
                 int* __restrict__ top2i, float* __restrict__ ent, int* __restrict__ counts) {
  const int token = (blockIdx.x << 2) + (threadIdx.x >> 6);
  const int lane = threadIdx.x & 63;
  const float* xr = ln3f + (size_t)token * 1024 + lane * 16;
  float lg[8];
  #pragma unroll
  for (int e = 0; e < 8; ++e) lg[e] = 0.0f;
  #pragma unroll
  for (int u = 0; u < 4; ++u) {
    const float4 xv = *(const float4*)(xr + u * 4);
    const float* gr = gW + (size_t)(lane * 16 + u * 4) * 8;
    float xa[4] = {xv.x, xv.y, xv.z, xv.w};
    #pragma unroll
    for (int qq = 0; qq < 4; ++qq)
      #pragma unroll
      for (int e = 0; e < 8; ++e) lg[e] += xa[qq] * gr[qq * 8 + e];
  }
  #pragma unroll
  for (int m = 1; m < 64; m <<= 1)
    #pragma unroll
    for (int e = 0; e < 8; ++e) lg[e] += __shfl_xor(lg[e], m, 64);
  if (lane == 0) {
    #pragma unroll
    for (int e = 0; e < 8; ++e) lg[e] += gb[e];
    int i0 = 0; float v0 = lg[0];
    #pragma unroll
    for (int e = 1; e < 8; ++e) if (lg[e] > v0) { v0 = lg[e]; i0 = e; }
    int i1 = 0; float v1 = -1e30f;
    #pragma unroll
    for (int e = 0; e < 8; ++e) if (e != i0 && lg[e] > v1) { v1 = lg[e]; i1 = e; }
    float den = 0.0f; float pr[8];
    #pragma unroll
    for (int e = 0; e < 8; ++e) { pr[e] = expf(lg[e] - v0); den += pr[e]; }
    const float dinv = 1.0f / den;
    float H = 0.0f, p0 = 0.0f, p1 = 0.0f;
    #pragma unroll
    for (int e = 0; e < 8; ++e) {
      const float p = pr[e] * dinv;
      H -= p * logf(p + 1e-10f);
      if (e == i0) p0 = p;
      if (e == i1) p1 = p;
    }
    ent[token] = H;
    top2p[token * 2] = p0; top2p[token * 2 + 1] = p1;
    top2i[token * 2] = i0; top2i[token * 2 + 1] = i1;
    atomicAdd(&counts[i0], 1);
    atomicAdd(&counts[i1], 1);
  }
}

// scan: entropy mean (fixed order), offsets, aux, tile table
__global__ __launch_bounds__(256)
void scan_kernel(const float* __restrict__ ent, const int* __restrict__ counts,
                 int* __restrict__ offs, TileInfo* __restrict__ table, float* __restrict__ auxout) {
  __shared__ float red[256];
  const int t = threadIdx.x;
  float s = 0.0f;
  for (int k = 0; k < 32; ++k) s += ent[t + (k << 8)];
  red[t] = s; __syncthreads();
  for (int hh = 128; hh > 0; hh >>= 1) { if (t < hh) red[t] += red[t + hh]; __syncthreads(); }
  if (t == 0) {
    const float entmean = red[0] * (1.0f / 8192.0f);
    float pen = 0.0f; int off = 0; int nt = 0;
    for (int e = 0; e < 8; ++e) {
      const int c = counts[e];
      offs[e] = off;
      for (int m = 0; m < c; m += 128) {
        table[nt].m0 = off + m;
        table[nt].mcnt = (c - m < 128) ? (c - m) : 128;
        table[nt].e = e; table[nt].pad = 0;
        ++nt;
      }
      off += c;
      const float fr = (float)c * (1.0f / 8192.0f) - 0.3f;
      pen += (fr > 0.0f) ? fr : 0.0f;
    }
    for (; nt < 160; ++nt) { table[nt].m0 = 0; table[nt].mcnt = 0; table[nt].e = 0; table[nt].pad = 0; }
    auxout[0] = 0.1f * entmean + pen;
  }
}

__global__ void scatter_kernel(const int* __restrict__ top2i, const int* __restrict__ offs,
                               int* __restrict__ fill, int* __restrict__ moe_rows,
                               int* __restrict__ row2slot) {
  const int id = blockIdx.x * 256 + threadIdx.x;  // 16384
  const int e = top2i[id];
  const int slot = atomicAdd(&fill[e], 1);
  const int row = offs[e] + slot;
  moe_rows[row] = id >> 1;
  row2slot[id] = row;
}

// x3 = x2 + p0*eo[r0] + p1*eo[r1]; also f16 copy for FF1
__global__ __launch_bounds__(256)
void combine_kernel(const float* __restrict__ x2, const f16* __restrict__ eo,
                    const float* __restrict__ top2p, const int* __restrict__ row2slot,
                    float* __restrict__ x3, f16* __restrict__ x3h) {
  const int n = blockIdx.x;
  const int t = threadIdx.x;
  const int r0 = row2slot[n * 2], r1 = row2slot[n * 2 + 1];
  const float p0 = top2p[n * 2], p1 = top2p[n * 2 + 1];
  const float4 xv = ((const float4*)(x2 + (size_t)n * 1024))[t];
  const f16x4 e0 = ((const f16x4*)(eo + (size_t)r0 * 1024))[t];
  const f16x4 e1 = ((const f16x4*)(eo + (size_t)r1 * 1024))[t];
  float4 o;
  o.x = xv.x + p0 * (float)e0[0] + p1 * (float)e1[0];
  o.y = xv.y + p0 * (float)e0[1] + p1 * (float)e1[1];
  o.z = xv.z + p0 * (float)e0[2] + p1 * (float)e1[2];
  o.w = xv.w + p0 * (float)e0[3] + p1 * (float)e1[3];
  ((float4*)(x3 + (size_t)n * 1024))[t] = o;
  f16x4 hv; hv[0] = (f16)o.x; hv[1] = (f16)o.y; hv[2] = (f16)o.z; hv[3] = (f16)o.w;
  ((f16x4*)(x3h + (size_t)n * 1024))[t] = hv;
}

// ---------------------------------------------------------------------------
extern "C" void kernel_launch(void* const* d_in, const int* in_sizes, int n_in,
                              void* d_out, int out_size, void* d_ws, size_t ws_size,
                              hipStream_t stream) {
  (void)in_sizes; (void)n_in; (void)out_size; (void)ws_size;
  const float* x     = (const float*)d_in[0];
  const float* g1    = (const float*)d_in[1];
  const float* b1    = (const float*)d_in[2];
  const float* g2    = (const float*)d_in[3];
  const float* b2    = (const float*)d_in[4];
  const float* g3    = (const float*)d_in[5];
  const float* b3    = (const float*)d_in[6];
  const float* Wqkv  = (const float*)d_in[7];
  const float* bqkv  = (const float*)d_in[8];
  const float* Wo    = (const float*)d_in[9];
  const float* bo    = (const float*)d_in[10];
  const float* convw = (const float*)d_in[11];
  const float* convb = (const float*)d_in[12];
  const float* gateW = (const float*)d_in[13];
  const float* gateb = (const float*)d_in[14];
  const float* expW  = (const float*)d_in[15];
  const float* expb  = (const float*)d_in[16];
  const float* ffW1  = (const float*)d_in[17];
  const float* ffb1  = (const float*)d_in[18];
  const float* ffW2  = (const float*)d_in[19];
  const float* ffb2  = (const float*)d_in[20];
  float* out = (float*)d_out;

  char* W = (char*)d_ws;
  f16* wqkvT_h = (f16*)(W + 0);
  f16* wqkvT_l = (f16*)(W + 6291456);
  f16* woT_h   = (f16*)(W + 12582912);
  f16* woT_l   = (f16*)(W + 14680064);
  f16* wcvT_h  = (f16*)(W + 16777216);
  f16* wcvT_l  = (f16*)(W + 23068672);
  f16* wexpT   = (f16*)(W + 29360128);
  f16* wff1T   = (f16*)(W + 46137344);
  f16* wff2T   = (f16*)(W + 54525952);
  char* META   = W + 62914560;
  int* counts    = (int*)(META);
  int* fill      = (int*)(META + 32);
  int* offs      = (int*)(META + 64);
  TileInfo* table = (TileInfo*)(META + 128);
  char* zbuf     = META + 3072;          // 1KB zeros (covered by memset below)
  int* qkv_rows  = (int*)(META + 4096);
  float* ent     = (float*)(META + 24576);
  float* top2p   = (float*)(META + 57344);
  int* top2i     = (int*)(META + 122880);
  int* moe_rows  = (int*)(META + 188416);
  int* row2slot  = (int*)(META + 253952);
  char* SA = W + 63963136;    // 32 MB: ln1/ln2 hi|lo ; ln3_hi | x3_hi
  char* SB = W + 97517568;    // 64 MB: qkv f32 -> x2 f32 -> h f16
  char* SC = W + 164626432;   // 32 MB: attn hi|lo -> ln3 f32
  char* SD = W + 198180864;   // 32 MB: x1 f32 -> eo f16
  char* SE = W + 231735296;   // 32 MB: x3 f32

  f16* ln1h = (f16*)SA;            f16* ln1l = (f16*)(SA + 16777216);
  f16* ln2h = ln1h;                f16* ln2l = ln1l;
  f16* ln3h = ln1h;                f16* x3h  = (f16*)(SA + 16777216);
  float* qkvbuf = (float*)SB;
  float* x2buf  = (float*)SB;
  f16*   hbuf   = (f16*)SB;
  f16* attnh = (f16*)SC;           f16* attnl = (f16*)(SC + 16777216);
  float* ln3f = (float*)SC;
  float* x1 = (float*)SD;
  f16* eobuf = (f16*)SD;
  float* x3 = (float*)SE;

  // zero: counts(32) + fill(32) + zbuf(@3072..4096); single memset covers 0..4096
  hipMemsetAsync((void*)META, 0, 4096, stream);

  dim3 blk(256);
  // weight prep
  transpose_kernel<1><<<dim3(96, 32, 1), blk, 0, stream>>>(Wqkv, 1024, 3072, wqkvT_h, wqkvT_l);
  transpose_kernel<1><<<dim3(32, 32, 1), blk, 0, stream>>>(Wo, 1024, 1024, woT_h, woT_l);
  convw_kernel<<<4096, blk, 0, stream>>>(convw, wcvT_h, wcvT_l);
  transpose_kernel<0><<<dim3(32, 32, 8), blk, 0, stream>>>(expW, 1024, 1024, wexpT, nullptr);
  transpose_kernel<0><<<dim3(128, 32, 1), blk, 0, stream>>>(ffW1, 1024, 4096, wff1T, nullptr);
  transpose_kernel<0><<<dim3(32, 128, 1), blk, 0, stream>>>(ffW2, 4096, 1024, wff2T, nullptr);
  qkvrows_kernel<<<17, blk, 0, stream>>>(qkv_rows);

  // LN1 -> split planes
  ln_kernel<1, 0><<<8192, blk, 0, stream>>>(x, g1, b1, ln1h, ln1l, nullptr);
  // QKV (rows 0..2175 per batch), split GEMM, fp32 out
  gemm_kernel<3, 1, 0><<<dim3(34, 24), blk, 0, stream>>>(ln1h, ln1l, 1024, wqkvT_h, wqkvT_l, 1024,
      bqkv, nullptr, qkvbuf, nullptr, 3072, 1024, qkv_rows, nullptr, nullptr);
  // attention
  attn_kernel<<<512, blk, 0, stream>>>(qkvbuf, attnh, attnl);
  // Wo projection + residual -> x1
  gemm_kernel<3, 0, 1><<<dim3(64, 8), blk, 0, stream>>>(attnh, attnl, 1024, woT_h, woT_l, 1024,
      bo, x, x1, nullptr, 1024, 1024, nullptr, nullptr, nullptr);
  // LN2
  ln_kernel<1, 0><<<8192, blk, 0, stream>>>(x1, g2, b2, ln2h, ln2l, nullptr);
  // conv (3-tap shifted GEMM, exact zero-pad) + residual -> x2
  gemm_kernel<3, 3, 1><<<dim3(64, 8), blk, 0, stream>>>(ln2h, ln2l, 1024, wcvT_h, wcvT_l, 3072,
      convb, x1, x2buf, nullptr, 1024, 3072, nullptr, nullptr, zbuf);
  // LN3 (f16 hi for experts + fp32 for gate)
  ln_kernel<0, 1><<<8192, blk, 0, stream>>>(x2buf, g3, b3, ln3h, nullptr, ln3f);
  // gate / scan / scatter
  gate_kernel<<<2048, blk, 0, stream>>>(ln3f, gateW, gateb, top2p, top2i, ent, counts);
  scan_kernel<<<1, blk, 0, stream>>>(ent, counts, offs, table, out + 8388608);
  scatter_kernel<<<64, blk, 0, stream>>>(top2i, offs, fill, moe_rows, row2slot);
  // grouped expert GEMM -> eo (f16)
  gemm_kernel<1, 2, 2><<<dim3(136, 8), blk, 0, stream>>>(ln3h, nullptr, 1024, wexpT, nullptr, 1024,
      expb, nullptr, nullptr, eobuf, 1024, 1024, moe_rows, table, nullptr);
  // combine -> x3 (+f16)
  combine_kernel<<<8192, blk, 0, stream>>>(x2buf, eobuf, top2p, row2slot, x3, x3h);
  // FF1 (gelu) -> h
  gemm_kernel<1, 0, 3><<<dim3(64, 32), blk, 0, stream>>>(x3h, nullptr, 1024, wff1T, nullptr, 1024,
      ffb1, nullptr, nullptr, hbuf, 4096, 1024, nullptr, nullptr, nullptr);
  // FF2 + residual -> final output
  gemm_kernel<1, 0, 1><<<dim3(64, 8), blk, 0, stream>>>(hbuf, nullptr, 4096, wff2T, nullptr, 4096,
      ffb2, x3, out, nullptr, 1024, 4096, nullptr, nullptr, nullptr);
}

// Round 3
// 976.520 us; speedup vs baseline: 1.7379x; 1.2498x over previous
//
#include <hip/hip_runtime.h>
#include <cmath>

typedef _Float16 f16;
typedef __attribute__((ext_vector_type(8))) _Float16 f16x8;
typedef __attribute__((ext_vector_type(4))) _Float16 f16x4;
typedef __attribute__((ext_vector_type(4))) float f32x4;

struct TileInfo { int m0, mcnt, e, pad; };

__device__ __forceinline__ void gload16(const void* g, void* l) {
  __builtin_amdgcn_global_load_lds((const __attribute__((address_space(1))) void*)g,
                                   (__attribute__((address_space(3))) void*)l, 16, 0, 0);
}

// ---------------------------------------------------------------------------
// Unified GEMM:  C[M,N] = A[M,K] * B[K,N] (+bias, +res, +gelu), B given
// transposed (BT[N,K], row-major).  A/B in f16; NPASS==3 adds lo-planes for
// fp32-faithful results (hh+hl+lh).  MODE: 0 direct, 1 rowmap(A rows),
// 2 tile-table (MoE grouped), 3 conv (3-tap shifted A rows with exact
// zero-padding via zbuf, K=3072).
// EPI: 0 f32=acc+bias; 1 f32=res+acc+bias; 2 f16=acc+bias; 3 f16=gelu(acc+bias)
// ---------------------------------------------------------------------------
template<int NPASS, int MODE, int EPI>
__global__ __launch_bounds__(256)
void gemm_kernel(const f16* __restrict__ Ah, const f16* __restrict__ Al, int lda,
                 const f16* __restrict__ Bh, const f16* __restrict__ Bl, int ldb,
                 const float* __restrict__ bias, const float* __restrict__ res,
                 float* __restrict__ outf, f16* __restrict__ outh, int ldo, int K,
                 const int* __restrict__ rowmap, const TileInfo* __restrict__ table,
                 const char* __restrict__ zbuf) {
  constexpr int BK = (NPASS == 1) ? 64 : 32;
  constexpr int RB = BK * 2;            // bytes per LDS tile row
  constexpr int TB = 128 * RB;          // bytes per tile plane
  constexpr int ROUNDS = TB / 4096;     // staging rounds (256 thr * 16B)
  constexpr int TPR = RB / 16;          // threads per row
  constexpr int RPR = 4096 / RB;        // rows per round
  constexpr int SWM = TPR - 1;          // swizzle mask
  constexpr int LA  = 0;
  constexpr int LAL = (NPASS == 3) ? TB : 0;
  constexpr int LB  = (NPASS == 3) ? 2 * TB : TB;
  constexpr int LBL = (NPASS == 3) ? 3 * TB : 0;

  __shared__ __align__(16) char lds[32768];

  const int tid  = threadIdx.x;
  const int wave = tid >> 6;
  const int lane = tid & 63;

  int m0, mcnt, eidx = 0;
  if (MODE == 2) {
    TileInfo ti = table[blockIdx.x];
    if (ti.mcnt <= 0) return;
    m0 = ti.m0; mcnt = ti.mcnt; eidx = ti.e;
  } else { m0 = blockIdx.x * 128; mcnt = 128; }
  const int n0 = blockIdx.y * 128;

  const f16* Bh_ = Bh;
  const float* bias_ = bias;
  size_t adelta = 0, bdelta = 0;
  if (NPASS == 3) {
    adelta = (size_t)((const char*)Al - (const char*)Ah);
    bdelta = (size_t)((const char*)Bl - (const char*)Bh);
  }
  if (MODE == 2) { Bh_ += ((size_t)eidx << 20); bias_ += eidx * 1024; }

  const int sr    = tid / TPR;
  const int cbyte = (tid % TPR) * 16;

  const char* aSrc[ROUNDS];
  const char* bSrc[ROUNDS];
  int aRowC[ROUNDS]; int aCbs[ROUNDS];
  #pragma unroll
  for (int r = 0; r < ROUNDS; ++r) {
    const int mr  = sr + r * RPR;
    const int cbs = cbyte ^ ((mr & SWM) << 4);
    int gi = m0 + ((mr < mcnt) ? mr : (mcnt - 1));
    if (MODE == 1 || MODE == 2) gi = rowmap[gi];
    if (MODE == 3) { aRowC[r] = gi; aCbs[r] = cbs; aSrc[r] = nullptr; }
    else           { aSrc[r] = (const char*)Ah + (size_t)gi * lda * 2 + cbs; aRowC[r] = 0; aCbs[r] = 0; }
    const int nr   = sr + r * RPR;
    const int ncbs = cbyte ^ ((nr & SWM) << 4);
    bSrc[r] = (const char*)Bh_ + (size_t)(n0 + nr) * ldb * 2 + ncbs;
  }

  f32x4 acc[4][4] = {};
  const int wm  = (wave >> 1) * 64;
  const int wn  = (wave & 1) * 64;
  const int fr  = lane & 15;
  const int kgb = (lane >> 4) * 16;

  for (int k0 = 0; k0 < K; k0 += BK) {
    #pragma unroll
    for (int r = 0; r < ROUNDS; ++r) {
      const char* as;
      const char* asl = nullptr;
      if (MODE == 3) {
        // exact zero-padded dilated-conv taps: tok + 2*(tap-1) within batch
        const int tap = k0 >> 10;
        const int kc  = k0 & 1023;
        const int tok = aRowC[r] & 4095;
        const int st  = tok + (tap - 1) * 2;
        if (st >= 0 && st < 4096) {
          as  = (const char*)Ah + (size_t)(aRowC[r] + (tap - 1) * 2) * 2048 + kc * 2 + aCbs[r];
          asl = as + adelta;
        } else {
          as  = zbuf;   // 16B of zeros (all lanes broadcast-read)
          asl = zbuf;
        }
      } else {
        as = aSrc[r] + (size_t)k0 * 2;
        if (NPASS == 3) asl = as + adelta;
      }
      gload16(as, lds + LA + r * 4096 + wave * 1024);
      if (NPASS == 3) gload16(asl, lds + LAL + r * 4096 + wave * 1024);
      const char* bs = bSrc[r] + (size_t)k0 * 2;
      gload16(bs, lds + LB + r * 4096 + wave * 1024);
      if (NPASS == 3) gload16(bs + bdelta, lds + LBL + r * 4096 + wave * 1024);
    }
    __syncthreads();
    #pragma unroll
    for (int kk = 0; kk < BK / 32; ++kk) {
      f16x8 ah[4], bh[4], al[4], bl[4];
      #pragma unroll
      for (int i = 0; i < 4; ++i) {
        const int ar = wm + i * 16 + fr;
        const int ao = ar * RB + ((kk * 64 + kgb) ^ ((ar & SWM) << 4));
        ah[i] = *(const f16x8*)(lds + LA + ao);
        if (NPASS == 3) al[i] = *(const f16x8*)(lds + LAL + ao);
        const int br = wn + i * 16 + fr;
        const int bo = br * RB + ((kk * 64 + kgb) ^ ((br & SWM) << 4));
        bh[i] = *(const f16x8*)(lds + LB + bo);
        if (NPASS == 3) bl[i] = *(const f16x8*)(lds + LBL + bo);
      }
      #pragma unroll
      for (int i = 0; i < 4; ++i) {
        #pragma unroll
        for (int j = 0; j < 4; ++j) {
          acc[i][j] = __builtin_amdgcn_mfma_f32_16x16x32_f16(ah[i], bh[j], acc[i][j], 0, 0, 0);
          if (NPASS == 3) {
            acc[i][j] = __builtin_amdgcn_mfma_f32_16x16x32_f16(ah[i], bl[j], acc[i][j], 0, 0, 0);
            acc[i][j] = __builtin_amdgcn_mfma_f32_16x16x32_f16(al[i], bh[j], acc[i][j], 0, 0, 0);
          }
        }
      }
    }
    __syncthreads();
  }

  #pragma unroll
  for (int i = 0; i < 4; ++i) {
    const int mb = wm + i * 16 + (lane >> 4) * 4;
    #pragma unroll
    for (int j = 0; j < 4; ++j) {
      const int nc = n0 + wn + j * 16 + fr;
      const float bv = bias_[nc];
      #pragma unroll
      for (int q = 0; q < 4; ++q) {
        const int ml = mb + q;
        if (MODE == 2 && ml >= mcnt) continue;
        const size_t orow = (size_t)(m0 + ml);
        float v = acc[i][j][q] + bv;
        if (EPI == 1) v += res[orow * ldo + nc];
        if (EPI == 3) v = 0.5f * v * (1.0f + erff(v * 0.70710678118654752440f));
        if (EPI <= 1) outf[orow * ldo + nc] = v;
        else          outh[orow * ldo + nc] = (f16)v;
      }
    }
  }
}

// ---------------------------------------------------------------------------
// LayerNorm: fp32 in -> f16 hi (+optional lo plane). WGATE: fuse gate-logit
// partials (y . gW[:,e]) with wave+LDS reduction -> logits[row][8] fp32.
// ---------------------------------------------------------------------------
template<int WLO, int WGATE>
__global__ __launch_bounds__(256)
void ln_kernel(const float* __restrict__ x, const float* __restrict__ g, const float* __restrict__ b,
               f16* __restrict__ oh, f16* __restrict__ ol,
               const float* __restrict__ gW, const float* __restrict__ gb,
               float* __restrict__ logits) {
  const int row = blockIdx.x;
  const int t = threadIdx.x;
  const float4 v = ((const float4*)(x + (size_t)row * 1024))[t];
  float s  = v.x + v.y + v.z + v.w;
  float ss = v.x * v.x + v.y * v.y + v.z * v.z + v.w * v.w;
  #pragma unroll
  for (int off = 32; off; off >>= 1) { s += __shfl_down(s, off, 64); ss += __shfl_down(ss, off, 64); }
  __shared__ float red[8];
  if ((t & 63) == 0) { red[t >> 6] = s; red[(t >> 6) + 4] = ss; }
  __syncthreads();
  s  = red[0] + red[1] + red[2] + red[3];
  ss = red[4] + red[5] + red[6] + red[7];
  const float mu  = s * (1.0f / 1024.0f);
  const float var = ss * (1.0f / 1024.0f) - mu * mu;
  const float inv = 1.0f / sqrtf(var + 1e-5f);
  const float4 gv = ((const float4*)g)[t];
  const float4 bv = ((const float4*)b)[t];
  float y[4];
  y[0] = (v.x - mu) * inv * gv.x + bv.x;
  y[1] = (v.y - mu) * inv * gv.y + bv.y;
  y[2] = (v.z - mu) * inv * gv.z + bv.z;
  y[3] = (v.w - mu) * inv * gv.w + bv.w;
  f16x4 hv;
  #pragma unroll
  for (int u = 0; u < 4; ++u) hv[u] = (f16)y[u];
  *(f16x4*)(oh + (size_t)row * 1024 + t * 4) = hv;
  if (WLO) {
    f16x4 lv;
    #pragma unroll
    for (int u = 0; u < 4; ++u) lv[u] = (f16)(y[u] - (float)hv[u]);
    *(f16x4*)(ol + (size_t)row * 1024 + t * 4) = lv;
  }
  if (WGATE) {
    const float* gr = gW + (size_t)(t * 4) * 8;
    float lg[8];
    #pragma unroll
    for (int e = 0; e < 8; ++e)
      lg[e] = y[0] * gr[e] + y[1] * gr[8 + e] + y[2] * gr[16 + e] + y[3] * gr[24 + e];
    #pragma unroll
    for (int m = 1; m < 64; m <<= 1)
      #pragma unroll
      for (int e = 0; e < 8; ++e) lg[e] += __shfl_xor(lg[e], m, 64);
    __shared__ float gred[4][8];
    if ((t & 63) == 0) {
      #pragma unroll
      for (int e = 0; e < 8; ++e) gred[t >> 6][e] = lg[e];
    }
    __syncthreads();
    if (t < 8)
      logits[(size_t)row * 8 + t] = gred[0][t] + gred[1][t] + gred[2][t] + gred[3][t] + gb[t];
  }
}

// ---------------------------------------------------------------------------
// Windowed "attention" (faithful to unfold bug): per (b,h,n<16):
// A[d][e]=softmax_e( (1/8) sum_s q[s,d]k[s,e] ), O[d][s]=sum_e A[d][e] v[s,e]
// output row n*256+d*4+(s>>6), channel h*64+(s&63).  All fp32.
// ---------------------------------------------------------------------------
__global__ __launch_bounds__(256)
void attn_kernel(const float* __restrict__ qkv, f16* __restrict__ oh, f16* __restrict__ ol) {
  __shared__ __align__(16) char sm[65536];
  const int bid = blockIdx.x;
  const int b = bid >> 8, h = (bid >> 4) & 15, n = bid & 15;
  const int t = threadIdx.x;
  const size_t rowbase = (size_t)(b * 2176 + n * 128);
  const float* qb = qkv + rowbase * 3072 + h * 64;
  const float* kb = qb + 1024;
  const float* vb = qb + 2048;

  const int dq = t >> 2;       // score row (hd)
  const int eg = t & 3;        // score col group
  float pacc[16];
  #pragma unroll
  for (int u = 0; u < 16; ++u) pacc[u] = 0.0f;

  const int ld0 = (t & 15) * 4;
  const int ls0 = t >> 4;

  // ---- QK over two s-chunks of 128 ----
  for (int cs = 0; cs < 2; ++cs) {
    for (int rr = 0; rr < 8; ++rr) {
      const int sp = ls0 + rr * 16;
      const int s  = cs * 128 + sp;
      const float4 qv = *(const float4*)(qb + (size_t)s * 3072 + ld0);
      const float4 kv = *(const float4*)(kb + (size_t)s * 3072 + ld0);
      float qa[4] = {qv.x, qv.y, qv.z, qv.w};
      float ka[4] = {kv.x, kv.y, kv.z, kv.w};
      #pragma unroll
      for (int j = 0; j < 4; ++j) {
        const int d = ld0 + j;
        const int off = d * 512 + ((sp * 4) ^ ((d & 7) << 4));
        *(float*)(sm + off) = qa[j];
        *(float*)(sm + 32768 + off) = ka[j];
      }
    }
    __syncthreads();
    for (int sg = 0; sg < 32; ++sg) {
      const f32x4 qv = *(const f32x4*)(sm + dq * 512 + ((sg * 16) ^ ((dq & 7) << 4)));
      #pragma unroll
      for (int j = 0; j < 16; ++j) {
        const int el = (j + eg * 4) & 15;      // address rotation (banks)
        const int e  = eg * 16 + el;
        const f32x4 kv = *(const f32x4*)(sm + 32768 + e * 512 + ((sg * 16) ^ ((e & 7) << 4)));
        pacc[j] += qv[0] * kv[0] + qv[1] * kv[1] + qv[2] * kv[2] + qv[3] * kv[3];
      }
    }
    __syncthreads();
  }

  // ---- softmax over e (row dq lives in 4 adjacent lanes) ----
  float mx = -1e30f;
  #pragma unroll
  for (int u = 0; u < 16; ++u) { pacc[u] *= 0.125f; mx = fmaxf(mx, pacc[u]); }
  mx = fmaxf(mx, __shfl_xor(mx, 1, 4));
  mx = fmaxf(mx, __shfl_xor(mx, 2, 4));
  float den = 0.0f;
  #pragma unroll
  for (int u = 0; u < 16; ++u) { pacc[u] = expf(pacc[u] - mx); den += pacc[u]; }
  den += __shfl_xor(den, 1, 4);
  den += __shfl_xor(den, 2, 4);
  const float dinv = 1.0f / den;
  #pragma unroll
  for (int u = 0; u < 16; ++u) pacc[u] *= dinv;

  // ---- PV over two s-chunks; P fetched cross-lane via shfl ----
  const int sg2 = t & 3;
  for (int vs = 0; vs < 2; ++vs) {
    for (int rr = 0; rr < 8; ++rr) {
      const int sp = ls0 + rr * 16;
      const int s  = vs * 128 + sp;
      const float4 vv = *(const float4*)(vb + (size_t)s * 3072 + ld0);
      float va[4] = {vv.x, vv.y, vv.z, vv.w};
      #pragma unroll
      for (int j = 0; j < 4; ++j) {
        const int e = ld0 + j;
        const int off = e * 512 + ((sp * 4) ^ ((e & 7) << 4));
        *(float*)(sm + 32768 + off) = va[j];
      }
    }
    __syncthreads();
    float o[32];
    #pragma unroll
    for (int u = 0; u < 32; ++u) o[u] = 0.0f;
    #pragma unroll
    for (int e = 0; e < 64; ++e) {
      const int jreg = ((e & 15) - ((e >> 4) << 2)) & 15;   // register of P[dq][e] in src lane
      const float p = __shfl(pacc[jreg], (t & 60) + (e >> 4), 64);
      #pragma unroll
      for (int k = 0; k < 8; ++k) {
        const int kk = (k + sg2 * 2) & 7;                   // address rotation
        const f32x4 vv = *(const f32x4*)(sm + 32768 + e * 512 + (((sg2 * 128) + kk * 16) ^ ((e & 7) << 4)));
        o[k * 4 + 0] += p * vv[0];
        o[k * 4 + 1] += p * vv[1];
        o[k * 4 + 2] += p * vv[2];
        o[k * 4 + 3] += p * vv[3];
      }
    }
    // write: row = b*4096 + n*256 + dq*4 + vs*2 + (sg2>>1); ch = h*64 + (sg2&1)*32 + kk*4+u
    const size_t prow = (size_t)(b * 4096 + n * 256 + dq * 4 + vs * 2 + (sg2 >> 1));
    const int cbase = h * 64 + (sg2 & 1) * 32;
    #pragma unroll
    for (int k = 0; k < 8; ++k) {
      const int kk = (k + sg2 * 2) & 7;
      f16x4 hv, lv;
      #pragma unroll
      for (int u = 0; u < 4; ++u) {
        const float val = o[k * 4 + u];
        hv[u] = (f16)val;
        lv[u] = (f16)(val - (float)hv[u]);
      }
      *(f16x4*)(oh + prow * 1024 + cbase + kk * 4) = hv;
      *(f16x4*)(ol + prow * 1024 + cbase + kk * 4) = lv;
    }
    __syncthreads();
  }
}

// ---------------------------------------------------------------------------
// weight transposes fp32 -> f16 (optional lo plane); batched over blockIdx.z
// ---------------------------------------------------------------------------
template<int SPLIT>
__global__ __launch_bounds__(256)
void transpose_kernel(const float* __restrict__ in, int R, int Cc,
                      f16* __restrict__ oh, f16* __restrict__ ol) {
  __shared__ float tile[32][33];
  const size_t mat = (size_t)blockIdx.z * R * Cc;
  in += mat; oh += mat; if (SPLIT) ol += mat;
  const int tx = threadIdx.x & 31, ty = threadIdx.x >> 5;
  const int c = blockIdx.x * 32 + tx;
  #pragma unroll
  for (int j = 0; j < 32; j += 8) {
    const int r = blockIdx.y * 32 + ty + j;
    tile[ty + j][tx] = in[(size_t)r * Cc + c];
  }
  __syncthreads();
  const int rT = blockIdx.y * 32 + tx;
  #pragma unroll
  for (int j = 0; j < 32; j += 8) {
    const int cT = blockIdx.x * 32 + ty + j;
    const float v = tile[tx][ty + j];
    const f16 hv = (f16)v;
    oh[(size_t)cT * R + rT] = hv;
    if (SPLIT) ol[(size_t)cT * R + rT] = (f16)(v - (float)hv);
  }
}

// conv weights [O,I,3] -> BT[o][tap*1024+i] hi/lo
__global__ __launch_bounds__(256)
void convw_kernel(const float* __restrict__ w, f16* __restrict__ oh, f16* __restrict__ ol) {
  const int id = blockIdx.x * 256 + threadIdx.x;  // 1024*1024
  const int o = id >> 10, i = id & 1023;
  const float* ws = w + (size_t)o * 3072 + i * 3;
  #pragma unroll
  for (int tap = 0; tap < 3; ++tap) {
    const float v = ws[tap];
    const f16 hv = (f16)v;
    const size_t oi = (size_t)o * 3072 + tap * 1024 + i;
    oh[oi] = hv;
    ol[oi] = (f16)(v - (float)hv);
  }
}

__global__ void qkvrows_kernel(int* __restrict__ rows) {
  const int r = blockIdx.x * 256 + threadIdx.x;
  if (r < 4352) rows[r] = (r >= 2176) ? (4096 + r - 2176) : r;
}

// ---------------------------------------------------------------------------
// gate finalize: per-token top-2/softmax/entropy from fused logits; counts
// via LDS histogram + 8 global atomics per block (contention fix).
// ---------------------------------------------------------------------------
__global__ __launch_bounds__(256)
void gatefin_kernel(const float* __restrict__ logits, float* __restrict__ top2p,
                    int* __restrict__ top2i, float* __restrict__ ent,
                    int* __restrict__ counts) {
  __shared__ int hist[8];
  const int t = threadIdx.x;
  if (t < 8) hist[t] = 0;
  __syncthreads();
  const int token = blockIdx.x * 256 + t;
  float lg[8];
  const float4 l0 = ((const float4*)(logits + (size_t)token * 8))[0];
  const float4 l1 = ((const float4*)(logits + (size_t)token * 8))[1];
  lg[0] = l0.x; lg[1] = l0.y; lg[2] = l0.z; lg[3] = l0.w;
  lg[4] = l1.x; lg[5] = l1.y; lg[6] = l1.z; lg[7] = l1.w;
  int i0 = 0; float v0 = lg[0];
  #pragma unroll
  for (int e = 1; e < 8; ++e) if (lg[e] > v0) { v0 = lg[e]; i0 = e; }
  int i1 = 0; float v1 = -1e30f;
  #pragma unroll
  for (int e = 0; e < 8; ++e) if (e != i0 && lg[e] > v1) { v1 = lg[e]; i1 = e; }
  float den = 0.0f; float pr[8];
  #pragma unroll
  for (int e = 0; e < 8; ++e) { pr[e] = expf(lg[e] - v0); den += pr[e]; }
  const float dinv = 1.0f / den;
  float H = 0.0f, p0 = 0.0f, p1 = 0.0f;
  #pragma unroll
  for (int e = 0; e < 8; ++e) {
    const float p = pr[e] * dinv;
    H -= p * logf(p + 1e-10f);
    if (e == i0) p0 = p;
    if (e == i1) p1 = p;
  }
  ent[token] = H;
  top2p[token * 2] = p0; top2p[token * 2 + 1] = p1;
  top2i[token * 2] = i0; top2i[token * 2 + 1] = i1;
  atomicAdd(&hist[i0], 1);
  atomicAdd(&hist[i1], 1);
  __syncthreads();
  if (t < 8) atomicAdd(&counts[t], hist[t]);
}

// scan: entropy mean (fixed order), offsets, aux, tile table
__global__ __launch_bounds__(256)
void scan_kernel(const float* __restrict__ ent, const int* __restrict__ counts,
                 int* __restrict__ offs, TileInfo* __restrict__ table, float* __restrict__ auxout) {
  __shared__ float red[256];
  const int t = threadIdx.x;
  float s = 0.0f;
  for (int k = 0; k < 32; ++k) s += ent[t + (k << 8)];
  red[t] = s; __syncthreads();
  for (int hh = 128; hh > 0; hh >>= 1) { if (t < hh) red[t] += red[t + hh]; __syncthreads(); }
  if (t == 0) {
    const float entmean = red[0] * (1.0f / 8192.0f);
    float pen = 0.0f; int off = 0; int nt = 0;
    for (int e = 0; e < 8; ++e) {
      const int c = counts[e];
      offs[e] = off;
      for (int m = 0; m < c; m += 128) {
        table[nt].m0 = off + m;
        table[nt].mcnt = (c - m < 128) ? (c - m) : 128;
        table[nt].e = e; table[nt].pad = 0;
        ++nt;
      }
      off += c;
      const float fr = (float)c * (1.0f / 8192.0f) - 0.3f;
      pen += (fr > 0.0f) ? fr : 0.0f;
    }
    for (; nt < 160; ++nt) { table[nt].m0 = 0; table[nt].mcnt = 0; table[nt].e = 0; table[nt].pad = 0; }
    auxout[0] = 0.1f * entmean + pen;
  }
}

// scatter: block-local LDS ranks + one chunk-reservation atomic per expert
__global__ __launch_bounds__(256)
void scatter_kernel(const int* __restrict__ top2i, const int* __restrict__ offs,
                    int* __restrict__ fill, int* __restrict__ moe_rows,
                    int* __restrict__ row2slot) {
  __shared__ int hist[8];
  __shared__ int base[8];
  const int t = threadIdx.x;
  if (t < 8) hist[t] = 0;
  __syncthreads();
  const int id = blockIdx.x * 256 + t;  // 16384
  const int e = top2i[id];
  const int myrank = atomicAdd(&hist[e], 1);
  __syncthreads();
  if (t < 8) base[t] = atomicAdd(&fill[t], hist[t]);
  __syncthreads();
  const int row = offs[e] + base[e] + myrank;
  moe_rows[row] = id >> 1;
  row2slot[id] = row;
}

// x3 = x2 + p0*eo[r0] + p1*eo[r1]; also f16 copy for FF1
__global__ __launch_bounds__(256)
void combine_kernel(const float* __restrict__ x2, const f16* __restrict__ eo,
                    const float* __restrict__ top2p, const int* __restrict__ row2slot,
                    float* __restrict__ x3, f16* __restrict__ x3h) {
  const int n = blockIdx.x;
  const int t = threadIdx.x;
  const int r0 = row2slot[n * 2], r1 = row2slot[n * 2 + 1];
  const float p0 = top2p[n * 2], p1 = top2p[n * 2 + 1];
  const float4 xv = ((const float4*)(x2 + (size_t)n * 1024))[t];
  const f16x4 e0 = ((const f16x4*)(eo + (size_t)r0 * 1024))[t];
  const f16x4 e1 = ((const f16x4*)(eo + (size_t)r1 * 1024))[t];
  float4 o;
  o.x = xv.x + p0 * (float)e0[0] + p1 * (float)e1[0];
  o.y = xv.y + p0 * (float)e0[1] + p1 * (float)e1[1];
  o.z = xv.z + p0 * (float)e0[2] + p1 * (float)e1[2];
  o.w = xv.w + p0 * (float)e0[3] + p1 * (float)e1[3];
  ((float4*)(x3 + (size_t)n * 1024))[t] = o;
  f16x4 hv; hv[0] = (f16)o.x; hv[1] = (f16)o.y; hv[2] = (f16)o.z; hv[3] = (f16)o.w;
  ((f16x4*)(x3h + (size_t)n * 1024))[t] = hv;
}

// ---------------------------------------------------------------------------
extern "C" void kernel_launch(void* const* d_in, const int* in_sizes, int n_in,
                              void* d_out, int out_size, void* d_ws, size_t ws_size,
                              hipStream_t stream) {
  (void)in_sizes; (void)n_in; (void)out_size; (void)ws_size;
  const float* x     = (const float*)d_in[0];
  const float* g1    = (const float*)d_in[1];
  const float* b1    = (const float*)d_in[2];
  const float* g2    = (const float*)d_in[3];
  const float* b2    = (const float*)d_in[4];
  const float* g3    = (const float*)d_in[5];
  const float* b3    = (const float*)d_in[6];
  const float* Wqkv  = (const float*)d_in[7];
  const float* bqkv  = (const float*)d_in[8];
  const float* Wo    = (const float*)d_in[9];
  const float* bo    = (const float*)d_in[10];
  const float* convw = (const float*)d_in[11];
  const float* convb = (const float*)d_in[12];
  const float* gateW = (const float*)d_in[13];
  const float* gateb = (const float*)d_in[14];
  const float* expW  = (const float*)d_in[15];
  const float* expb  = (const float*)d_in[16];
  const float* ffW1  = (const float*)d_in[17];
  const float* ffb1  = (const float*)d_in[18];
  const float* ffW2  = (const float*)d_in[19];
  const float* ffb2  = (const float*)d_in[20];
  float* out = (float*)d_out;

  char* W = (char*)d_ws;
  f16* wqkvT_h = (f16*)(W + 0);
  f16* wqkvT_l = (f16*)(W + 6291456);
  f16* woT_h   = (f16*)(W + 12582912);
  f16* woT_l   = (f16*)(W + 14680064);
  f16* wcvT_h  = (f16*)(W + 16777216);
  f16* wcvT_l  = (f16*)(W + 23068672);
  f16* wexpT   = (f16*)(W + 29360128);
  f16* wff1T   = (f16*)(W + 46137344);
  f16* wff2T   = (f16*)(W + 54525952);
  char* META   = W + 62914560;
  int* counts    = (int*)(META);
  int* fill      = (int*)(META + 32);
  int* offs      = (int*)(META + 64);
  TileInfo* table = (TileInfo*)(META + 128);
  char* zbuf     = META + 3072;          // 1KB zeros (covered by memset below)
  int* qkv_rows  = (int*)(META + 4096);
  float* ent     = (float*)(META + 24576);
  float* top2p   = (float*)(META + 57344);
  int* top2i     = (int*)(META + 122880);
  int* moe_rows  = (int*)(META + 188416);
  int* row2slot  = (int*)(META + 253952);
  float* logits  = (float*)(META + 327680);   // 8192*8 f32 = 256KB
  char* SA = W + 63963136;    // 32 MB: ln1/ln2 hi|lo ; ln3_hi | x3_hi
  char* SB = W + 97517568;    // 64 MB: qkv f32 -> x2 f32 -> h f16
  char* SC = W + 164626432;   // 32 MB: attn hi|lo
  char* SD = W + 198180864;   // 32 MB: x1 f32 -> eo f16
  char* SE = W + 231735296;   // 32 MB: x3 f32

  f16* ln1h = (f16*)SA;            f16* ln1l = (f16*)(SA + 16777216);
  f16* ln2h = ln1h;                f16* ln2l = ln1l;
  f16* ln3h = ln1h;                f16* x3h  = (f16*)(SA + 16777216);
  float* qkvbuf = (float*)SB;
  float* x2buf  = (float*)SB;
  f16*   hbuf   = (f16*)SB;
  f16* attnh = (f16*)SC;           f16* attnl = (f16*)(SC + 16777216);
  float* x1 = (float*)SD;
  f16* eobuf = (f16*)SD;
  float* x3 = (float*)SE;

  // zero: counts(32) + fill(32) + zbuf(@3072..4096); single memset covers 0..4096
  hipMemsetAsync((void*)META, 0, 4096, stream);

  dim3 blk(256);
  // weight prep
  transpose_kernel<1><<<dim3(96, 32, 1), blk, 0, stream>>>(Wqkv, 1024, 3072, wqkvT_h, wqkvT_l);
  transpose_kernel<1><<<dim3(32, 32, 1), blk, 0, stream>>>(Wo, 1024, 1024, woT_h, woT_l);
  convw_kernel<<<4096, blk, 0, stream>>>(convw, wcvT_h, wcvT_l);
  transpose_kernel<0><<<dim3(32, 32, 8), blk, 0, stream>>>(expW, 1024, 1024, wexpT, nullptr);
  transpose_kernel<0><<<dim3(128, 32, 1), blk, 0, stream>>>(ffW1, 1024, 4096, wff1T, nullptr);
  transpose_kernel<0><<<dim3(32, 128, 1), blk, 0, stream>>>(ffW2, 4096, 1024, wff2T, nullptr);
  qkvrows_kernel<<<17, blk, 0, stream>>>(qkv_rows);

  // LN1 -> split planes
  ln_kernel<1, 0><<<8192, blk, 0, stream>>>(x, g1, b1, ln1h, ln1l, nullptr, nullptr, nullptr);
  // QKV (rows 0..2175 per batch), split GEMM, fp32 out
  gemm_kernel<3, 1, 0><<<dim3(34, 24), blk, 0, stream>>>(ln1h, ln1l, 1024, wqkvT_h, wqkvT_l, 1024,
      bqkv, nullptr, qkvbuf, nullptr, 3072, 1024, qkv_rows, nullptr, nullptr);
  // attention
  attn_kernel<<<512, blk, 0, stream>>>(qkvbuf, attnh, attnl);
  // Wo projection + residual -> x1
  gemm_kernel<3, 0, 1><<<dim3(64, 8), blk, 0, stream>>>(attnh, attnl, 1024, woT_h, woT_l, 1024,
      bo, x, x1, nullptr, 1024, 1024, nullptr, nullptr, nullptr);
  // LN2
  ln_kernel<1, 0><<<8192, blk, 0, stream>>>(x1, g2, b2, ln2h, ln2l, nullptr, nullptr, nullptr);
  // conv (3-tap shifted GEMM, exact zero-pad) + residual -> x2
  gemm_kernel<3, 3, 1><<<dim3(64, 8), blk, 0, stream>>>(ln2h, ln2l, 1024, wcvT_h, wcvT_l, 3072,
      convb, x1, x2buf, nullptr, 1024, 3072, nullptr, nullptr, zbuf);
  // LN3 fused with gate logits (f16 hi for experts + logits for routing)
  ln_kernel<0, 1><<<8192, blk, 0, stream>>>(x2buf, g3, b3, ln3h, nullptr, gateW, gateb, logits);
  // gate finalize / scan / scatter
  gatefin_kernel<<<32, blk, 0, stream>>>(logits, top2p, top2i, ent, counts);
  scan_kernel<<<1, blk, 0, stream>>>(ent, counts, offs, table, out + 8388608);
  scatter_kernel<<<64, blk, 0, stream>>>(top2i, offs, fill, moe_rows, row2slot);
  // grouped expert GEMM -> eo (f16)
  gemm_kernel<1, 2, 2><<<dim3(136, 8), blk, 0, stream>>>(ln3h, nullptr, 1024, wexpT, nullptr, 1024,
      expb, nullptr, nullptr, eobuf, 1024, 1024, moe_rows, table, nullptr);
  // combine -> x3 (+f16)
  combine_kernel<<<8192, blk, 0, stream>>>(x2buf, eobuf, top2p, row2slot, x3, x3h);
  // FF1 (gelu) -> h
  gemm_kernel<1, 0, 3><<<dim3(64, 32), blk, 0, stream>>>(x3h, nullptr, 1024, wff1T, nullptr, 1024,
      ffb1, nullptr, nullptr, hbuf, 4096, 1024, nullptr, nullptr, nullptr);
  // FF2 + residual -> final output
  gemm_kernel<1, 0, 1><<<dim3(64, 8), blk, 0, stream>>>(hbuf, nullptr, 4096, wff2T, nullptr, 4096,
      ffb2, x3, out, nullptr, 1024, 4096, nullptr, nullptr, nullptr);
}

// Round 4
// 949.425 us; speedup vs baseline: 1.7875x; 1.0285x over previous
//
#include <hip/hip_runtime.h>
#include <cmath>

typedef _Float16 f16;
typedef __attribute__((ext_vector_type(8))) _Float16 f16x8;
typedef __attribute__((ext_vector_type(4))) _Float16 f16x4;
typedef __attribute__((ext_vector_type(4))) float f32x4;

struct TileInfo { int m0, mcnt, e, pad; };

__device__ __forceinline__ void gload16(const void* g, void* l) {
  __builtin_amdgcn_global_load_lds((const __attribute__((address_space(1))) void*)g,
                                   (__attribute__((address_space(3))) void*)l, 16, 0, 0);
}

// ---------------------------------------------------------------------------
// Unified GEMM:  C[M,N] = A[M,K] * B[K,N] (+bias, +res, +gelu), B given
// transposed (BT[N,K], row-major).  A/B in f16; NPASS==3 adds lo-planes for
// fp32-faithful results (hh+hl+lh).  MODE: 0 direct, 1 rowmap(A rows),
// 2 tile-table (MoE grouped), 3 conv (3-tap shifted A rows with exact
// zero-padding via zbuf, K=3072).  BK=64 everywhere (1024%64==0 so conv
// tiles never straddle a tap boundary).
// EPI: 0 f32=acc+bias; 1 f32=res+acc+bias; 2 f16=acc+bias; 3 f16=gelu(acc+bias)
// ---------------------------------------------------------------------------
template<int NPASS, int MODE, int EPI>
__global__ __launch_bounds__(256)
void gemm_kernel(const f16* __restrict__ Ah, const f16* __restrict__ Al, int lda,
                 const f16* __restrict__ Bh, const f16* __restrict__ Bl, int ldb,
                 const float* __restrict__ bias, const float* __restrict__ res,
                 float* __restrict__ outf, f16* __restrict__ outh, int ldo, int K,
                 const int* __restrict__ rowmap, const TileInfo* __restrict__ table,
                 const char* __restrict__ zbuf) {
  constexpr int BK = 64;
  constexpr int RB = BK * 2;            // bytes per LDS tile row (128)
  constexpr int TB = 128 * RB;          // bytes per tile plane (16KB)
  constexpr int ROUNDS = TB / 4096;     // staging rounds (4)
  constexpr int TPR = RB / 16;          // threads per row (8)
  constexpr int RPR = 4096 / RB;        // rows per round (32)
  constexpr int SWM = TPR - 1;          // swizzle mask (7)
  constexpr int LA  = 0;
  constexpr int LAL = (NPASS == 3) ? TB : 0;
  constexpr int LB  = (NPASS == 3) ? 2 * TB : TB;
  constexpr int LBL = (NPASS == 3) ? 3 * TB : 0;

  __shared__ __align__(16) char lds[(NPASS == 3) ? 65536 : 32768];

  const int tid  = threadIdx.x;
  const int wave = tid >> 6;
  const int lane = tid & 63;

  int m0, mcnt, eidx = 0;
  if (MODE == 2) {
    TileInfo ti = table[blockIdx.x];
    if (ti.mcnt <= 0) return;
    m0 = ti.m0; mcnt = ti.mcnt; eidx = ti.e;
  } else { m0 = blockIdx.x * 128; mcnt = 128; }
  const int n0 = blockIdx.y * 128;

  const f16* Bh_ = Bh;
  const float* bias_ = bias;
  size_t adelta = 0, bdelta = 0;
  if (NPASS == 3) {
    adelta = (size_t)((const char*)Al - (const char*)Ah);
    bdelta = (size_t)((const char*)Bl - (const char*)Bh);
  }
  if (MODE == 2) { Bh_ += ((size_t)eidx << 20); bias_ += eidx * 1024; }

  const int sr    = tid / TPR;
  const int cbyte = (tid % TPR) * 16;

  const char* aSrc[ROUNDS];
  const char* bSrc[ROUNDS];
  int aRowC[ROUNDS]; int aCbs[ROUNDS];
  #pragma unroll
  for (int r = 0; r < ROUNDS; ++r) {
    const int mr  = sr + r * RPR;
    const int cbs = cbyte ^ ((mr & SWM) << 4);
    int gi = m0 + ((mr < mcnt) ? mr : (mcnt - 1));
    if (MODE == 1 || MODE == 2) gi = rowmap[gi];
    if (MODE == 3) { aRowC[r] = gi; aCbs[r] = cbs; aSrc[r] = nullptr; }
    else           { aSrc[r] = (const char*)Ah + (size_t)gi * lda * 2 + cbs; aRowC[r] = 0; aCbs[r] = 0; }
    const int nr   = sr + r * RPR;
    const int ncbs = cbyte ^ ((nr & SWM) << 4);
    bSrc[r] = (const char*)Bh_ + (size_t)(n0 + nr) * ldb * 2 + ncbs;
  }

  f32x4 acc[4][4] = {};
  const int wm  = (wave >> 1) * 64;
  const int wn  = (wave & 1) * 64;
  const int fr  = lane & 15;
  const int kgb = (lane >> 4) * 16;

  for (int k0 = 0; k0 < K; k0 += BK) {
    #pragma unroll
    for (int r = 0; r < ROUNDS; ++r) {
      const char* as;
      const char* asl = nullptr;
      if (MODE == 3) {
        // exact zero-padded dilated-conv taps: tok + 2*(tap-1) within batch
        const int tap = k0 >> 10;
        const int kc  = k0 & 1023;
        const int tok = aRowC[r] & 4095;
        const int st  = tok + (tap - 1) * 2;
        if (st >= 0 && st < 4096) {
          as  = (const char*)Ah + (size_t)(aRowC[r] + (tap - 1) * 2) * 2048 + kc * 2 + aCbs[r];
          asl = as + adelta;
        } else {
          as  = zbuf;   // 16B of zeros (all lanes broadcast-read)
          asl = zbuf;
        }
      } else {
        as = aSrc[r] + (size_t)k0 * 2;
        if (NPASS == 3) asl = as + adelta;
      }
      gload16(as, lds + LA + r * 4096 + wave * 1024);
      if (NPASS == 3) gload16(asl, lds + LAL + r * 4096 + wave * 1024);
      const char* bs = bSrc[r] + (size_t)k0 * 2;
      gload16(bs, lds + LB + r * 4096 + wave * 1024);
      if (NPASS == 3) gload16(bs + bdelta, lds + LBL + r * 4096 + wave * 1024);
    }
    __syncthreads();
    #pragma unroll
    for (int kk = 0; kk < BK / 32; ++kk) {
      f16x8 ah[4], bh[4], al[4], bl[4];
      #pragma unroll
      for (int i = 0; i < 4; ++i) {
        const int ar = wm + i * 16 + fr;
        const int ao = ar * RB + ((kk * 64 + kgb) ^ ((ar & SWM) << 4));
        ah[i] = *(const f16x8*)(lds + LA + ao);
        if (NPASS == 3) al[i] = *(const f16x8*)(lds + LAL + ao);
        const int br = wn + i * 16 + fr;
        const int bo = br * RB + ((kk * 64 + kgb) ^ ((br & SWM) << 4));
        bh[i] = *(const f16x8*)(lds + LB + bo);
        if (NPASS == 3) bl[i] = *(const f16x8*)(lds + LBL + bo);
      }
      #pragma unroll
      for (int i = 0; i < 4; ++i) {
        #pragma unroll
        for (int j = 0; j < 4; ++j) {
          acc[i][j] = __builtin_amdgcn_mfma_f32_16x16x32_f16(ah[i], bh[j], acc[i][j], 0, 0, 0);
          if (NPASS == 3) {
            acc[i][j] = __builtin_amdgcn_mfma_f32_16x16x32_f16(ah[i], bl[j], acc[i][j], 0, 0, 0);
            acc[i][j] = __builtin_amdgcn_mfma_f32_16x16x32_f16(al[i], bh[j], acc[i][j], 0, 0, 0);
          }
        }
      }
    }
    __syncthreads();
  }

  #pragma unroll
  for (int i = 0; i < 4; ++i) {
    const int mb = wm + i * 16 + (lane >> 4) * 4;
    #pragma unroll
    for (int j = 0; j < 4; ++j) {
      const int nc = n0 + wn + j * 16 + fr;
      const float bv = bias_[nc];
      #pragma unroll
      for (int q = 0; q < 4; ++q) {
        const int ml = mb + q;
        if (MODE == 2 && ml >= mcnt) continue;
        const size_t orow = (size_t)(m0 + ml);
        float v = acc[i][j][q] + bv;
        if (EPI == 1) v += res[orow * ldo + nc];
        if (EPI == 3) v = 0.5f * v * (1.0f + erff(v * 0.70710678118654752440f));
        if (EPI <= 1) outf[orow * ldo + nc] = v;
        else          outh[orow * ldo + nc] = (f16)v;
      }
    }
  }
}

// ---------------------------------------------------------------------------
// LayerNorm: fp32 in -> f16 hi (+optional lo plane). WGATE: fuse gate-logit
// partials (y . gW[:,e]) with wave+LDS reduction -> logits[row][8] fp32.
// ---------------------------------------------------------------------------
template<int WLO, int WGATE>
__global__ __launch_bounds__(256)
void ln_kernel(const float* __restrict__ x, const float* __restrict__ g, const float* __restrict__ b,
               f16* __restrict__ oh, f16* __restrict__ ol,
               const float* __restrict__ gW, const float* __restrict__ gb,
               float* __restrict__ logits) {
  const int row = blockIdx.x;
  const int t = threadIdx.x;
  const float4 v = ((const float4*)(x + (size_t)row * 1024))[t];
  float s  = v.x + v.y + v.z + v.w;
  float ss = v.x * v.x + v.y * v.y + v.z * v.z + v.w * v.w;
  #pragma unroll
  for (int off = 32; off; off >>= 1) { s += __shfl_down(s, off, 64); ss += __shfl_down(ss, off, 64); }
  __shared__ float red[8];
  if ((t & 63) == 0) { red[t >> 6] = s; red[(t >> 6) + 4] = ss; }
  __syncthreads();
  s  = red[0] + red[1] + red[2] + red[3];
  ss = red[4] + red[5] + red[6] + red[7];
  const float mu  = s * (1.0f / 1024.0f);
  const float var = ss * (1.0f / 1024.0f) - mu * mu;
  const float inv = 1.0f / sqrtf(var + 1e-5f);
  const float4 gv = ((const float4*)g)[t];
  const float4 bv = ((const float4*)b)[t];
  float y[4];
  y[0] = (v.x - mu) * inv * gv.x + bv.x;
  y[1] = (v.y - mu) * inv * gv.y + bv.y;
  y[2] = (v.z - mu) * inv * gv.z + bv.z;
  y[3] = (v.w - mu) * inv * gv.w + bv.w;
  f16x4 hv;
  #pragma unroll
  for (int u = 0; u < 4; ++u) hv[u] = (f16)y[u];
  *(f16x4*)(oh + (size_t)row * 1024 + t * 4) = hv;
  if (WLO) {
    f16x4 lv;
    #pragma unroll
    for (int u = 0; u < 4; ++u) lv[u] = (f16)(y[u] - (float)hv[u]);
    *(f16x4*)(ol + (size_t)row * 1024 + t * 4) = lv;
  }
  if (WGATE) {
    const float* gr = gW + (size_t)(t * 4) * 8;
    float lg[8];
    #pragma unroll
    for (int e = 0; e < 8; ++e)
      lg[e] = y[0] * gr[e] + y[1] * gr[8 + e] + y[2] * gr[16 + e] + y[3] * gr[24 + e];
    #pragma unroll
    for (int m = 1; m < 64; m <<= 1)
      #pragma unroll
      for (int e = 0; e < 8; ++e) lg[e] += __shfl_xor(lg[e], m, 64);
    __shared__ float gred[4][8];
    if ((t & 63) == 0) {
      #pragma unroll
      for (int e = 0; e < 8; ++e) gred[t >> 6][e] = lg[e];
    }
    __syncthreads();
    if (t < 8)
      logits[(size_t)row * 8 + t] = gred[0][t] + gred[1][t] + gred[2][t] + gred[3][t] + gb[t];
  }
}

// ---------------------------------------------------------------------------
// Windowed "attention" (faithful to unfold bug): per (b,h,n<16):
// A[d][e]=softmax_e( (1/8) sum_s q[s,d]k[s,e] ), O[d][s]=sum_e A[d][e] v[s,e]
// output row n*256+d*4+(s>>6), channel h*64+(s&63).  All fp32.
// ---------------------------------------------------------------------------
__global__ __launch_bounds__(256)
void attn_kernel(const float* __restrict__ qkv, f16* __restrict__ oh, f16* __restrict__ ol) {
  __shared__ __align__(16) char sm[65536];
  const int bid = blockIdx.x;
  const int b = bid >> 8, h = (bid >> 4) & 15, n = bid & 15;
  const int t = threadIdx.x;
  const size_t rowbase = (size_t)(b * 2176 + n * 128);
  const float* qb = qkv + rowbase * 3072 + h * 64;
  const float* kb = qb + 1024;
  const float* vb = qb + 2048;

  const int dq = t >> 2;       // score row (hd)
  const int eg = t & 3;        // score col group
  float pacc[16];
  #pragma unroll
  for (int u = 0; u < 16; ++u) pacc[u] = 0.0f;

  const int ld0 = (t & 15) * 4;
  const int ls0 = t >> 4;

  // ---- QK over two s-chunks of 128 ----
  for (int cs = 0; cs < 2; ++cs) {
    for (int rr = 0; rr < 8; ++rr) {
      const int sp = ls0 + rr * 16;
      const int s  = cs * 128 + sp;
      const float4 qv = *(const float4*)(qb + (size_t)s * 3072 + ld0);
      const float4 kv = *(const float4*)(kb + (size_t)s * 3072 + ld0);
      float qa[4] = {qv.x, qv.y, qv.z, qv.w};
      float ka[4] = {kv.x, kv.y, kv.z, kv.w};
      #pragma unroll
      for (int j = 0; j < 4; ++j) {
        const int d = ld0 + j;
        const int off = d * 512 + ((sp * 4) ^ ((d & 7) << 4));
        *(float*)(sm + off) = qa[j];
        *(float*)(sm + 32768 + off) = ka[j];
      }
    }
    __syncthreads();
    for (int sg = 0; sg < 32; ++sg) {
      const f32x4 qv = *(const f32x4*)(sm + dq * 512 + ((sg * 16) ^ ((dq & 7) << 4)));
      #pragma unroll
      for (int j = 0; j < 16; ++j) {
        const int el = (j + eg * 4) & 15;      // address rotation (banks)
        const int e  = eg * 16 + el;
        const f32x4 kv = *(const f32x4*)(sm + 32768 + e * 512 + ((sg * 16) ^ ((e & 7) << 4)));
        pacc[j] += qv[0] * kv[0] + qv[1] * kv[1] + qv[2] * kv[2] + qv[3] * kv[3];
      }
    }
    __syncthreads();
  }

  // ---- softmax over e (row dq lives in 4 adjacent lanes) ----
  float mx = -1e30f;
  #pragma unroll
  for (int u = 0; u < 16; ++u) { pacc[u] *= 0.125f; mx = fmaxf(mx, pacc[u]); }
  mx = fmaxf(mx, __shfl_xor(mx, 1, 4));
  mx = fmaxf(mx, __shfl_xor(mx, 2, 4));
  float den = 0.0f;
  #pragma unroll
  for (int u = 0; u < 16; ++u) { pacc[u] = expf(pacc[u] - mx); den += pacc[u]; }
  den += __shfl_xor(den, 1, 4);
  den += __shfl_xor(den, 2, 4);
  const float dinv = 1.0f / den;
  #pragma unroll
  for (int u = 0; u < 16; ++u) pacc[u] *= dinv;

  // ---- PV over two s-chunks; P fetched cross-lane via shfl ----
  const int sg2 = t & 3;
  for (int vs = 0; vs < 2; ++vs) {
    for (int rr = 0; rr < 8; ++rr) {
      const int sp = ls0 + rr * 16;
      const int s  = vs * 128 + sp;
      const float4 vv = *(const float4*)(vb + (size_t)s * 3072 + ld0);
      float va[4] = {vv.x, vv.y, vv.z, vv.w};
      #pragma unroll
      for (int j = 0; j < 4; ++j) {
        const int e = ld0 + j;
        const int off = e * 512 + ((sp * 4) ^ ((e & 7) << 4));
        *(float*)(sm + 32768 + off) = va[j];
      }
    }
    __syncthreads();
    float o[32];
    #pragma unroll
    for (int u = 0; u < 32; ++u) o[u] = 0.0f;
    #pragma unroll
    for (int e = 0; e < 64; ++e) {
      const int jreg = ((e & 15) - ((e >> 4) << 2)) & 15;   // register of P[dq][e] in src lane
      const float p = __shfl(pacc[jreg], (t & 60) + (e >> 4), 64);
      #pragma unroll
      for (int k = 0; k < 8; ++k) {
        const int kk = (k + sg2 * 2) & 7;                   // address rotation
        const f32x4 vv = *(const f32x4*)(sm + 32768 + e * 512 + (((sg2 * 128) + kk * 16) ^ ((e & 7) << 4)));
        o[k * 4 + 0] += p * vv[0];
        o[k * 4 + 1] += p * vv[1];
        o[k * 4 + 2] += p * vv[2];
        o[k * 4 + 3] += p * vv[3];
      }
    }
    // write: row = b*4096 + n*256 + dq*4 + vs*2 + (sg2>>1); ch = h*64 + (sg2&1)*32 + kk*4+u
    const size_t prow = (size_t)(b * 4096 + n * 256 + dq * 4 + vs * 2 + (sg2 >> 1));
    const int cbase = h * 64 + (sg2 & 1) * 32;
    #pragma unroll
    for (int k = 0; k < 8; ++k) {
      const int kk = (k + sg2 * 2) & 7;
      f16x4 hv, lv;
      #pragma unroll
      for (int u = 0; u < 4; ++u) {
        const float val = o[k * 4 + u];
        hv[u] = (f16)val;
        lv[u] = (f16)(val - (float)hv[u]);
      }
      *(f16x4*)(oh + prow * 1024 + cbase + kk * 4) = hv;
      *(f16x4*)(ol + prow * 1024 + cbase + kk * 4) = lv;
    }
    __syncthreads();
  }
}

// ---------------------------------------------------------------------------
// weight transposes fp32 -> f16 (optional lo plane); batched over blockIdx.z
// ---------------------------------------------------------------------------
template<int SPLIT>
__global__ __launch_bounds__(256)
void transpose_kernel(const float* __restrict__ in, int R, int Cc,
                      f16* __restrict__ oh, f16* __restrict__ ol) {
  __shared__ float tile[32][33];
  const size_t mat = (size_t)blockIdx.z * R * Cc;
  in += mat; oh += mat; if (SPLIT) ol += mat;
  const int tx = threadIdx.x & 31, ty = threadIdx.x >> 5;
  const int c = blockIdx.x * 32 + tx;
  #pragma unroll
  for (int j = 0; j < 32; j += 8) {
    const int r = blockIdx.y * 32 + ty + j;
    tile[ty + j][tx] = in[(size_t)r * Cc + c];
  }
  __syncthreads();
  const int rT = blockIdx.y * 32 + tx;
  #pragma unroll
  for (int j = 0; j < 32; j += 8) {
    const int cT = blockIdx.x * 32 + ty + j;
    const float v = tile[tx][ty + j];
    const f16 hv = (f16)v;
    oh[(size_t)cT * R + rT] = hv;
    if (SPLIT) ol[(size_t)cT * R + rT] = (f16)(v - (float)hv);
  }
}

// conv weights [O,I,3] -> BT[o][tap*1024+i] hi/lo
__global__ __launch_bounds__(256)
void convw_kernel(const float* __restrict__ w, f16* __restrict__ oh, f16* __restrict__ ol) {
  const int id = blockIdx.x * 256 + threadIdx.x;  // 1024*1024
  const int o = id >> 10, i = id & 1023;
  const float* ws = w + (size_t)o * 3072 + i * 3;
  #pragma unroll
  for (int tap = 0; tap < 3; ++tap) {
    const float v = ws[tap];
    const f16 hv = (f16)v;
    const size_t oi = (size_t)o * 3072 + tap * 1024 + i;
    oh[oi] = hv;
    ol[oi] = (f16)(v - (float)hv);
  }
}

__global__ void qkvrows_kernel(int* __restrict__ rows) {
  const int r = blockIdx.x * 256 + threadIdx.x;
  if (r < 4352) rows[r] = (r >= 2176) ? (4096 + r - 2176) : r;
}

// ---------------------------------------------------------------------------
// gate finalize: per-token top-2/softmax/entropy from fused logits; counts
// via LDS histogram + 8 global atomics per block (contention fix).
// ---------------------------------------------------------------------------
__global__ __launch_bounds__(256)
void gatefin_kernel(const float* __restrict__ logits, float* __restrict__ top2p,
                    int* __restrict__ top2i, float* __restrict__ ent,
                    int* __restrict__ counts) {
  __shared__ int hist[8];
  const int t = threadIdx.x;
  if (t < 8) hist[t] = 0;
  __syncthreads();
  const int token = blockIdx.x * 256 + t;
  float lg[8];
  const float4 l0 = ((const float4*)(logits + (size_t)token * 8))[0];
  const float4 l1 = ((const float4*)(logits + (size_t)token * 8))[1];
  lg[0] = l0.x; lg[1] = l0.y; lg[2] = l0.z; lg[3] = l0.w;
  lg[4] = l1.x; lg[5] = l1.y; lg[6] = l1.z; lg[7] = l1.w;
  int i0 = 0; float v0 = lg[0];
  #pragma unroll
  for (int e = 1; e < 8; ++e) if (lg[e] > v0) { v0 = lg[e]; i0 = e; }
  int i1 = 0; float v1 = -1e30f;
  #pragma unroll
  for (int e = 0; e < 8; ++e) if (e != i0 && lg[e] > v1) { v1 = lg[e]; i1 = e; }
  float den = 0.0f; float pr[8];
  #pragma unroll
  for (int e = 0; e < 8; ++e) { pr[e] = expf(lg[e] - v0); den += pr[e]; }
  const float dinv = 1.0f / den;
  float H = 0.0f, p0 = 0.0f, p1 = 0.0f;
  #pragma unroll
  for (int e = 0; e < 8; ++e) {
    const float p = pr[e] * dinv;
    H -= p * logf(p + 1e-10f);
    if (e == i0) p0 = p;
    if (e == i1) p1 = p;
  }
  ent[token] = H;
  top2p[token * 2] = p0; top2p[token * 2 + 1] = p1;
  top2i[token * 2] = i0; top2i[token * 2 + 1] = i1;
  atomicAdd(&hist[i0], 1);
  atomicAdd(&hist[i1], 1);
  __syncthreads();
  if (t < 8) atomicAdd(&counts[t], hist[t]);
}

// scan: entropy mean (fixed order), offsets, aux, tile table
__global__ __launch_bounds__(256)
void scan_kernel(const float* __restrict__ ent, const int* __restrict__ counts,
                 int* __restrict__ offs, TileInfo* __restrict__ table, float* __restrict__ auxout) {
  __shared__ float red[256];
  const int t = threadIdx.x;
  float s = 0.0f;
  for (int k = 0; k < 32; ++k) s += ent[t + (k << 8)];
  red[t] = s; __syncthreads();
  for (int hh = 128; hh > 0; hh >>= 1) { if (t < hh) red[t] += red[t + hh]; __syncthreads(); }
  if (t == 0) {
    const float entmean = red[0] * (1.0f / 8192.0f);
    float pen = 0.0f; int off = 0; int nt = 0;
    for (int e = 0; e < 8; ++e) {
      const int c = counts[e];
      offs[e] = off;
      for (int m = 0; m < c; m += 128) {
        table[nt].m0 = off + m;
        table[nt].mcnt = (c - m < 128) ? (c - m) : 128;
        table[nt].e = e; table[nt].pad = 0;
        ++nt;
      }
      off += c;
      const float fr = (float)c * (1.0f / 8192.0f) - 0.3f;
      pen += (fr > 0.0f) ? fr : 0.0f;
    }
    for (; nt < 160; ++nt) { table[nt].m0 = 0; table[nt].mcnt = 0; table[nt].e = 0; table[nt].pad = 0; }
    auxout[0] = 0.1f * entmean + pen;
  }
}

// scatter: block-local LDS ranks + one chunk-reservation atomic per expert
__global__ __launch_bounds__(256)
void scatter_kernel(const int* __restrict__ top2i, const int* __restrict__ offs,
                    int* __restrict__ fill, int* __restrict__ moe_rows,
                    int* __restrict__ row2slot) {
  __shared__ int hist[8];
  __shared__ int base[8];
  const int t = threadIdx.x;
  if (t < 8) hist[t] = 0;
  __syncthreads();
  const int id = blockIdx.x * 256 + t;  // 16384
  const int e = top2i[id];
  const int myrank = atomicAdd(&hist[e], 1);
  __syncthreads();
  if (t < 8) base[t] = atomicAdd(&fill[t], hist[t]);
  __syncthreads();
  const int row = offs[e] + base[e] + myrank;
  moe_rows[row] = id >> 1;
  row2slot[id] = row;
}

// x3 = x2 + p0*eo[r0] + p1*eo[r1]; also f16 copy for FF1
__global__ __launch_bounds__(256)
void combine_kernel(const float* __restrict__ x2, const f16* __restrict__ eo,
                    const float* __restrict__ top2p, const int* __restrict__ row2slot,
                    float* __restrict__ x3, f16* __restrict__ x3h) {
  const int n = blockIdx.x;
  const int t = threadIdx.x;
  const int r0 = row2slot[n * 2], r1 = row2slot[n * 2 + 1];
  const float p0 = top2p[n * 2], p1 = top2p[n * 2 + 1];
  const float4 xv = ((const float4*)(x2 + (size_t)n * 1024))[t];
  const f16x4 e0 = ((const f16x4*)(eo + (size_t)r0 * 1024))[t];
  const f16x4 e1 = ((const f16x4*)(eo + (size_t)r1 * 1024))[t];
  float4 o;
  o.x = xv.x + p0 * (float)e0[0] + p1 * (float)e1[0];
  o.y = xv.y + p0 * (float)e0[1] + p1 * (float)e1[1];
  o.z = xv.z + p0 * (float)e0[2] + p1 * (float)e1[2];
  o.w = xv.w + p0 * (float)e0[3] + p1 * (float)e1[3];
  ((float4*)(x3 + (size_t)n * 1024))[t] = o;
  f16x4 hv; hv[0] = (f16)o.x; hv[1] = (f16)o.y; hv[2] = (f16)o.z; hv[3] = (f16)o.w;
  ((f16x4*)(x3h + (size_t)n * 1024))[t] = hv;
}

// ---------------------------------------------------------------------------
extern "C" void kernel_launch(void* const* d_in, const int* in_sizes, int n_in,
                              void* d_out, int out_size, void* d_ws, size_t ws_size,
                              hipStream_t stream) {
  (void)in_sizes; (void)n_in; (void)out_size; (void)ws_size;
  const float* x     = (const float*)d_in[0];
  const float* g1    = (const float*)d_in[1];
  const float* b1    = (const float*)d_in[2];
  const float* g2    = (const float*)d_in[3];
  const float* b2    = (const float*)d_in[4];
  const float* g3    = (const float*)d_in[5];
  const float* b3    = (const float*)d_in[6];
  const float* Wqkv  = (const float*)d_in[7];
  const float* bqkv  = (const float*)d_in[8];
  const float* Wo    = (const float*)d_in[9];
  const float* bo    = (const float*)d_in[10];
  const float* convw = (const float*)d_in[11];
  const float* convb = (const float*)d_in[12];
  const float* gateW = (const float*)d_in[13];
  const float* gateb = (const float*)d_in[14];
  const float* expW  = (const float*)d_in[15];
  const float* expb  = (const float*)d_in[16];
  const float* ffW1  = (const float*)d_in[17];
  const float* ffb1  = (const float*)d_in[18];
  const float* ffW2  = (const float*)d_in[19];
  const float* ffb2  = (const float*)d_in[20];
  float* out = (float*)d_out;

  char* W = (char*)d_ws;
  f16* wqkvT_h = (f16*)(W + 0);
  f16* wqkvT_l = (f16*)(W + 6291456);
  f16* woT_h   = (f16*)(W + 12582912);
  f16* woT_l   = (f16*)(W + 14680064);
  f16* wcvT_h  = (f16*)(W + 16777216);
  f16* wcvT_l  = (f16*)(W + 23068672);
  f16* wexpT   = (f16*)(W + 29360128);
  f16* wff1T   = (f16*)(W + 46137344);
  f16* wff2T   = (f16*)(W + 54525952);
  char* META   = W + 62914560;
  int* counts    = (int*)(META);
  int* fill      = (int*)(META + 32);
  int* offs      = (int*)(META + 64);
  TileInfo* table = (TileInfo*)(META + 128);
  char* zbuf     = META + 3072;          // 1KB zeros (covered by memset below)
  int* qkv_rows  = (int*)(META + 4096);
  float* ent     = (float*)(META + 24576);
  float* top2p   = (float*)(META + 57344);
  int* top2i     = (int*)(META + 122880);
  int* moe_rows  = (int*)(META + 188416);
  int* row2slot  = (int*)(META + 253952);
  float* logits  = (float*)(META + 327680);   // 8192*8 f32 = 256KB
  char* SA = W + 63963136;    // 32 MB: ln1/ln2 hi|lo ; ln3_hi | x3_hi
  char* SB = W + 97517568;    // 64 MB: qkv f32 -> x2 f32 -> h f16
  char* SC = W + 164626432;   // 32 MB: attn hi|lo
  char* SD = W + 198180864;   // 32 MB: x1 f32 -> eo f16
  char* SE = W + 231735296;   // 32 MB: x3 f32

  f16* ln1h = (f16*)SA;            f16* ln1l = (f16*)(SA + 16777216);
  f16* ln2h = ln1h;                f16* ln2l = ln1l;
  f16* ln3h = ln1h;                f16* x3h  = (f16*)(SA + 16777216);
  float* qkvbuf = (float*)SB;
  float* x2buf  = (float*)SB;
  f16*   hbuf   = (f16*)SB;
  f16* attnh = (f16*)SC;           f16* attnl = (f16*)(SC + 16777216);
  float* x1 = (float*)SD;
  f16* eobuf = (f16*)SD;
  float* x3 = (float*)SE;

  // zero: counts(32) + fill(32) + zbuf(@3072..4096); single memset covers 0..4096
  hipMemsetAsync((void*)META, 0, 4096, stream);

  dim3 blk(256);
  // weight prep
  transpose_kernel<1><<<dim3(96, 32, 1), blk, 0, stream>>>(Wqkv, 1024, 3072, wqkvT_h, wqkvT_l);
  transpose_kernel<1><<<dim3(32, 32, 1), blk, 0, stream>>>(Wo, 1024, 1024, woT_h, woT_l);
  convw_kernel<<<4096, blk, 0, stream>>>(convw, wcvT_h, wcvT_l);
  transpose_kernel<0><<<dim3(32, 32, 8), blk, 0, stream>>>(expW, 1024, 1024, wexpT, nullptr);
  transpose_kernel<0><<<dim3(128, 32, 1), blk, 0, stream>>>(ffW1, 1024, 4096, wff1T, nullptr);
  transpose_kernel<0><<<dim3(32, 128, 1), blk, 0, stream>>>(ffW2, 4096, 1024, wff2T, nullptr);
  qkvrows_kernel<<<17, blk, 0, stream>>>(qkv_rows);

  // LN1 -> split planes
  ln_kernel<1, 0><<<8192, blk, 0, stream>>>(x, g1, b1, ln1h, ln1l, nullptr, nullptr, nullptr);
  // QKV (rows 0..2175 per batch), split GEMM, fp32 out
  gemm_kernel<3, 1, 0><<<dim3(34, 24), blk, 0, stream>>>(ln1h, ln1l, 1024, wqkvT_h, wqkvT_l, 1024,
      bqkv, nullptr, qkvbuf, nullptr, 3072, 1024, qkv_rows, nullptr, nullptr);
  // attention
  attn_kernel<<<512, blk, 0, stream>>>(qkvbuf, attnh, attnl);
  // Wo projection + residual -> x1
  gemm_kernel<3, 0, 1><<<dim3(64, 8), blk, 0, stream>>>(attnh, attnl, 1024, woT_h, woT_l, 1024,
      bo, x, x1, nullptr, 1024, 1024, nullptr, nullptr, nullptr);
  // LN2
  ln_kernel<1, 0><<<8192, blk, 0, stream>>>(x1, g2, b2, ln2h, ln2l, nullptr, nullptr, nullptr);
  // conv (3-tap shifted GEMM, exact zero-pad) + residual -> x2
  gemm_kernel<3, 3, 1><<<dim3(64, 8), blk, 0, stream>>>(ln2h, ln2l, 1024, wcvT_h, wcvT_l, 3072,
      convb, x1, x2buf, nullptr, 1024, 3072, nullptr, nullptr, zbuf);
  // LN3 fused with gate logits (f16 hi for experts + logits for routing)
  ln_kernel<0, 1><<<8192, blk, 0, stream>>>(x2buf, g3, b3, ln3h, nullptr, gateW, gateb, logits);
  // gate finalize / scan / scatter
  gatefin_kernel<<<32, blk, 0, stream>>>(logits, top2p, top2i, ent, counts);
  scan_kernel<<<1, blk, 0, stream>>>(ent, counts, offs, table, out + 8388608);
  scatter_kernel<<<64, blk, 0, stream>>>(top2i, offs, fill, moe_rows, row2slot);
  // grouped expert GEMM -> eo (f16)
  gemm_kernel<1, 2, 2><<<dim3(136, 8), blk, 0, stream>>>(ln3h, nullptr, 1024, wexpT, nullptr, 1024,
      expb, nullptr, nullptr, eobuf, 1024, 1024, moe_rows, table, nullptr);
  // combine -> x3 (+f16)
  combine_kernel<<<8192, blk, 0, stream>>>(x2buf, eobuf, top2p, row2slot, x3, x3h);
  // FF1 (gelu) -> h
  gemm_kernel<1, 0, 3><<<dim3(64, 32), blk, 0, stream>>>(x3h, nullptr, 1024, wff1T, nullptr, 1024,
      ffb1, nullptr, nullptr, hbuf, 4096, 1024, nullptr, nullptr, nullptr);
  // FF2 + residual -> final output
  gemm_kernel<1, 0, 1><<<dim3(64, 8), blk, 0, stream>>>(hbuf, nullptr, 4096, wff2T, nullptr, 4096,
      ffb2, x3, out, nullptr, 1024, 4096, nullptr, nullptr, nullptr);
}

// Round 5
// 875.419 us; speedup vs baseline: 1.9386x; 1.0845x over previous
//
#include <hip/hip_runtime.h>
#include <cmath>

typedef _Float16 f16;
typedef __attribute__((ext_vector_type(8))) _Float16 f16x8;
typedef __attribute__((ext_vector_type(4))) _Float16 f16x4;
typedef __attribute__((ext_vector_type(4))) float f32x4;

struct TileInfo { int m0, mcnt, e, pad; };

__device__ __forceinline__ void gload16(const void* g, void* l) {
  __builtin_amdgcn_global_load_lds((const __attribute__((address_space(1))) void*)g,
                                   (__attribute__((address_space(3))) void*)l, 16, 0, 0);
}

// fast gelu: 0.5u(1+tanh(c)) = u*e/(e+1), e=exp(2c), c=0.79788456(u+0.044715u^3)
// |diff vs erf-gelu| <= ~1e-3; exp-arg clamped to avoid inf*0 NaN.
__device__ __forceinline__ float fast_gelu(float u) {
  const float c = u * (0.7978845608028654f + 0.0356774081f * u * u);
  const float t = fminf(2.0f * c, 80.0f);
  const float e = __expf(t);
  return u * (e * __builtin_amdgcn_rcpf(e + 1.0f));
}

// ---------------------------------------------------------------------------
// Unified GEMM:  C[M,N] = A[M,K] * B[K,N] (+bias, +res, +gelu), B given
// transposed (BT[N,K], row-major).  A/B in f16; NPASS==3 adds lo-planes for
// fp32-faithful results (hh+hl+lh).  MODE: 0 direct, 1 rowmap(A rows),
// 2 tile-table (MoE grouped), 3 conv (3-tap shifted A rows with exact
// zero-padding via zbuf, K=3072).  BK=64 everywhere (1024%64==0 so conv
// tiles never straddle a tap boundary).
// EPI: 0 f32=acc+bias; 1 f32=res+acc+bias; 2 f16=acc+bias; 3 f16=gelu(acc+bias)
// ---------------------------------------------------------------------------
template<int NPASS, int MODE, int EPI>
__global__ __launch_bounds__(256)
void gemm_kernel(const f16* __restrict__ Ah, const f16* __restrict__ Al, int lda,
                 const f16* __restrict__ Bh, const f16* __restrict__ Bl, int ldb,
                 const float* __restrict__ bias, const float* __restrict__ res,
                 float* __restrict__ outf, f16* __restrict__ outh, int ldo, int K,
                 const int* __restrict__ rowmap, const TileInfo* __restrict__ table,
                 const char* __restrict__ zbuf) {
  constexpr int BK = 64;
  constexpr int RB = BK * 2;            // bytes per LDS tile row (128)
  constexpr int TB = 128 * RB;          // bytes per tile plane (16KB)
  constexpr int ROUNDS = TB / 4096;     // staging rounds (4)
  constexpr int TPR = RB / 16;          // threads per row (8)
  constexpr int RPR = 4096 / RB;        // rows per round (32)
  constexpr int SWM = TPR - 1;          // swizzle mask (7)
  constexpr int LA  = 0;
  constexpr int LAL = (NPASS == 3) ? TB : 0;
  constexpr int LB  = (NPASS == 3) ? 2 * TB : TB;
  constexpr int LBL = (NPASS == 3) ? 3 * TB : 0;

  __shared__ __align__(16) char lds[(NPASS == 3) ? 65536 : 32768];

  const int tid  = threadIdx.x;
  const int wave = tid >> 6;
  const int lane = tid & 63;

  int m0, mcnt, eidx = 0;
  if (MODE == 2) {
    TileInfo ti = table[blockIdx.x];
    if (ti.mcnt <= 0) return;
    m0 = ti.m0; mcnt = ti.mcnt; eidx = ti.e;
  } else { m0 = blockIdx.x * 128; mcnt = 128; }
  const int n0 = blockIdx.y * 128;

  const f16* Bh_ = Bh;
  const float* bias_ = bias;
  size_t adelta = 0, bdelta = 0;
  if (NPASS == 3) {
    adelta = (size_t)((const char*)Al - (const char*)Ah);
    bdelta = (size_t)((const char*)Bl - (const char*)Bh);
  }
  if (MODE == 2) { Bh_ += ((size_t)eidx << 20); bias_ += eidx * 1024; }

  const int sr    = tid / TPR;
  const int cbyte = (tid % TPR) * 16;

  const char* aSrc[ROUNDS];
  const char* bSrc[ROUNDS];
  int aRowC[ROUNDS]; int aCbs[ROUNDS];
  #pragma unroll
  for (int r = 0; r < ROUNDS; ++r) {
    const int mr  = sr + r * RPR;
    const int cbs = cbyte ^ ((mr & SWM) << 4);
    int gi = m0 + ((mr < mcnt) ? mr : (mcnt - 1));
    if (MODE == 1 || MODE == 2) gi = rowmap[gi];
    if (MODE == 3) { aRowC[r] = gi; aCbs[r] = cbs; aSrc[r] = nullptr; }
    else           { aSrc[r] = (const char*)Ah + (size_t)gi * lda * 2 + cbs; aRowC[r] = 0; aCbs[r] = 0; }
    const int nr   = sr + r * RPR;
    const int ncbs = cbyte ^ ((nr & SWM) << 4);
    bSrc[r] = (const char*)Bh_ + (size_t)(n0 + nr) * ldb * 2 + ncbs;
  }

  f32x4 acc[4][4] = {};
  const int wm  = (wave >> 1) * 64;
  const int wn  = (wave & 1) * 64;
  const int fr  = lane & 15;
  const int kgb = (lane >> 4) * 16;

  for (int k0 = 0; k0 < K; k0 += BK) {
    #pragma unroll
    for (int r = 0; r < ROUNDS; ++r) {
      const char* as;
      const char* asl = nullptr;
      if (MODE == 3) {
        // exact zero-padded dilated-conv taps: tok + 2*(tap-1) within batch
        const int tap = k0 >> 10;
        const int kc  = k0 & 1023;
        const int tok = aRowC[r] & 4095;
        const int st  = tok + (tap - 1) * 2;
        if (st >= 0 && st < 4096) {
          as  = (const char*)Ah + (size_t)(aRowC[r] + (tap - 1) * 2) * 2048 + kc * 2 + aCbs[r];
          asl = as + adelta;
        } else {
          as  = zbuf;   // 16B of zeros (all lanes broadcast-read)
          asl = zbuf;
        }
      } else {
        as = aSrc[r] + (size_t)k0 * 2;
        if (NPASS == 3) asl = as + adelta;
      }
      gload16(as, lds + LA + r * 4096 + wave * 1024);
      if (NPASS == 3) gload16(asl, lds + LAL + r * 4096 + wave * 1024);
      const char* bs = bSrc[r] + (size_t)k0 * 2;
      gload16(bs, lds + LB + r * 4096 + wave * 1024);
      if (NPASS == 3) gload16(bs + bdelta, lds + LBL + r * 4096 + wave * 1024);
    }
    __syncthreads();
    #pragma unroll
    for (int kk = 0; kk < BK / 32; ++kk) {
      f16x8 ah[4], bh[4], al[4], bl[4];
      #pragma unroll
      for (int i = 0; i < 4; ++i) {
        const int ar = wm + i * 16 + fr;
        const int ao = ar * RB + ((kk * 64 + kgb) ^ ((ar & SWM) << 4));
        ah[i] = *(const f16x8*)(lds + LA + ao);
        if (NPASS == 3) al[i] = *(const f16x8*)(lds + LAL + ao);
        const int br = wn + i * 16 + fr;
        const int bo = br * RB + ((kk * 64 + kgb) ^ ((br & SWM) << 4));
        bh[i] = *(const f16x8*)(lds + LB + bo);
        if (NPASS == 3) bl[i] = *(const f16x8*)(lds + LBL + bo);
      }
      #pragma unroll
      for (int i = 0; i < 4; ++i) {
        #pragma unroll
        for (int j = 0; j < 4; ++j) {
          acc[i][j] = __builtin_amdgcn_mfma_f32_16x16x32_f16(ah[i], bh[j], acc[i][j], 0, 0, 0);
          if (NPASS == 3) {
            acc[i][j] = __builtin_amdgcn_mfma_f32_16x16x32_f16(ah[i], bl[j], acc[i][j], 0, 0, 0);
            acc[i][j] = __builtin_amdgcn_mfma_f32_16x16x32_f16(al[i], bh[j], acc[i][j], 0, 0, 0);
          }
        }
      }
    }
    __syncthreads();
  }

  #pragma unroll
  for (int i = 0; i < 4; ++i) {
    const int mb = wm + i * 16 + (lane >> 4) * 4;
    #pragma unroll
    for (int j = 0; j < 4; ++j) {
      const int nc = n0 + wn + j * 16 + fr;
      const float bv = bias_[nc];
      #pragma unroll
      for (int q = 0; q < 4; ++q) {
        const int ml = mb + q;
        if (MODE == 2 && ml >= mcnt) continue;
        const size_t orow = (size_t)(m0 + ml);
        float v = acc[i][j][q] + bv;
        if (EPI == 1) v += res[orow * ldo + nc];
        if (EPI == 3) v = fast_gelu(v);
        if (EPI <= 1) outf[orow * ldo + nc] = v;
        else          outh[orow * ldo + nc] = (f16)v;
      }
    }
  }
}

// ---------------------------------------------------------------------------
// LayerNorm: fp32 in -> f16 hi (+optional lo plane). WGATE: fuse gate-logit
// partials (y . gW[:,e]) with wave+LDS reduction -> logits[row][8] fp32.
// ---------------------------------------------------------------------------
template<int WLO, int WGATE>
__global__ __launch_bounds__(256)
void ln_kernel(const float* __restrict__ x, const float* __restrict__ g, const float* __restrict__ b,
               f16* __restrict__ oh, f16* __restrict__ ol,
               const float* __restrict__ gW, const float* __restrict__ gb,
               float* __restrict__ logits) {
  const int row = blockIdx.x;
  const int t = threadIdx.x;
  const float4 v = ((const float4*)(x + (size_t)row * 1024))[t];
  float s  = v.x + v.y + v.z + v.w;
  float ss = v.x * v.x + v.y * v.y + v.z * v.z + v.w * v.w;
  #pragma unroll
  for (int off = 32; off; off >>= 1) { s += __shfl_down(s, off, 64); ss += __shfl_down(ss, off, 64); }
  __shared__ float red[8];
  if ((t & 63) == 0) { red[t >> 6] = s; red[(t >> 6) + 4] = ss; }
  __syncthreads();
  s  = red[0] + red[1] + red[2] + red[3];
  ss = red[4] + red[5] + red[6] + red[7];
  const float mu  = s * (1.0f / 1024.0f);
  const float var = ss * (1.0f / 1024.0f) - mu * mu;
  const float inv = 1.0f / sqrtf(var + 1e-5f);
  const float4 gv = ((const float4*)g)[t];
  const float4 bv = ((const float4*)b)[t];
  float y[4];
  y[0] = (v.x - mu) * inv * gv.x + bv.x;
  y[1] = (v.y - mu) * inv * gv.y + bv.y;
  y[2] = (v.z - mu) * inv * gv.z + bv.z;
  y[3] = (v.w - mu) * inv * gv.w + bv.w;
  f16x4 hv;
  #pragma unroll
  for (int u = 0; u < 4; ++u) hv[u] = (f16)y[u];
  *(f16x4*)(oh + (size_t)row * 1024 + t * 4) = hv;
  if (WLO) {
    f16x4 lv;
    #pragma unroll
    for (int u = 0; u < 4; ++u) lv[u] = (f16)(y[u] - (float)hv[u]);
    *(f16x4*)(ol + (size_t)row * 1024 + t * 4) = lv;
  }
  if (WGATE) {
    const float* gr = gW + (size_t)(t * 4) * 8;
    float lg[8];
    #pragma unroll
    for (int e = 0; e < 8; ++e)
      lg[e] = y[0] * gr[e] + y[1] * gr[8 + e] + y[2] * gr[16 + e] + y[3] * gr[24 + e];
    #pragma unroll
    for (int m = 1; m < 64; m <<= 1)
      #pragma unroll
      for (int e = 0; e < 8; ++e) lg[e] += __shfl_xor(lg[e], m, 64);
    __shared__ float gred[4][8];
    if ((t & 63) == 0) {
      #pragma unroll
      for (int e = 0; e < 8; ++e) gred[t >> 6][e] = lg[e];
    }
    __syncthreads();
    if (t < 8)
      logits[(size_t)row * 8 + t] = gred[0][t] + gred[1][t] + gred[2][t] + gred[3][t] + gb[t];
  }
}

// ---------------------------------------------------------------------------
// Windowed "attention" (faithful to unfold bug): per (b,h,n<16):
// A[d][e]=softmax_e( (1/8) sum_s q[s,d]k[s,e] ), O[d][s]=sum_e A[d][e] v[s,e]
// output row n*256+d*4+(s>>6), channel h*64+(s&63).  All fp32.
// ---------------------------------------------------------------------------
__global__ __launch_bounds__(256)
void attn_kernel(const float* __restrict__ qkv, f16* __restrict__ oh, f16* __restrict__ ol) {
  __shared__ __align__(16) char sm[65536];
  const int bid = blockIdx.x;
  const int b = bid >> 8, h = (bid >> 4) & 15, n = bid & 15;
  const int t = threadIdx.x;
  const size_t rowbase = (size_t)(b * 2176 + n * 128);
  const float* qb = qkv + rowbase * 3072 + h * 64;
  const float* kb = qb + 1024;
  const float* vb = qb + 2048;

  const int dq = t >> 2;       // score row (hd)
  const int eg = t & 3;        // score col group
  float pacc[16];
  #pragma unroll
  for (int u = 0; u < 16; ++u) pacc[u] = 0.0f;

  const int ld0 = (t & 15) * 4;
  const int ls0 = t >> 4;

  // ---- QK over two s-chunks of 128 ----
  for (int cs = 0; cs < 2; ++cs) {
    for (int rr = 0; rr < 8; ++rr) {
      const int sp = ls0 + rr * 16;
      const int s  = cs * 128 + sp;
      const float4 qv = *(const float4*)(qb + (size_t)s * 3072 + ld0);
      const float4 kv = *(const float4*)(kb + (size_t)s * 3072 + ld0);
      float qa[4] = {qv.x, qv.y, qv.z, qv.w};
      float ka[4] = {kv.x, kv.y, kv.z, kv.w};
      #pragma unroll
      for (int j = 0; j < 4; ++j) {
        const int d = ld0 + j;
        const int off = d * 512 + ((sp * 4) ^ ((d & 7) << 4));
        *(float*)(sm + off) = qa[j];
        *(float*)(sm + 32768 + off) = ka[j];
      }
    }
    __syncthreads();
    for (int sg = 0; sg < 32; ++sg) {
      const f32x4 qv = *(const f32x4*)(sm + dq * 512 + ((sg * 16) ^ ((dq & 7) << 4)));
      #pragma unroll
      for (int j = 0; j < 16; ++j) {
        const int el = (j + eg * 4) & 15;      // address rotation (banks)
        const int e  = eg * 16 + el;
        const f32x4 kv = *(const f32x4*)(sm + 32768 + e * 512 + ((sg * 16) ^ ((e & 7) << 4)));
        pacc[j] += qv[0] * kv[0] + qv[1] * kv[1] + qv[2] * kv[2] + qv[3] * kv[3];
      }
    }
    __syncthreads();
  }

  // ---- softmax over e (row dq lives in 4 adjacent lanes) ----
  float mx = -1e30f;
  #pragma unroll
  for (int u = 0; u < 16; ++u) { pacc[u] *= 0.125f; mx = fmaxf(mx, pacc[u]); }
  mx = fmaxf(mx, __shfl_xor(mx, 1, 4));
  mx = fmaxf(mx, __shfl_xor(mx, 2, 4));
  float den = 0.0f;
  #pragma unroll
  for (int u = 0; u < 16; ++u) { pacc[u] = expf(pacc[u] - mx); den += pacc[u]; }
  den += __shfl_xor(den, 1, 4);
  den += __shfl_xor(den, 2, 4);
  const float dinv = 1.0f / den;
  #pragma unroll
  for (int u = 0; u < 16; ++u) pacc[u] *= dinv;

  // ---- PV over two s-chunks; P fetched cross-lane via shfl ----
  const int sg2 = t & 3;
  for (int vs = 0; vs < 2; ++vs) {
    for (int rr = 0; rr < 8; ++rr) {
      const int sp = ls0 + rr * 16;
      const int s  = vs * 128 + sp;
      const float4 vv = *(const float4*)(vb + (size_t)s * 3072 + ld0);
      float va[4] = {vv.x, vv.y, vv.z, vv.w};
      #pragma unroll
      for (int j = 0; j < 4; ++j) {
        const int e = ld0 + j;
        const int off = e * 512 + ((sp * 4) ^ ((e & 7) << 4));
        *(float*)(sm + 32768 + off) = va[j];
      }
    }
    __syncthreads();
    float o[32];
    #pragma unroll
    for (int u = 0; u < 32; ++u) o[u] = 0.0f;
    #pragma unroll
    for (int e = 0; e < 64; ++e) {
      const int jreg = ((e & 15) - ((e >> 4) << 2)) & 15;   // register of P[dq][e] in src lane
      const float p = __shfl(pacc[jreg], (t & 60) + (e >> 4), 64);
      #pragma unroll
      for (int k = 0; k < 8; ++k) {
        const int kk = (k + sg2 * 2) & 7;                   // address rotation
        const f32x4 vv = *(const f32x4*)(sm + 32768 + e * 512 + (((sg2 * 128) + kk * 16) ^ ((e & 7) << 4)));
        o[k * 4 + 0] += p * vv[0];
        o[k * 4 + 1] += p * vv[1];
        o[k * 4 + 2] += p * vv[2];
        o[k * 4 + 3] += p * vv[3];
      }
    }
    // write: row = b*4096 + n*256 + dq*4 + vs*2 + (sg2>>1); ch = h*64 + (sg2&1)*32 + kk*4+u
    const size_t prow = (size_t)(b * 4096 + n * 256 + dq * 4 + vs * 2 + (sg2 >> 1));
    const int cbase = h * 64 + (sg2 & 1) * 32;
    #pragma unroll
    for (int k = 0; k < 8; ++k) {
      const int kk = (k + sg2 * 2) & 7;
      f16x4 hv, lv;
      #pragma unroll
      for (int u = 0; u < 4; ++u) {
        const float val = o[k * 4 + u];
        hv[u] = (f16)val;
        lv[u] = (f16)(val - (float)hv[u]);
      }
      *(f16x4*)(oh + prow * 1024 + cbase + kk * 4) = hv;
      *(f16x4*)(ol + prow * 1024 + cbase + kk * 4) = lv;
    }
    __syncthreads();
  }
}

// ---------------------------------------------------------------------------
// weight transposes fp32 -> f16 (optional lo plane); batched over blockIdx.z
// ---------------------------------------------------------------------------
template<int SPLIT>
__global__ __launch_bounds__(256)
void transpose_kernel(const float* __restrict__ in, int R, int Cc,
                      f16* __restrict__ oh, f16* __restrict__ ol) {
  __shared__ float tile[32][33];
  const size_t mat = (size_t)blockIdx.z * R * Cc;
  in += mat; oh += mat; if (SPLIT) ol += mat;
  const int tx = threadIdx.x & 31, ty = threadIdx.x >> 5;
  const int c = blockIdx.x * 32 + tx;
  #pragma unroll
  for (int j = 0; j < 32; j += 8) {
    const int r = blockIdx.y * 32 + ty + j;
    tile[ty + j][tx] = in[(size_t)r * Cc + c];
  }
  __syncthreads();
  const int rT = blockIdx.y * 32 + tx;
  #pragma unroll
  for (int j = 0; j < 32; j += 8) {
    const int cT = blockIdx.x * 32 + ty + j;
    const float v = tile[tx][ty + j];
    const f16 hv = (f16)v;
    oh[(size_t)cT * R + rT] = hv;
    if (SPLIT) ol[(size_t)cT * R + rT] = (f16)(v - (float)hv);
  }
}

// conv weights [O,I,3] -> BT[o][tap*1024+i] hi/lo
__global__ __launch_bounds__(256)
void convw_kernel(const float* __restrict__ w, f16* __restrict__ oh, f16* __restrict__ ol) {
  const int id = blockIdx.x * 256 + threadIdx.x;  // 1024*1024
  const int o = id >> 10, i = id & 1023;
  const float* ws = w + (size_t)o * 3072 + i * 3;
  #pragma unroll
  for (int tap = 0; tap < 3; ++tap) {
    const float v = ws[tap];
    const f16 hv = (f16)v;
    const size_t oi = (size_t)o * 3072 + tap * 1024 + i;
    oh[oi] = hv;
    ol[oi] = (f16)(v - (float)hv);
  }
}

__global__ void qkvrows_kernel(int* __restrict__ rows) {
  const int r = blockIdx.x * 256 + threadIdx.x;
  if (r < 4352) rows[r] = (r >= 2176) ? (4096 + r - 2176) : r;
}

// ---------------------------------------------------------------------------
// gate finalize: per-token top-2/softmax/entropy from fused logits; counts
// via LDS histogram + 8 global atomics per block (contention fix).
// ---------------------------------------------------------------------------
__global__ __launch_bounds__(256)
void gatefin_kernel(const float* __restrict__ logits, float* __restrict__ top2p,
                    int* __restrict__ top2i, float* __restrict__ ent,
                    int* __restrict__ counts) {
  __shared__ int hist[8];
  const int t = threadIdx.x;
  if (t < 8) hist[t] = 0;
  __syncthreads();
  const int token = blockIdx.x * 256 + t;
  float lg[8];
  const float4 l0 = ((const float4*)(logits + (size_t)token * 8))[0];
  const float4 l1 = ((const float4*)(logits + (size_t)token * 8))[1];
  lg[0] = l0.x; lg[1] = l0.y; lg[2] = l0.z; lg[3] = l0.w;
  lg[4] = l1.x; lg[5] = l1.y; lg[6] = l1.z; lg[7] = l1.w;
  int i0 = 0; float v0 = lg[0];
  #pragma unroll
  for (int e = 1; e < 8; ++e) if (lg[e] > v0) { v0 = lg[e]; i0 = e; }
  int i1 = 0; float v1 = -1e30f;
  #pragma unroll
  for (int e = 0; e < 8; ++e) if (e != i0 && lg[e] > v1) { v1 = lg[e]; i1 = e; }
  float den = 0.0f; float pr[8];
  #pragma unroll
  for (int e = 0; e < 8; ++e) { pr[e] = expf(lg[e] - v0); den += pr[e]; }
  const float dinv = 1.0f / den;
  float H = 0.0f, p0 = 0.0f, p1 = 0.0f;
  #pragma unroll
  for (int e = 0; e < 8; ++e) {
    const float p = pr[e] * dinv;
    H -= p * logf(p + 1e-10f);
    if (e == i0) p0 = p;
    if (e == i1) p1 = p;
  }
  ent[token] = H;
  top2p[token * 2] = p0; top2p[token * 2 + 1] = p1;
  top2i[token * 2] = i0; top2i[token * 2 + 1] = i1;
  atomicAdd(&hist[i0], 1);
  atomicAdd(&hist[i1], 1);
  __syncthreads();
  if (t < 8) atomicAdd(&counts[t], hist[t]);
}

// scan: entropy mean (fixed order), offsets, aux, tile table
__global__ __launch_bounds__(256)
void scan_kernel(const float* __restrict__ ent, const int* __restrict__ counts,
                 int* __restrict__ offs, TileInfo* __restrict__ table, float* __restrict__ auxout) {
  __shared__ float red[256];
  const int t = threadIdx.x;
  float s = 0.0f;
  for (int k = 0; k < 32; ++k) s += ent[t + (k << 8)];
  red[t] = s; __syncthreads();
  for (int hh = 128; hh > 0; hh >>= 1) { if (t < hh) red[t] += red[t + hh]; __syncthreads(); }
  if (t == 0) {
    const float entmean = red[0] * (1.0f / 8192.0f);
    float pen = 0.0f; int off = 0; int nt = 0;
    for (int e = 0; e < 8; ++e) {
      const int c = counts[e];
      offs[e] = off;
      for (int m = 0; m < c; m += 128) {
        table[nt].m0 = off + m;
        table[nt].mcnt = (c - m < 128) ? (c - m) : 128;
        table[nt].e = e; table[nt].pad = 0;
        ++nt;
      }
      off += c;
      const float fr = (float)c * (1.0f / 8192.0f) - 0.3f;
      pen += (fr > 0.0f) ? fr : 0.0f;
    }
    for (; nt < 160; ++nt) { table[nt].m0 = 0; table[nt].mcnt = 0; table[nt].e = 0; table[nt].pad = 0; }
    auxout[0] = 0.1f * entmean + pen;
  }
}

// scatter: block-local LDS ranks + one chunk-reservation atomic per expert
__global__ __launch_bounds__(256)
void scatter_kernel(const int* __restrict__ top2i, const int* __restrict__ offs,
                    int* __restrict__ fill, int* __restrict__ moe_rows,
                    int* __restrict__ row2slot) {
  __shared__ int hist[8];
  __shared__ int base[8];
  const int t = threadIdx.x;
  if (t < 8) hist[t] = 0;
  __syncthreads();
  const int id = blockIdx.x * 256 + t;  // 16384
  const int e = top2i[id];
  const int myrank = atomicAdd(&hist[e], 1);
  __syncthreads();
  if (t < 8) base[t] = atomicAdd(&fill[t], hist[t]);
  __syncthreads();
  const int row = offs[e] + base[e] + myrank;
  moe_rows[row] = id >> 1;
  row2slot[id] = row;
}

// x3 = x2 + p0*eo[r0] + p1*eo[r1]; also f16 copy for FF1
__global__ __launch_bounds__(256)
void combine_kernel(const float* __restrict__ x2, const f16* __restrict__ eo,
                    const float* __restrict__ top2p, const int* __restrict__ row2slot,
                    float* __restrict__ x3, f16* __restrict__ x3h) {
  const int n = blockIdx.x;
  const int t = threadIdx.x;
  const int r0 = row2slot[n * 2], r1 = row2slot[n * 2 + 1];
  const float p0 = top2p[n * 2], p1 = top2p[n * 2 + 1];
  const float4 xv = ((const float4*)(x2 + (size_t)n * 1024))[t];
  const f16x4 e0 = ((const f16x4*)(eo + (size_t)r0 * 1024))[t];
  const f16x4 e1 = ((const f16x4*)(eo + (size_t)r1 * 1024))[t];
  float4 o;
  o.x = xv.x + p0 * (float)e0[0] + p1 * (float)e1[0];
  o.y = xv.y + p0 * (float)e0[1] + p1 * (float)e1[1];
  o.z = xv.z + p0 * (float)e0[2] + p1 * (float)e1[2];
  o.w = xv.w + p0 * (float)e0[3] + p1 * (float)e1[3];
  ((float4*)(x3 + (size_t)n * 1024))[t] = o;
  f16x4 hv; hv[0] = (f16)o.x; hv[1] = (f16)o.y; hv[2] = (f16)o.z; hv[3] = (f16)o.w;
  ((f16x4*)(x3h + (size_t)n * 1024))[t] = hv;
}

// ---------------------------------------------------------------------------
extern "C" void kernel_launch(void* const* d_in, const int* in_sizes, int n_in,
                              void* d_out, int out_size, void* d_ws, size_t ws_size,
                              hipStream_t stream) {
  (void)in_sizes; (void)n_in; (void)out_size; (void)ws_size;
  const float* x     = (const float*)d_in[0];
  const float* g1    = (const float*)d_in[1];
  const float* b1    = (const float*)d_in[2];
  const float* g2    = (const float*)d_in[3];
  const float* b2    = (const float*)d_in[4];
  const float* g3    = (const float*)d_in[5];
  const float* b3    = (const float*)d_in[6];
  const float* Wqkv  = (const float*)d_in[7];
  const float* bqkv  = (const float*)d_in[8];
  const float* Wo    = (const float*)d_in[9];
  const float* bo    = (const float*)d_in[10];
  const float* convw = (const float*)d_in[11];
  const float* convb = (const float*)d_in[12];
  const float* gateW = (const float*)d_in[13];
  const float* gateb = (const float*)d_in[14];
  const float* expW  = (const float*)d_in[15];
  const float* expb  = (const float*)d_in[16];
  const float* ffW1  = (const float*)d_in[17];
  const float* ffb1  = (const float*)d_in[18];
  const float* ffW2  = (const float*)d_in[19];
  const float* ffb2  = (const float*)d_in[20];
  float* out = (float*)d_out;

  char* W = (char*)d_ws;
  f16* wqkvT_h = (f16*)(W + 0);
  f16* wqkvT_l = (f16*)(W + 6291456);
  f16* woT_h   = (f16*)(W + 12582912);
  f16* woT_l   = (f16*)(W + 14680064);
  f16* wcvT_h  = (f16*)(W + 16777216);
  f16* wcvT_l  = (f16*)(W + 23068672);
  f16* wexpT   = (f16*)(W + 29360128);
  f16* wff1T   = (f16*)(W + 46137344);
  f16* wff2T   = (f16*)(W + 54525952);
  char* META   = W + 62914560;
  int* counts    = (int*)(META);
  int* fill      = (int*)(META + 32);
  int* offs      = (int*)(META + 64);
  TileInfo* table = (TileInfo*)(META + 128);
  char* zbuf     = META + 3072;          // 1KB zeros (covered by memset below)
  int* qkv_rows  = (int*)(META + 4096);
  float* ent     = (float*)(META + 24576);
  float* top2p   = (float*)(META + 57344);
  int* top2i     = (int*)(META + 122880);
  int* moe_rows  = (int*)(META + 188416);
  int* row2slot  = (int*)(META + 253952);
  float* logits  = (float*)(META + 327680);   // 8192*8 f32 = 256KB
  char* SA = W + 63963136;    // 32 MB: ln1/ln2 hi|lo ; ln3_hi | x3_hi
  char* SB = W + 97517568;    // 64 MB: qkv f32 -> x2 f32 -> h f16
  char* SC = W + 164626432;   // 32 MB: attn hi|lo
  char* SD = W + 198180864;   // 32 MB: x1 f32 -> eo f16
  char* SE = W + 231735296;   // 32 MB: x3 f32

  f16* ln1h = (f16*)SA;            f16* ln1l = (f16*)(SA + 16777216);
  f16* ln2h = ln1h;                f16* ln2l = ln1l;
  f16* ln3h = ln1h;                f16* x3h  = (f16*)(SA + 16777216);
  float* qkvbuf = (float*)SB;
  float* x2buf  = (float*)SB;
  f16*   hbuf   = (f16*)SB;
  f16* attnh = (f16*)SC;           f16* attnl = (f16*)(SC + 16777216);
  float* x1 = (float*)SD;
  f16* eobuf = (f16*)SD;
  float* x3 = (float*)SE;

  // zero: counts(32) + fill(32) + zbuf(@3072..4096); single memset covers 0..4096
  hipMemsetAsync((void*)META, 0, 4096, stream);

  dim3 blk(256);
  // weight prep
  transpose_kernel<1><<<dim3(96, 32, 1), blk, 0, stream>>>(Wqkv, 1024, 3072, wqkvT_h, wqkvT_l);
  transpose_kernel<1><<<dim3(32, 32, 1), blk, 0, stream>>>(Wo, 1024, 1024, woT_h, woT_l);
  convw_kernel<<<4096, blk, 0, stream>>>(convw, wcvT_h, wcvT_l);
  transpose_kernel<0><<<dim3(32, 32, 8), blk, 0, stream>>>(expW, 1024, 1024, wexpT, nullptr);
  transpose_kernel<0><<<dim3(128, 32, 1), blk, 0, stream>>>(ffW1, 1024, 4096, wff1T, nullptr);
  transpose_kernel<0><<<dim3(32, 128, 1), blk, 0, stream>>>(ffW2, 4096, 1024, wff2T, nullptr);
  qkvrows_kernel<<<17, blk, 0, stream>>>(qkv_rows);

  // LN1 -> split planes
  ln_kernel<1, 0><<<8192, blk, 0, stream>>>(x, g1, b1, ln1h, ln1l, nullptr, nullptr, nullptr);
  // QKV (rows 0..2175 per batch), split GEMM, fp32 out
  gemm_kernel<3, 1, 0><<<dim3(34, 24), blk, 0, stream>>>(ln1h, ln1l, 1024, wqkvT_h, wqkvT_l, 1024,
      bqkv, nullptr, qkvbuf, nullptr, 3072, 1024, qkv_rows, nullptr, nullptr);
  // attention
  attn_kernel<<<512, blk, 0, stream>>>(qkvbuf, attnh, attnl);
  // Wo projection + residual -> x1
  gemm_kernel<3, 0, 1><<<dim3(64, 8), blk, 0, stream>>>(attnh, attnl, 1024, woT_h, woT_l, 1024,
      bo, x, x1, nullptr, 1024, 1024, nullptr, nullptr, nullptr);
  // LN2
  ln_kernel<1, 0><<<8192, blk, 0, stream>>>(x1, g2, b2, ln2h, ln2l, nullptr, nullptr, nullptr);
  // conv (3-tap shifted GEMM, exact zero-pad) + residual -> x2
  gemm_kernel<3, 3, 1><<<dim3(64, 8), blk, 0, stream>>>(ln2h, ln2l, 1024, wcvT_h, wcvT_l, 3072,
      convb, x1, x2buf, nullptr, 1024, 3072, nullptr, nullptr, zbuf);
  // LN3 fused with gate logits (f16 hi for experts + logits for routing)
  ln_kernel<0, 1><<<8192, blk, 0, stream>>>(x2buf, g3, b3, ln3h, nullptr, gateW, gateb, logits);
  // gate finalize / scan / scatter
  gatefin_kernel<<<32, blk, 0, stream>>>(logits, top2p, top2i, ent, counts);
  scan_kernel<<<1, blk, 0, stream>>>(ent, counts, offs, table, out + 8388608);
  scatter_kernel<<<64, blk, 0, stream>>>(top2i, offs, fill, moe_rows, row2slot);
  // grouped expert GEMM -> eo (f16)
  gemm_kernel<1, 2, 2><<<dim3(136, 8), blk, 0, stream>>>(ln3h, nullptr, 1024, wexpT, nullptr, 1024,
      expb, nullptr, nullptr, eobuf, 1024, 1024, moe_rows, table, nullptr);
  // combine -> x3 (+f16)
  combine_kernel<<<8192, blk, 0, stream>>>(x2buf, eobuf, top2p, row2slot, x3, x3h);
  // FF1 (gelu) -> h
  gemm_kernel<1, 0, 3><<<dim3(64, 32), blk, 0, stream>>>(x3h, nullptr, 1024, wff1T, nullptr, 1024,
      ffb1, nullptr, nullptr, hbuf, 4096, 1024, nullptr, nullptr, nullptr);
  // FF2 + residual -> final output
  gemm_kernel<1, 0, 1><<<dim3(64, 8), blk, 0, stream>>>(hbuf, nullptr, 4096, wff2T, nullptr, 4096,
      ffb2, x3, out, nullptr, 1024, 4096, nullptr, nullptr, nullptr);
}

// Round 6
// 804.224 us; speedup vs baseline: 2.1102x; 1.0885x over previous
//
#include <hip/hip_runtime.h>
#include <cmath>

typedef _Float16 f16;
typedef __attribute__((ext_vector_type(8))) _Float16 f16x8;
typedef __attribute__((ext_vector_type(4))) _Float16 f16x4;
typedef __attribute__((ext_vector_type(4))) float f32x4;

struct TileInfo { int m0, mcnt, e, pad; };

__device__ __forceinline__ void gload16(const void* g, void* l) {
  __builtin_amdgcn_global_load_lds((const __attribute__((address_space(1))) void*)g,
                                   (__attribute__((address_space(3))) void*)l, 16, 0, 0);
}

// fast gelu: 0.5u(1+tanh(c)) = u*e/(e+1), e=exp(2c), c=0.79788456(u+0.044715u^3)
__device__ __forceinline__ float fast_gelu(float u) {
  const float c = u * (0.7978845608028654f + 0.0356774081f * u * u);
  const float t = fminf(2.0f * c, 80.0f);
  const float e = __expf(t);
  return u * (e * __builtin_amdgcn_rcpf(e + 1.0f));
}

// ---------------------------------------------------------------------------
// Unified GEMM (unchanged from R4): see previous rounds for doc.
// ---------------------------------------------------------------------------
template<int NPASS, int MODE, int EPI>
__global__ __launch_bounds__(256)
void gemm_kernel(const f16* __restrict__ Ah, const f16* __restrict__ Al, int lda,
                 const f16* __restrict__ Bh, const f16* __restrict__ Bl, int ldb,
                 const float* __restrict__ bias, const float* __restrict__ res,
                 float* __restrict__ outf, f16* __restrict__ outh, int ldo, int K,
                 const int* __restrict__ rowmap, const TileInfo* __restrict__ table,
                 const char* __restrict__ zbuf) {
  constexpr int BK = 64;
  constexpr int RB = BK * 2;
  constexpr int TB = 128 * RB;
  constexpr int ROUNDS = TB / 4096;
  constexpr int TPR = RB / 16;
  constexpr int RPR = 4096 / RB;
  constexpr int SWM = TPR - 1;
  constexpr int LA  = 0;
  constexpr int LAL = (NPASS == 3) ? TB : 0;
  constexpr int LB  = (NPASS == 3) ? 2 * TB : TB;
  constexpr int LBL = (NPASS == 3) ? 3 * TB : 0;

  __shared__ __align__(16) char lds[(NPASS == 3) ? 65536 : 32768];

  const int tid  = threadIdx.x;
  const int wave = tid >> 6;
  const int lane = tid & 63;

  int m0, mcnt, eidx = 0;
  if (MODE == 2) {
    TileInfo ti = table[blockIdx.x];
    if (ti.mcnt <= 0) return;
    m0 = ti.m0; mcnt = ti.mcnt; eidx = ti.e;
  } else { m0 = blockIdx.x * 128; mcnt = 128; }
  const int n0 = blockIdx.y * 128;

  const f16* Bh_ = Bh;
  const float* bias_ = bias;
  size_t adelta = 0, bdelta = 0;
  if (NPASS == 3) {
    adelta = (size_t)((const char*)Al - (const char*)Ah);
    bdelta = (size_t)((const char*)Bl - (const char*)Bh);
  }
  if (MODE == 2) { Bh_ += ((size_t)eidx << 20); bias_ += eidx * 1024; }

  const int sr    = tid / TPR;
  const int cbyte = (tid % TPR) * 16;

  const char* aSrc[ROUNDS];
  const char* bSrc[ROUNDS];
  int aRowC[ROUNDS]; int aCbs[ROUNDS];
  #pragma unroll
  for (int r = 0; r < ROUNDS; ++r) {
    const int mr  = sr + r * RPR;
    const int cbs = cbyte ^ ((mr & SWM) << 4);
    int gi = m0 + ((mr < mcnt) ? mr : (mcnt - 1));
    if (MODE == 1 || MODE == 2) gi = rowmap[gi];
    if (MODE == 3) { aRowC[r] = gi; aCbs[r] = cbs; aSrc[r] = nullptr; }
    else           { aSrc[r] = (const char*)Ah + (size_t)gi * lda * 2 + cbs; aRowC[r] = 0; aCbs[r] = 0; }
    const int nr   = sr + r * RPR;
    const int ncbs = cbyte ^ ((nr & SWM) << 4);
    bSrc[r] = (const char*)Bh_ + (size_t)(n0 + nr) * ldb * 2 + ncbs;
  }

  f32x4 acc[4][4] = {};
  const int wm  = (wave >> 1) * 64;
  const int wn  = (wave & 1) * 64;
  const int fr  = lane & 15;
  const int kgb = (lane >> 4) * 16;

  for (int k0 = 0; k0 < K; k0 += BK) {
    #pragma unroll
    for (int r = 0; r < ROUNDS; ++r) {
      const char* as;
      const char* asl = nullptr;
      if (MODE == 3) {
        const int tap = k0 >> 10;
        const int kc  = k0 & 1023;
        const int tok = aRowC[r] & 4095;
        const int st  = tok + (tap - 1) * 2;
        if (st >= 0 && st < 4096) {
          as  = (const char*)Ah + (size_t)(aRowC[r] + (tap - 1) * 2) * 2048 + kc * 2 + aCbs[r];
          asl = as + adelta;
        } else {
          as  = zbuf;
          asl = zbuf;
        }
      } else {
        as = aSrc[r] + (size_t)k0 * 2;
        if (NPASS == 3) asl = as + adelta;
      }
      gload16(as, lds + LA + r * 4096 + wave * 1024);
      if (NPASS == 3) gload16(asl, lds + LAL + r * 4096 + wave * 1024);
      const char* bs = bSrc[r] + (size_t)k0 * 2;
      gload16(bs, lds + LB + r * 4096 + wave * 1024);
      if (NPASS == 3) gload16(bs + bdelta, lds + LBL + r * 4096 + wave * 1024);
    }
    __syncthreads();
    #pragma unroll
    for (int kk = 0; kk < BK / 32; ++kk) {
      f16x8 ah[4], bh[4], al[4], bl[4];
      #pragma unroll
      for (int i = 0; i < 4; ++i) {
        const int ar = wm + i * 16 + fr;
        const int ao = ar * RB + ((kk * 64 + kgb) ^ ((ar & SWM) << 4));
        ah[i] = *(const f16x8*)(lds + LA + ao);
        if (NPASS == 3) al[i] = *(const f16x8*)(lds + LAL + ao);
        const int br = wn + i * 16 + fr;
        const int bo = br * RB + ((kk * 64 + kgb) ^ ((br & SWM) << 4));
        bh[i] = *(const f16x8*)(lds + LB + bo);
        if (NPASS == 3) bl[i] = *(const f16x8*)(lds + LBL + bo);
      }
      #pragma unroll
      for (int i = 0; i < 4; ++i) {
        #pragma unroll
        for (int j = 0; j < 4; ++j) {
          acc[i][j] = __builtin_amdgcn_mfma_f32_16x16x32_f16(ah[i], bh[j], acc[i][j], 0, 0, 0);
          if (NPASS == 3) {
            acc[i][j] = __builtin_amdgcn_mfma_f32_16x16x32_f16(ah[i], bl[j], acc[i][j], 0, 0, 0);
            acc[i][j] = __builtin_amdgcn_mfma_f32_16x16x32_f16(al[i], bh[j], acc[i][j], 0, 0, 0);
          }
        }
      }
    }
    __syncthreads();
  }

  #pragma unroll
  for (int i = 0; i < 4; ++i) {
    const int mb = wm + i * 16 + (lane >> 4) * 4;
    #pragma unroll
    for (int j = 0; j < 4; ++j) {
      const int nc = n0 + wn + j * 16 + fr;
      const float bv = bias_[nc];
      #pragma unroll
      for (int q = 0; q < 4; ++q) {
        const int ml = mb + q;
        if (MODE == 2 && ml >= mcnt) continue;
        const size_t orow = (size_t)(m0 + ml);
        float v = acc[i][j][q] + bv;
        if (EPI == 1) v += res[orow * ldo + nc];
        if (EPI == 3) v = fast_gelu(v);
        if (EPI <= 1) outf[orow * ldo + nc] = v;
        else          outh[orow * ldo + nc] = (f16)v;
      }
    }
  }
}

// ---------------------------------------------------------------------------
// LayerNorm (unchanged)
// ---------------------------------------------------------------------------
template<int WLO, int WGATE>
__global__ __launch_bounds__(256)
void ln_kernel(const float* __restrict__ x, const float* __restrict__ g, const float* __restrict__ b,
               f16* __restrict__ oh, f16* __restrict__ ol,
               const float* __restrict__ gW, const float* __restrict__ gb,
               float* __restrict__ logits) {
  const int row = blockIdx.x;
  const int t = threadIdx.x;
  const float4 v = ((const float4*)(x + (size_t)row * 1024))[t];
  float s  = v.x + v.y + v.z + v.w;
  float ss = v.x * v.x + v.y * v.y + v.z * v.z + v.w * v.w;
  #pragma unroll
  for (int off = 32; off; off >>= 1) { s += __shfl_down(s, off, 64); ss += __shfl_down(ss, off, 64); }
  __shared__ float red[8];
  if ((t & 63) == 0) { red[t >> 6] = s; red[(t >> 6) + 4] = ss; }
  __syncthreads();
  s  = red[0] + red[1] + red[2] + red[3];
  ss = red[4] + red[5] + red[6] + red[7];
  const float mu  = s * (1.0f / 1024.0f);
  const float var = ss * (1.0f / 1024.0f) - mu * mu;
  const float inv = 1.0f / sqrtf(var + 1e-5f);
  const float4 gv = ((const float4*)g)[t];
  const float4 bv = ((const float4*)b)[t];
  float y[4];
  y[0] = (v.x - mu) * inv * gv.x + bv.x;
  y[1] = (v.y - mu) * inv * gv.y + bv.y;
  y[2] = (v.z - mu) * inv * gv.z + bv.z;
  y[3] = (v.w - mu) * inv * gv.w + bv.w;
  f16x4 hv;
  #pragma unroll
  for (int u = 0; u < 4; ++u) hv[u] = (f16)y[u];
  *(f16x4*)(oh + (size_t)row * 1024 + t * 4) = hv;
  if (WLO) {
    f16x4 lv;
    #pragma unroll
    for (int u = 0; u < 4; ++u) lv[u] = (f16)(y[u] - (float)hv[u]);
    *(f16x4*)(ol + (size_t)row * 1024 + t * 4) = lv;
  }
  if (WGATE) {
    const float* gr = gW + (size_t)(t * 4) * 8;
    float lg[8];
    #pragma unroll
    for (int e = 0; e < 8; ++e)
      lg[e] = y[0] * gr[e] + y[1] * gr[8 + e] + y[2] * gr[16 + e] + y[3] * gr[24 + e];
    #pragma unroll
    for (int m = 1; m < 64; m <<= 1)
      #pragma unroll
      for (int e = 0; e < 8; ++e) lg[e] += __shfl_xor(lg[e], m, 64);
    __shared__ float gred[4][8];
    if ((t & 63) == 0) {
      #pragma unroll
      for (int e = 0; e < 8; ++e) gred[t >> 6][e] = lg[e];
    }
    __syncthreads();
    if (t < 8)
      logits[(size_t)row * 8 + t] = gred[0][t] + gred[1][t] + gred[2][t] + gred[3][t] + gb[t];
  }
}

// ---------------------------------------------------------------------------
// Windowed attention, restructured: 512 thr/block, natural [s][ch] staging,
// outer-product QK (2d x 4e per thread), in-register softmax (shfl width 16),
// P staged to LDS, PV with e-contiguous dot4 (4s x 4d per thread). All fp32.
// LDS: SQ/SV @0 (32KB), SK @32768 (32KB), P @65536 (16KB) -> 80KB.
// ---------------------------------------------------------------------------
__global__ __launch_bounds__(512, 4)
void attn_kernel(const float* __restrict__ qkv, f16* __restrict__ oh, f16* __restrict__ ol) {
  __shared__ __align__(16) char sm[81920];
  const int bid = blockIdx.x;
  const int b = bid >> 8, h = (bid >> 4) & 15, n = bid & 15;
  const int t = threadIdx.x;
  const size_t rowbase = (size_t)(b * 2176 + n * 128);
  const char* qg = (const char*)(qkv + rowbase * 3072 + h * 64);
  const char* kg = qg + 4096;
  const char* vg = qg + 8192;

  const int srow = t >> 4;            // staging row within 32-row pass
  const int scol = (t & 15) * 16;     // staging byte col
  const int wuni = (t >> 6) * 1024;   // wave-uniform LDS dest portion

  // ---- QK: pacc[d=dt*2+i][e=et*4+z] ----
  const int dt = t >> 4;   // 0..31
  const int et = t & 15;   // 0..15
  float pacc[2][4] = {};

  for (int r = 0; r < 2; ++r) {
    #pragma unroll
    for (int p = 0; p < 4; ++p) {
      const size_t off = (size_t)(r * 128 + p * 32 + srow) * 12288 + scol;
      gload16(qg + off, sm + p * 8192 + wuni);
      gload16(kg + off, sm + 32768 + p * 8192 + wuni);
    }
    __syncthreads();
    #pragma unroll 4
    for (int s = 0; s < 128; ++s) {
      const float2 q2 = *(const float2*)(sm + s * 256 + dt * 8);
      const f32x4 k4 = *(const f32x4*)(sm + 32768 + s * 256 + et * 16);
      #pragma unroll
      for (int z = 0; z < 4; ++z) {
        pacc[0][z] += q2.x * k4[z];
        pacc[1][z] += q2.y * k4[z];
      }
    }
    __syncthreads();
  }

  // ---- softmax over e (row d lives in the 16-lane et group) ----
  #pragma unroll
  for (int i = 0; i < 2; ++i) {
    #pragma unroll
    for (int z = 0; z < 4; ++z) pacc[i][z] *= 0.125f;
    float m = fmaxf(fmaxf(pacc[i][0], pacc[i][1]), fmaxf(pacc[i][2], pacc[i][3]));
    m = fmaxf(m, __shfl_xor(m, 1, 16));
    m = fmaxf(m, __shfl_xor(m, 2, 16));
    m = fmaxf(m, __shfl_xor(m, 4, 16));
    m = fmaxf(m, __shfl_xor(m, 8, 16));
    float den = 0.0f;
    #pragma unroll
    for (int z = 0; z < 4; ++z) { pacc[i][z] = expf(pacc[i][z] - m); den += pacc[i][z]; }
    den += __shfl_xor(den, 1, 16);
    den += __shfl_xor(den, 2, 16);
    den += __shfl_xor(den, 4, 16);
    den += __shfl_xor(den, 8, 16);
    const float dinv = 1.0f / den;
    f32x4 pv;
    #pragma unroll
    for (int z = 0; z < 4; ++z) pv[z] = pacc[i][z] * dinv;
    *(f32x4*)(sm + 65536 + (dt * 2 + i) * 256 + et * 16) = pv;
  }

  // ---- PV: o[s=st*4+j][d=dt2*4+i], e-contiguous dot4 ----
  const int dt2 = t & 15;
  const int st  = t >> 4;  // 0..31
  const int ch  = h * 64 + (st & 15) * 4;
  const size_t rb2 = (size_t)(b * 4096 + n * 256);

  for (int c = 0; c < 2; ++c) {
    __syncthreads();   // prev V reads done (c=1); P writes + QK reads done (c=0)
    #pragma unroll
    for (int p = 0; p < 4; ++p) {
      const size_t off = (size_t)(c * 128 + p * 32 + srow) * 12288 + scol;
      gload16(vg + off, sm + p * 8192 + wuni);
    }
    __syncthreads();
    float o[16];
    #pragma unroll
    for (int u = 0; u < 16; ++u) o[u] = 0.0f;
    #pragma unroll 2
    for (int e4 = 0; e4 < 16; ++e4) {
      f32x4 p4[4], v4[4];
      #pragma unroll
      for (int i = 0; i < 4; ++i)
        p4[i] = *(const f32x4*)(sm + 65536 + (dt2 * 4 + i) * 256 + e4 * 16);
      #pragma unroll
      for (int j = 0; j < 4; ++j)
        v4[j] = *(const f32x4*)(sm + (st * 4 + j) * 256 + e4 * 16);
      #pragma unroll
      for (int j = 0; j < 4; ++j)
        #pragma unroll
        for (int i = 0; i < 4; ++i) {
          o[j * 4 + i] += v4[j][0] * p4[i][0] + v4[j][1] * p4[i][1]
                        + v4[j][2] * p4[i][2] + v4[j][3] * p4[i][3];
        }
    }
    // write: row = b*4096 + n*256 + d*4 + (s>>6); ch = h*64 + (s&63)
    const int rq = c * 2 + (st >> 4);
    #pragma unroll
    for (int i = 0; i < 4; ++i) {
      const size_t row = rb2 + (size_t)(dt2 * 4 + i) * 4 + rq;
      f16x4 hv, lv;
      #pragma unroll
      for (int j = 0; j < 4; ++j) {
        const float val = o[j * 4 + i];
        hv[j] = (f16)val;
        lv[j] = (f16)(val - (float)hv[j]);
      }
      *(f16x4*)(oh + row * 1024 + ch) = hv;
      *(f16x4*)(ol + row * 1024 + ch) = lv;
    }
  }
}

// ---------------------------------------------------------------------------
// weight transposes fp32 -> f16 (optional lo plane); batched over blockIdx.z
// ---------------------------------------------------------------------------
template<int SPLIT>
__global__ __launch_bounds__(256)
void transpose_kernel(const float* __restrict__ in, int R, int Cc,
                      f16* __restrict__ oh, f16* __restrict__ ol) {
  __shared__ float tile[32][33];
  const size_t mat = (size_t)blockIdx.z * R * Cc;
  in += mat; oh += mat; if (SPLIT) ol += mat;
  const int tx = threadIdx.x & 31, ty = threadIdx.x >> 5;
  const int c = blockIdx.x * 32 + tx;
  #pragma unroll
  for (int j = 0; j < 32; j += 8) {
    const int r = blockIdx.y * 32 + ty + j;
    tile[ty + j][tx] = in[(size_t)r * Cc + c];
  }
  __syncthreads();
  const int rT = blockIdx.y * 32 + tx;
  #pragma unroll
  for (int j = 0; j < 32; j += 8) {
    const int cT = blockIdx.x * 32 + ty + j;
    const float v = tile[tx][ty + j];
    const f16 hv = (f16)v;
    oh[(size_t)cT * R + rT] = hv;
    if (SPLIT) ol[(size_t)cT * R + rT] = (f16)(v - (float)hv);
  }
}

// conv weights [O,I,3] -> BT[o][tap*1024+i] hi/lo
__global__ __launch_bounds__(256)
void convw_kernel(const float* __restrict__ w, f16* __restrict__ oh, f16* __restrict__ ol) {
  const int id = blockIdx.x * 256 + threadIdx.x;
  const int o = id >> 10, i = id & 1023;
  const float* ws = w + (size_t)o * 3072 + i * 3;
  #pragma unroll
  for (int tap = 0; tap < 3; ++tap) {
    const float v = ws[tap];
    const f16 hv = (f16)v;
    const size_t oi = (size_t)o * 3072 + tap * 1024 + i;
    oh[oi] = hv;
    ol[oi] = (f16)(v - (float)hv);
  }
}

__global__ void qkvrows_kernel(int* __restrict__ rows) {
  const int r = blockIdx.x * 256 + threadIdx.x;
  if (r < 4352) rows[r] = (r >= 2176) ? (4096 + r - 2176) : r;
}

// ---------------------------------------------------------------------------
// gate finalize
// ---------------------------------------------------------------------------
__global__ __launch_bounds__(256)
void gatefin_kernel(const float* __restrict__ logits, float* __restrict__ top2p,
                    int* __restrict__ top2i, float* __restrict__ ent,
                    int* __restrict__ counts) {
  __shared__ int hist[8];
  const int t = threadIdx.x;
  if (t < 8) hist[t] = 0;
  __syncthreads();
  const int token = blockIdx.x * 256 + t;
  float lg[8];
  const float4 l0 = ((const float4*)(logits + (size_t)token * 8))[0];
  const float4 l1 = ((const float4*)(logits + (size_t)token * 8))[1];
  lg[0] = l0.x; lg[1] = l0.y; lg[2] = l0.z; lg[3] = l0.w;
  lg[4] = l1.x; lg[5] = l1.y; lg[6] = l1.z; lg[7] = l1.w;
  int i0 = 0; float v0 = lg[0];
  #pragma unroll
  for (int e = 1; e < 8; ++e) if (lg[e] > v0) { v0 = lg[e]; i0 = e; }
  int i1 = 0; float v1 = -1e30f;
  #pragma unroll
  for (int e = 0; e < 8; ++e) if (e != i0 && lg[e] > v1) { v1 = lg[e]; i1 = e; }
  float den = 0.0f; float pr[8];
  #pragma unroll
  for (int e = 0; e < 8; ++e) { pr[e] = expf(lg[e] - v0); den += pr[e]; }
  const float dinv = 1.0f / den;
  float H = 0.0f, p0 = 0.0f, p1 = 0.0f;
  #pragma unroll
  for (int e = 0; e < 8; ++e) {
    const float p = pr[e] * dinv;
    H -= p * logf(p + 1e-10f);
    if (e == i0) p0 = p;
    if (e == i1) p1 = p;
  }
  ent[token] = H;
  top2p[token * 2] = p0; top2p[token * 2 + 1] = p1;
  top2i[token * 2] = i0; top2i[token * 2 + 1] = i1;
  atomicAdd(&hist[i0], 1);
  atomicAdd(&hist[i1], 1);
  __syncthreads();
  if (t < 8) atomicAdd(&counts[t], hist[t]);
}

// scan: entropy mean (fixed order), offsets, aux, tile table
__global__ __launch_bounds__(256)
void scan_kernel(const float* __restrict__ ent, const int* __restrict__ counts,
                 int* __restrict__ offs, TileInfo* __restrict__ table, float* __restrict__ auxout) {
  __shared__ float red[256];
  const int t = threadIdx.x;
  float s = 0.0f;
  for (int k = 0; k < 32; ++k) s += ent[t + (k << 8)];
  red[t] = s; __syncthreads();
  for (int hh = 128; hh > 0; hh >>= 1) { if (t < hh) red[t] += red[t + hh]; __syncthreads(); }
  if (t == 0) {
    const float entmean = red[0] * (1.0f / 8192.0f);
    float pen = 0.0f; int off = 0; int nt = 0;
    for (int e = 0; e < 8; ++e) {
      const int c = counts[e];
      offs[e] = off;
      for (int m = 0; m < c; m += 128) {
        table[nt].m0 = off + m;
        table[nt].mcnt = (c - m < 128) ? (c - m) : 128;
        table[nt].e = e; table[nt].pad = 0;
        ++nt;
      }
      off += c;
      const float fr = (float)c * (1.0f / 8192.0f) - 0.3f;
      pen += (fr > 0.0f) ? fr : 0.0f;
    }
    for (; nt < 160; ++nt) { table[nt].m0 = 0; table[nt].mcnt = 0; table[nt].e = 0; table[nt].pad = 0; }
    auxout[0] = 0.1f * entmean + pen;
  }
}

// scatter: block-local LDS ranks + one chunk-reservation atomic per expert
__global__ __launch_bounds__(256)
void scatter_kernel(const int* __restrict__ top2i, const int* __restrict__ offs,
                    int* __restrict__ fill, int* __restrict__ moe_rows,
                    int* __restrict__ row2slot) {
  __shared__ int hist[8];
  __shared__ int base[8];
  const int t = threadIdx.x;
  if (t < 8) hist[t] = 0;
  __syncthreads();
  const int id = blockIdx.x * 256 + t;
  const int e = top2i[id];
  const int myrank = atomicAdd(&hist[e], 1);
  __syncthreads();
  if (t < 8) base[t] = atomicAdd(&fill[t], hist[t]);
  __syncthreads();
  const int row = offs[e] + base[e] + myrank;
  moe_rows[row] = id >> 1;
  row2slot[id] = row;
}

// x3 = x2 + p0*eo[r0] + p1*eo[r1]; also f16 copy for FF1
__global__ __launch_bounds__(256)
void combine_kernel(const float* __restrict__ x2, const f16* __restrict__ eo,
                    const float* __restrict__ top2p, const int* __restrict__ row2slot,
                    float* __restrict__ x3, f16* __restrict__ x3h) {
  const int n = blockIdx.x;
  const int t = threadIdx.x;
  const int r0 = row2slot[n * 2], r1 = row2slot[n * 2 + 1];
  const float p0 = top2p[n * 2], p1 = top2p[n * 2 + 1];
  const float4 xv = ((const float4*)(x2 + (size_t)n * 1024))[t];
  const f16x4 e0 = ((const f16x4*)(eo + (size_t)r0 * 1024))[t];
  const f16x4 e1 = ((const f16x4*)(eo + (size_t)r1 * 1024))[t];
  float4 o;
  o.x = xv.x + p0 * (float)e0[0] + p1 * (float)e1[0];
  o.y = xv.y + p0 * (float)e0[1] + p1 * (float)e1[1];
  o.z = xv.z + p0 * (float)e0[2] + p1 * (float)e1[2];
  o.w = xv.w + p0 * (float)e0[3] + p1 * (float)e1[3];
  ((float4*)(x3 + (size_t)n * 1024))[t] = o;
  f16x4 hv; hv[0] = (f16)o.x; hv[1] = (f16)o.y; hv[2] = (f16)o.z; hv[3] = (f16)o.w;
  ((f16x4*)(x3h + (size_t)n * 1024))[t] = hv;
}

// ---------------------------------------------------------------------------
extern "C" void kernel_launch(void* const* d_in, const int* in_sizes, int n_in,
                              void* d_out, int out_size, void* d_ws, size_t ws_size,
                              hipStream_t stream) {
  (void)in_sizes; (void)n_in; (void)out_size; (void)ws_size;
  const float* x     = (const float*)d_in[0];
  const float* g1    = (const float*)d_in[1];
  const float* b1    = (const float*)d_in[2];
  const float* g2    = (const float*)d_in[3];
  const float* b2    = (const float*)d_in[4];
  const float* g3    = (const float*)d_in[5];
  const float* b3    = (const float*)d_in[6];
  const float* Wqkv  = (const float*)d_in[7];
  const float* bqkv  = (const float*)d_in[8];
  const float* Wo    = (const float*)d_in[9];
  const float* bo    = (const float*)d_in[10];
  const float* convw = (const float*)d_in[11];
  const float* convb = (const float*)d_in[12];
  const float* gateW = (const float*)d_in[13];
  const float* gateb = (const float*)d_in[14];
  const float* expW  = (const float*)d_in[15];
  const float* expb  = (const float*)d_in[16];
  const float* ffW1  = (const float*)d_in[17];
  const float* ffb1  = (const float*)d_in[18];
  const float* ffW2  = (const float*)d_in[19];
  const float* ffb2  = (const float*)d_in[20];
  float* out = (float*)d_out;

  char* W = (char*)d_ws;
  f16* wqkvT_h = (f16*)(W + 0);
  f16* wqkvT_l = (f16*)(W + 6291456);
  f16* woT_h   = (f16*)(W + 12582912);
  f16* woT_l   = (f16*)(W + 14680064);
  f16* wcvT_h  = (f16*)(W + 16777216);
  f16* wcvT_l  = (f16*)(W + 23068672);
  f16* wexpT   = (f16*)(W + 29360128);
  f16* wff1T   = (f16*)(W + 46137344);
  f16* wff2T   = (f16*)(W + 54525952);
  char* META   = W + 62914560;
  int* counts    = (int*)(META);
  int* fill      = (int*)(META + 32);
  int* offs      = (int*)(META + 64);
  TileInfo* table = (TileInfo*)(META + 128);
  char* zbuf     = META + 3072;
  int* qkv_rows  = (int*)(META + 4096);
  float* ent     = (float*)(META + 24576);
  float* top2p   = (float*)(META + 57344);
  int* top2i     = (int*)(META + 122880);
  int* moe_rows  = (int*)(META + 188416);
  int* row2slot  = (int*)(META + 253952);
  float* logits  = (float*)(META + 327680);
  char* SA = W + 63963136;
  char* SB = W + 97517568;
  char* SC = W + 164626432;
  char* SD = W + 198180864;
  char* SE = W + 231735296;

  f16* ln1h = (f16*)SA;            f16* ln1l = (f16*)(SA + 16777216);
  f16* ln2h = ln1h;                f16* ln2l = ln1l;
  f16* ln3h = ln1h;                f16* x3h  = (f16*)(SA + 16777216);
  float* qkvbuf = (float*)SB;
  float* x2buf  = (float*)SB;
  f16*   hbuf   = (f16*)SB;
  f16* attnh = (f16*)SC;           f16* attnl = (f16*)(SC + 16777216);
  float* x1 = (float*)SD;
  f16* eobuf = (f16*)SD;
  float* x3 = (float*)SE;

  hipMemsetAsync((void*)META, 0, 4096, stream);

  dim3 blk(256);
  // weight prep
  transpose_kernel<1><<<dim3(96, 32, 1), blk, 0, stream>>>(Wqkv, 1024, 3072, wqkvT_h, wqkvT_l);
  transpose_kernel<1><<<dim3(32, 32, 1), blk, 0, stream>>>(Wo, 1024, 1024, woT_h, woT_l);
  convw_kernel<<<4096, blk, 0, stream>>>(convw, wcvT_h, wcvT_l);
  transpose_kernel<0><<<dim3(32, 32, 8), blk, 0, stream>>>(expW, 1024, 1024, wexpT, nullptr);
  transpose_kernel<0><<<dim3(128, 32, 1), blk, 0, stream>>>(ffW1, 1024, 4096, wff1T, nullptr);
  transpose_kernel<0><<<dim3(32, 128, 1), blk, 0, stream>>>(ffW2, 4096, 1024, wff2T, nullptr);
  qkvrows_kernel<<<17, blk, 0, stream>>>(qkv_rows);

  // LN1 -> split planes
  ln_kernel<1, 0><<<8192, blk, 0, stream>>>(x, g1, b1, ln1h, ln1l, nullptr, nullptr, nullptr);
  // QKV (rows 0..2175 per batch), split GEMM, fp32 out
  gemm_kernel<3, 1, 0><<<dim3(34, 24), blk, 0, stream>>>(ln1h, ln1l, 1024, wqkvT_h, wqkvT_l, 1024,
      bqkv, nullptr, qkvbuf, nullptr, 3072, 1024, qkv_rows, nullptr, nullptr);
  // attention (512 threads)
  attn_kernel<<<512, dim3(512), 0, stream>>>(qkvbuf, attnh, attnl);
  // Wo projection + residual -> x1
  gemm_kernel<3, 0, 1><<<dim3(64, 8), blk, 0, stream>>>(attnh, attnl, 1024, woT_h, woT_l, 1024,
      bo, x, x1, nullptr, 1024, 1024, nullptr, nullptr, nullptr);
  // LN2
  ln_kernel<1, 0><<<8192, blk, 0, stream>>>(x1, g2, b2, ln2h, ln2l, nullptr, nullptr, nullptr);
  // conv (3-tap shifted GEMM, exact zero-pad) + residual -> x2
  gemm_kernel<3, 3, 1><<<dim3(64, 8), blk, 0, stream>>>(ln2h, ln2l, 1024, wcvT_h, wcvT_l, 3072,
      convb, x1, x2buf, nullptr, 1024, 3072, nullptr, nullptr, zbuf);
  // LN3 fused with gate logits
  ln_kernel<0, 1><<<8192, blk, 0, stream>>>(x2buf, g3, b3, ln3h, nullptr, gateW, gateb, logits);
  // gate finalize / scan / scatter
  gatefin_kernel<<<32, blk, 0, stream>>>(logits, top2p, top2i, ent, counts);
  scan_kernel<<<1, blk, 0, stream>>>(ent, counts, offs, table, out + 8388608);
  scatter_kernel<<<64, blk, 0, stream>>>(top2i, offs, fill, moe_rows, row2slot);
  // grouped expert GEMM -> eo (f16)
  gemm_kernel<1, 2, 2><<<dim3(136, 8), blk, 0, stream>>>(ln3h, nullptr, 1024, wexpT, nullptr, 1024,
      expb, nullptr, nullptr, eobuf, 1024, 1024, moe_rows, table, nullptr);
  // combine -> x3 (+f16)
  combine_kernel<<<8192, blk, 0, stream>>>(x2buf, eobuf, top2p, row2slot, x3, x3h);
  // FF1 (gelu) -> h
  gemm_kernel<1, 0, 3><<<dim3(64, 32), blk, 0, stream>>>(x3h, nullptr, 1024, wff1T, nullptr, 1024,
      ffb1, nullptr, nullptr, hbuf, 4096, 1024, nullptr, nullptr, nullptr);
  // FF2 + residual -> final output
  gemm_kernel<1, 0, 1><<<dim3(64, 8), blk, 0, stream>>>(hbuf, nullptr, 4096, wff2T, nullptr, 4096,
      ffb2, x3, out, nullptr, 1024, 4096, nullptr, nullptr, nullptr);
}

// Round 7
// 741.057 us; speedup vs baseline: 2.2901x; 1.0852x over previous
//
#include <hip/hip_runtime.h>
#include <cmath>

typedef _Float16 f16;
typedef __attribute__((ext_vector_type(8))) _Float16 f16x8;
typedef __attribute__((ext_vector_type(4))) _Float16 f16x4;
typedef __attribute__((ext_vector_type(4))) float f32x4;

struct TileInfo { int m0, mcnt, e, pad; };

__device__ __forceinline__ void gload16(const void* g, void* l) {
  __builtin_amdgcn_global_load_lds((const __attribute__((address_space(1))) void*)g,
                                   (__attribute__((address_space(3))) void*)l, 16, 0, 0);
}

// fast gelu: 0.5u(1+tanh(c)) = u*e/(e+1), e=exp(2c), c=0.79788456(u+0.044715u^3)
__device__ __forceinline__ float fast_gelu(float u) {
  const float c = u * (0.7978845608028654f + 0.0356774081f * u * u);
  const float t = fminf(2.0f * c, 80.0f);
  const float e = __expf(t);
  return u * (e * __builtin_amdgcn_rcpf(e + 1.0f));
}

// ---------------------------------------------------------------------------
// Unified GEMM.  NPASS==3: single-buffered BK=64 loop (hi/lo split planes,
// fp32-faithful).  NPASS==1: double-buffered counted-vmcnt schedule —
// per iter: ds_read frags -> lgkmcnt(0) -> barrier -> issue tile kt+2 stages
// -> MFMA -> vmcnt(8) (tile kt+1 landed, kt+2 stays in flight) -> barrier.
// MODE: 0 direct, 1 rowmap, 2 tile-table (MoE), 3 conv (NPASS==3 only).
// EPI: 0 f32=acc+bias; 1 f32=res+acc+bias; 2 f16=acc+bias; 3 f16=gelu(acc+bias)
// ---------------------------------------------------------------------------
template<int NPASS, int MODE, int EPI>
__global__ __launch_bounds__(256)
void gemm_kernel(const f16* __restrict__ Ah, const f16* __restrict__ Al, int lda,
                 const f16* __restrict__ Bh, const f16* __restrict__ Bl, int ldb,
                 const float* __restrict__ bias, const float* __restrict__ res,
                 float* __restrict__ outf, f16* __restrict__ outh, int ldo, int K,
                 const int* __restrict__ rowmap, const TileInfo* __restrict__ table,
                 const char* __restrict__ zbuf) {
  constexpr int BK = 64;
  constexpr int RB = 128;               // bytes per LDS tile row
  constexpr int TB = 16384;             // bytes per tile plane (128 rows)
  constexpr int ROUNDS = 4;             // staging rounds per plane
  constexpr int TPR = 8;                // threads per row
  constexpr int RPR = 32;               // rows per round
  constexpr int SWM = 7;                // swizzle mask
  constexpr int LA  = 0;
  constexpr int LAL = (NPASS == 3) ? TB : 0;
  constexpr int LB  = (NPASS == 3) ? 2 * TB : TB;
  constexpr int LBL = (NPASS == 3) ? 3 * TB : 0;

  __shared__ __align__(16) char lds[65536];

  const int tid  = threadIdx.x;
  const int wave = tid >> 6;
  const int lane = tid & 63;

  int m0, mcnt, eidx = 0;
  if (MODE == 2) {
    TileInfo ti = table[blockIdx.x];
    if (ti.mcnt <= 0) return;
    m0 = ti.m0; mcnt = ti.mcnt; eidx = ti.e;
  } else { m0 = blockIdx.x * 128; mcnt = 128; }
  const int n0 = blockIdx.y * 128;

  const f16* Bh_ = Bh;
  const float* bias_ = bias;
  size_t adelta = 0, bdelta = 0;
  if (NPASS == 3) {
    adelta = (size_t)((const char*)Al - (const char*)Ah);
    bdelta = (size_t)((const char*)Bl - (const char*)Bh);
  }
  if (MODE == 2) { Bh_ += ((size_t)eidx << 20); bias_ += eidx * 1024; }

  const int sr    = tid / TPR;
  const int cbyte = (tid % TPR) * 16;

  const char* aSrc[ROUNDS];
  const char* bSrc[ROUNDS];
  int aRowC[ROUNDS]; int aCbs[ROUNDS];
  #pragma unroll
  for (int r = 0; r < ROUNDS; ++r) {
    const int mr  = sr + r * RPR;
    const int cbs = cbyte ^ ((mr & SWM) << 4);
    int gi = m0 + ((mr < mcnt) ? mr : (mcnt - 1));
    if (MODE == 1 || MODE == 2) gi = rowmap[gi];
    if (MODE == 3) { aRowC[r] = gi; aCbs[r] = cbs; aSrc[r] = nullptr; }
    else           { aSrc[r] = (const char*)Ah + (size_t)gi * lda * 2 + cbs; aRowC[r] = 0; aCbs[r] = 0; }
    const int nr   = sr + r * RPR;
    const int ncbs = cbyte ^ ((nr & SWM) << 4);
    bSrc[r] = (const char*)Bh_ + (size_t)(n0 + nr) * ldb * 2 + ncbs;
  }

  f32x4 acc[4][4] = {};
  const int wm  = (wave >> 1) * 64;
  const int wn  = (wave & 1) * 64;
  const int fr  = lane & 15;
  const int kgb = (lane >> 4) * 16;

  if constexpr (NPASS == 1) {
    // ---- double-buffered counted-vmcnt K-loop ----
    const int NT = K / BK;
    // prologue: stage tile 0 -> buf0, tile 1 -> buf1 (8 loads each/thread)
    #pragma unroll
    for (int r = 0; r < ROUNDS; ++r) {
      gload16(aSrc[r], lds + r * 4096 + wave * 1024);
      gload16(bSrc[r], lds + 16384 + r * 4096 + wave * 1024);
    }
    #pragma unroll
    for (int r = 0; r < ROUNDS; ++r) {
      gload16(aSrc[r] + (size_t)BK * 2, lds + 32768 + r * 4096 + wave * 1024);
      gload16(bSrc[r] + (size_t)BK * 2, lds + 32768 + 16384 + r * 4096 + wave * 1024);
    }
    asm volatile("s_waitcnt vmcnt(8)" ::: "memory");   // tile 0 landed
    __builtin_amdgcn_s_barrier();

    for (int kt = 0; kt < NT; ++kt) {
      const int c = kt & 1;
      const char* LAp = lds + c * 32768;
      const char* LBp = LAp + 16384;
      f16x8 ah[2][4], bh[2][4];
      #pragma unroll
      for (int kk = 0; kk < 2; ++kk) {
        #pragma unroll
        for (int i = 0; i < 4; ++i) {
          const int ar = wm + i * 16 + fr;
          ah[kk][i] = *(const f16x8*)(LAp + ar * RB + ((kk * 64 + kgb) ^ ((ar & SWM) << 4)));
          const int br = wn + i * 16 + fr;
          bh[kk][i] = *(const f16x8*)(LBp + br * RB + ((kk * 64 + kgb) ^ ((br & SWM) << 4)));
        }
      }
      asm volatile("s_waitcnt lgkmcnt(0)" ::: "memory");  // our reads of buf c done
      __builtin_amdgcn_s_barrier();                       // all waves done reading buf c
      if (kt + 2 < NT) {
        const size_t ko = (size_t)(kt + 2) * BK * 2;
        #pragma unroll
        for (int r = 0; r < ROUNDS; ++r) {
          gload16(aSrc[r] + ko, lds + c * 32768 + r * 4096 + wave * 1024);
          gload16(bSrc[r] + ko, lds + c * 32768 + 16384 + r * 4096 + wave * 1024);
        }
      }
      #pragma unroll
      for (int kk = 0; kk < 2; ++kk)
        #pragma unroll
        for (int i = 0; i < 4; ++i)
          #pragma unroll
          for (int j = 0; j < 4; ++j)
            acc[i][j] = __builtin_amdgcn_mfma_f32_16x16x32_f16(ah[kk][i], bh[kk][j], acc[i][j], 0, 0, 0);
      if (kt + 2 < NT) asm volatile("s_waitcnt vmcnt(8)" ::: "memory");  // kt+1 landed; kt+2 in flight
      else             asm volatile("s_waitcnt vmcnt(0)" ::: "memory");
      __builtin_amdgcn_s_barrier();
    }
  } else {
    // ---- single-buffered 3-pass loop (fp32-faithful) ----
    for (int k0 = 0; k0 < K; k0 += BK) {
      #pragma unroll
      for (int r = 0; r < ROUNDS; ++r) {
        const char* as;
        const char* asl = nullptr;
        if (MODE == 3) {
          const int tap = k0 >> 10;
          const int kc  = k0 & 1023;
          const int tok = aRowC[r] & 4095;
          const int st  = tok + (tap - 1) * 2;
          if (st >= 0 && st < 4096) {
            as  = (const char*)Ah + (size_t)(aRowC[r] + (tap - 1) * 2) * 2048 + kc * 2 + aCbs[r];
            asl = as + adelta;
          } else {
            as  = zbuf;
            asl = zbuf;
          }
        } else {
          as  = aSrc[r] + (size_t)k0 * 2;
          asl = as + adelta;
        }
        gload16(as, lds + LA + r * 4096 + wave * 1024);
        gload16(asl, lds + LAL + r * 4096 + wave * 1024);
        const char* bs = bSrc[r] + (size_t)k0 * 2;
        gload16(bs, lds + LB + r * 4096 + wave * 1024);
        gload16(bs + bdelta, lds + LBL + r * 4096 + wave * 1024);
      }
      __syncthreads();
      #pragma unroll
      for (int kk = 0; kk < 2; ++kk) {
        f16x8 ah[4], bh[4], al[4], bl[4];
        #pragma unroll
        for (int i = 0; i < 4; ++i) {
          const int ar = wm + i * 16 + fr;
          const int ao = ar * RB + ((kk * 64 + kgb) ^ ((ar & SWM) << 4));
          ah[i] = *(const f16x8*)(lds + LA + ao);
          al[i] = *(const f16x8*)(lds + LAL + ao);
          const int br = wn + i * 16 + fr;
          const int bo = br * RB + ((kk * 64 + kgb) ^ ((br & SWM) << 4));
          bh[i] = *(const f16x8*)(lds + LB + bo);
          bl[i] = *(const f16x8*)(lds + LBL + bo);
        }
        #pragma unroll
        for (int i = 0; i < 4; ++i) {
          #pragma unroll
          for (int j = 0; j < 4; ++j) {
            acc[i][j] = __builtin_amdgcn_mfma_f32_16x16x32_f16(ah[i], bh[j], acc[i][j], 0, 0, 0);
            acc[i][j] = __builtin_amdgcn_mfma_f32_16x16x32_f16(ah[i], bl[j], acc[i][j], 0, 0, 0);
            acc[i][j] = __builtin_amdgcn_mfma_f32_16x16x32_f16(al[i], bh[j], acc[i][j], 0, 0, 0);
          }
        }
      }
      __syncthreads();
    }
  }

  #pragma unroll
  for (int i = 0; i < 4; ++i) {
    const int mb = wm + i * 16 + (lane >> 4) * 4;
    #pragma unroll
    for (int j = 0; j < 4; ++j) {
      const int nc = n0 + wn + j * 16 + fr;
      const float bv = bias_[nc];
      #pragma unroll
      for (int q = 0; q < 4; ++q) {
        const int ml = mb + q;
        if (MODE == 2 && ml >= mcnt) continue;
        const size_t orow = (size_t)(m0 + ml);
        float v = acc[i][j][q] + bv;
        if (EPI == 1) v += res[orow * ldo + nc];
        if (EPI == 3) v = fast_gelu(v);
        if (EPI <= 1) outf[orow * ldo + nc] = v;
        else          outh[orow * ldo + nc] = (f16)v;
      }
    }
  }
}

// ---------------------------------------------------------------------------
// LayerNorm: fp32 in -> f16 hi (+optional lo plane). WGATE: fused gate logits.
// ---------------------------------------------------------------------------
template<int WLO, int WGATE>
__global__ __launch_bounds__(256)
void ln_kernel(const float* __restrict__ x, const float* __restrict__ g, const float* __restrict__ b,
               f16* __restrict__ oh, f16* __restrict__ ol,
               const float* __restrict__ gW, const float* __restrict__ gb,
               float* __restrict__ logits) {
  const int row = blockIdx.x;
  const int t = threadIdx.x;
  const float4 v = ((const float4*)(x + (size_t)row * 1024))[t];
  float s  = v.x + v.y + v.z + v.w;
  float ss = v.x * v.x + v.y * v.y + v.z * v.z + v.w * v.w;
  #pragma unroll
  for (int off = 32; off; off >>= 1) { s += __shfl_down(s, off, 64); ss += __shfl_down(ss, off, 64); }
  __shared__ float red[8];
  if ((t & 63) == 0) { red[t >> 6] = s; red[(t >> 6) + 4] = ss; }
  __syncthreads();
  s  = red[0] + red[1] + red[2] + red[3];
  ss = red[4] + red[5] + red[6] + red[7];
  const float mu  = s * (1.0f / 1024.0f);
  const float var = ss * (1.0f / 1024.0f) - mu * mu;
  const float inv = 1.0f / sqrtf(var + 1e-5f);
  const float4 gv = ((const float4*)g)[t];
  const float4 bv = ((const float4*)b)[t];
  float y[4];
  y[0] = (v.x - mu) * inv * gv.x + bv.x;
  y[1] = (v.y - mu) * inv * gv.y + bv.y;
  y[2] = (v.z - mu) * inv * gv.z + bv.z;
  y[3] = (v.w - mu) * inv * gv.w + bv.w;
  f16x4 hv;
  #pragma unroll
  for (int u = 0; u < 4; ++u) hv[u] = (f16)y[u];
  *(f16x4*)(oh + (size_t)row * 1024 + t * 4) = hv;
  if (WLO) {
    f16x4 lv;
    #pragma unroll
    for (int u = 0; u < 4; ++u) lv[u] = (f16)(y[u] - (float)hv[u]);
    *(f16x4*)(ol + (size_t)row * 1024 + t * 4) = lv;
  }
  if (WGATE) {
    const float* gr = gW + (size_t)(t * 4) * 8;
    float lg[8];
    #pragma unroll
    for (int e = 0; e < 8; ++e)
      lg[e] = y[0] * gr[e] + y[1] * gr[8 + e] + y[2] * gr[16 + e] + y[3] * gr[24 + e];
    #pragma unroll
    for (int m = 1; m < 64; m <<= 1)
      #pragma unroll
      for (int e = 0; e < 8; ++e) lg[e] += __shfl_xor(lg[e], m, 64);
    __shared__ float gred[4][8];
    if ((t & 63) == 0) {
      #pragma unroll
      for (int e = 0; e < 8; ++e) gred[t >> 6][e] = lg[e];
    }
    __syncthreads();
    if (t < 8)
      logits[(size_t)row * 8 + t] = gred[0][t] + gred[1][t] + gred[2][t] + gred[3][t] + gb[t];
  }
}

// ---------------------------------------------------------------------------
// Windowed attention (512 thr/block): see R6.
// ---------------------------------------------------------------------------
__global__ __launch_bounds__(512, 4)
void attn_kernel(const float* __restrict__ qkv, f16* __restrict__ oh, f16* __restrict__ ol) {
  __shared__ __align__(16) char sm[81920];
  const int bid = blockIdx.x;
  const int b = bid >> 8, h = (bid >> 4) & 15, n = bid & 15;
  const int t = threadIdx.x;
  const size_t rowbase = (size_t)(b * 2176 + n * 128);
  const char* qg = (const char*)(qkv + rowbase * 3072 + h * 64);
  const char* kg = qg + 4096;
  const char* vg = qg + 8192;

  const int srow = t >> 4;
  const int scol = (t & 15) * 16;
  const int wuni = (t >> 6) * 1024;

  const int dt = t >> 4;
  const int et = t & 15;
  float pacc[2][4] = {};

  for (int r = 0; r < 2; ++r) {
    #pragma unroll
    for (int p = 0; p < 4; ++p) {
      const size_t off = (size_t)(r * 128 + p * 32 + srow) * 12288 + scol;
      gload16(qg + off, sm + p * 8192 + wuni);
      gload16(kg + off, sm + 32768 + p * 8192 + wuni);
    }
    __syncthreads();
    #pragma unroll 4
    for (int s = 0; s < 128; ++s) {
      const float2 q2 = *(const float2*)(sm + s * 256 + dt * 8);
      const f32x4 k4 = *(const f32x4*)(sm + 32768 + s * 256 + et * 16);
      #pragma unroll
      for (int z = 0; z < 4; ++z) {
        pacc[0][z] += q2.x * k4[z];
        pacc[1][z] += q2.y * k4[z];
      }
    }
    __syncthreads();
  }

  #pragma unroll
  for (int i = 0; i < 2; ++i) {
    #pragma unroll
    for (int z = 0; z < 4; ++z) pacc[i][z] *= 0.125f;
    float m = fmaxf(fmaxf(pacc[i][0], pacc[i][1]), fmaxf(pacc[i][2], pacc[i][3]));
    m = fmaxf(m, __shfl_xor(m, 1, 16));
    m = fmaxf(m, __shfl_xor(m, 2, 16));
    m = fmaxf(m, __shfl_xor(m, 4, 16));
    m = fmaxf(m, __shfl_xor(m, 8, 16));
    float den = 0.0f;
    #pragma unroll
    for (int z = 0; z < 4; ++z) { pacc[i][z] = __expf(pacc[i][z] - m); den += pacc[i][z]; }
    den += __shfl_xor(den, 1, 16);
    den += __shfl_xor(den, 2, 16);
    den += __shfl_xor(den, 4, 16);
    den += __shfl_xor(den, 8, 16);
    const float dinv = 1.0f / den;
    f32x4 pv;
    #pragma unroll
    for (int z = 0; z < 4; ++z) pv[z] = pacc[i][z] * dinv;
    *(f32x4*)(sm + 65536 + (dt * 2 + i) * 256 + et * 16) = pv;
  }

  const int dt2 = t & 15;
  const int st  = t >> 4;
  const int ch  = h * 64 + (st & 15) * 4;
  const size_t rb2 = (size_t)(b * 4096 + n * 256);

  for (int c = 0; c < 2; ++c) {
    __syncthreads();
    #pragma unroll
    for (int p = 0; p < 4; ++p) {
      const size_t off = (size_t)(c * 128 + p * 32 + srow) * 12288 + scol;
      gload16(vg + off, sm + p * 8192 + wuni);
    }
    __syncthreads();
    float o[16];
    #pragma unroll
    for (int u = 0; u < 16; ++u) o[u] = 0.0f;
    #pragma unroll 2
    for (int e4 = 0; e4 < 16; ++e4) {
      f32x4 p4[4], v4[4];
      #pragma unroll
      for (int i = 0; i < 4; ++i)
        p4[i] = *(const f32x4*)(sm + 65536 + (dt2 * 4 + i) * 256 + e4 * 16);
      #pragma unroll
      for (int j = 0; j < 4; ++j)
        v4[j] = *(const f32x4*)(sm + (st * 4 + j) * 256 + e4 * 16);
      #pragma unroll
      for (int j = 0; j < 4; ++j)
        #pragma unroll
        for (int i = 0; i < 4; ++i) {
          o[j * 4 + i] += v4[j][0] * p4[i][0] + v4[j][1] * p4[i][1]
                        + v4[j][2] * p4[i][2] + v4[j][3] * p4[i][3];
        }
    }
    const int rq = c * 2 + (st >> 4);
    #pragma unroll
    for (int i = 0; i < 4; ++i) {
      const size_t row = rb2 + (size_t)(dt2 * 4 + i) * 4 + rq;
      f16x4 hv, lv;
      #pragma unroll
      for (int j = 0; j < 4; ++j) {
        const float val = o[j * 4 + i];
        hv[j] = (f16)val;
        lv[j] = (f16)(val - (float)hv[j]);
      }
      *(f16x4*)(oh + row * 1024 + ch) = hv;
      *(f16x4*)(ol + row * 1024 + ch) = lv;
    }
  }
}

// ---------------------------------------------------------------------------
// weight transposes fp32 -> f16 (optional lo plane); batched over blockIdx.z
// ---------------------------------------------------------------------------
template<int SPLIT>
__global__ __launch_bounds__(256)
void transpose_kernel(const float* __restrict__ in, int R, int Cc,
                      f16* __restrict__ oh, f16* __restrict__ ol) {
  __shared__ float tile[32][33];
  const size_t mat = (size_t)blockIdx.z * R * Cc;
  in += mat; oh += mat; if (SPLIT) ol += mat;
  const int tx = threadIdx.x & 31, ty = threadIdx.x >> 5;
  const int c = blockIdx.x * 32 + tx;
  #pragma unroll
  for (int j = 0; j < 32; j += 8) {
    const int r = blockIdx.y * 32 + ty + j;
    tile[ty + j][tx] = in[(size_t)r * Cc + c];
  }
  __syncthreads();
  const int rT = blockIdx.y * 32 + tx;
  #pragma unroll
  for (int j = 0; j < 32; j += 8) {
    const int cT = blockIdx.x * 32 + ty + j;
    const float v = tile[tx][ty + j];
    const f16 hv = (f16)v;
    oh[(size_t)cT * R + rT] = hv;
    if (SPLIT) ol[(size_t)cT * R + rT] = (f16)(v - (float)hv);
  }
}

// conv weights [O,I,3] -> BT[o][tap*1024+i] hi/lo
__global__ __launch_bounds__(256)
void convw_kernel(const float* __restrict__ w, f16* __restrict__ oh, f16* __restrict__ ol) {
  const int id = blockIdx.x * 256 + threadIdx.x;
  const int o = id >> 10, i = id & 1023;
  const float* ws = w + (size_t)o * 3072 + i * 3;
  #pragma unroll
  for (int tap = 0; tap < 3; ++tap) {
    const float v = ws[tap];
    const f16 hv = (f16)v;
    const size_t oi = (size_t)o * 3072 + tap * 1024 + i;
    oh[oi] = hv;
    ol[oi] = (f16)(v - (float)hv);
  }
}

__global__ void qkvrows_kernel(int* __restrict__ rows) {
  const int r = blockIdx.x * 256 + threadIdx.x;
  if (r < 4352) rows[r] = (r >= 2176) ? (4096 + r - 2176) : r;
}

// ---------------------------------------------------------------------------
// gate finalize
// ---------------------------------------------------------------------------
__global__ __launch_bounds__(256)
void gatefin_kernel(const float* __restrict__ logits, float* __restrict__ top2p,
                    int* __restrict__ top2i, float* __restrict__ ent,
                    int* __restrict__ counts) {
  __shared__ int hist[8];
  const int t = threadIdx.x;
  if (t < 8) hist[t] = 0;
  __syncthreads();
  const int token = blockIdx.x * 256 + t;
  float lg[8];
  const float4 l0 = ((const float4*)(logits + (size_t)token * 8))[0];
  const float4 l1 = ((const float4*)(logits + (size_t)token * 8))[1];
  lg[0] = l0.x; lg[1] = l0.y; lg[2] = l0.z; lg[3] = l0.w;
  lg[4] = l1.x; lg[5] = l1.y; lg[6] = l1.z; lg[7] = l1.w;
  int i0 = 0; float v0 = lg[0];
  #pragma unroll
  for (int e = 1; e < 8; ++e) if (lg[e] > v0) { v0 = lg[e]; i0 = e; }
  int i1 = 0; float v1 = -1e30f;
  #pragma unroll
  for (int e = 0; e < 8; ++e) if (e != i0 && lg[e] > v1) { v1 = lg[e]; i1 = e; }
  float den = 0.0f; float pr[8];
  #pragma unroll
  for (int e = 0; e < 8; ++e) { pr[e] = __expf(lg[e] - v0); den += pr[e]; }
  const float dinv = 1.0f / den;
  float H = 0.0f, p0 = 0.0f, p1 = 0.0f;
  #pragma unroll
  for (int e = 0; e < 8; ++e) {
    const float p = pr[e] * dinv;
    H -= p * __logf(p + 1e-10f);
    if (e == i0) p0 = p;
    if (e == i1) p1 = p;
  }
  ent[token] = H;
  top2p[token * 2] = p0; top2p[token * 2 + 1] = p1;
  top2i[token * 2] = i0; top2i[token * 2 + 1] = i1;
  atomicAdd(&hist[i0], 1);
  atomicAdd(&hist[i1], 1);
  __syncthreads();
  if (t < 8) atomicAdd(&counts[t], hist[t]);
}

// scan: entropy mean (fixed order), offsets, aux, tile table
__global__ __launch_bounds__(256)
void scan_kernel(const float* __restrict__ ent, const int* __restrict__ counts,
                 int* __restrict__ offs, TileInfo* __restrict__ table, float* __restrict__ auxout) {
  __shared__ float red[256];
  const int t = threadIdx.x;
  float s = 0.0f;
  for (int k = 0; k < 32; ++k) s += ent[t + (k << 8)];
  red[t] = s; __syncthreads();
  for (int hh = 128; hh > 0; hh >>= 1) { if (t < hh) red[t] += red[t + hh]; __syncthreads(); }
  if (t == 0) {
    const float entmean = red[0] * (1.0f / 8192.0f);
    float pen = 0.0f; int off = 0; int nt = 0;
    for (int e = 0; e < 8; ++e) {
      const int c = counts[e];
      offs[e] = off;
      for (int m = 0; m < c; m += 128) {
        table[nt].m0 = off + m;
        table[nt].mcnt = (c - m < 128) ? (c - m) : 128;
        table[nt].e = e; table[nt].pad = 0;
        ++nt;
      }
      off += c;
      const float fr = (float)c * (1.0f / 8192.0f) - 0.3f;
      pen += (fr > 0.0f) ? fr : 0.0f;
    }
    for (; nt < 160; ++nt) { table[nt].m0 = 0; table[nt].mcnt = 0; table[nt].e = 0; table[nt].pad = 0; }
    auxout[0] = 0.1f * entmean + pen;
  }
}

// scatter: block-local LDS ranks + one chunk-reservation atomic per expert
__global__ __launch_bounds__(256)
void scatter_kernel(const int* __restrict__ top2i, const int* __restrict__ offs,
                    int* __restrict__ fill, int* __restrict__ moe_rows,
                    int* __restrict__ row2slot) {
  __shared__ int hist[8];
  __shared__ int base[8];
  const int t = threadIdx.x;
  if (t < 8) hist[t] = 0;
  __syncthreads();
  const int id = blockIdx.x * 256 + t;
  const int e = top2i[id];
  const int myrank = atomicAdd(&hist[e], 1);
  __syncthreads();
  if (t < 8) base[t] = atomicAdd(&fill[t], hist[t]);
  __syncthreads();
  const int row = offs[e] + base[e] + myrank;
  moe_rows[row] = id >> 1;
  row2slot[id] = row;
}

// x3 = x2 + p0*eo[r0] + p1*eo[r1]; also f16 copy for FF1
__global__ __launch_bounds__(256)
void combine_kernel(const float* __restrict__ x2, const f16* __restrict__ eo,
                    const float* __restrict__ top2p, const int* __restrict__ row2slot,
                    float* __restrict__ x3, f16* __restrict__ x3h) {
  const int n = blockIdx.x;
  const int t = threadIdx.x;
  const int r0 = row2slot[n * 2], r1 = row2slot[n * 2 + 1];
  const float p0 = top2p[n * 2], p1 = top2p[n * 2 + 1];
  const float4 xv = ((const float4*)(x2 + (size_t)n * 1024))[t];
  const f16x4 e0 = ((const f16x4*)(eo + (size_t)r0 * 1024))[t];
  const f16x4 e1 = ((const f16x4*)(eo + (size_t)r1 * 1024))[t];
  float4 o;
  o.x = xv.x + p0 * (float)e0[0] + p1 * (float)e1[0];
  o.y = xv.y + p0 * (float)e0[1] + p1 * (float)e1[1];
  o.z = xv.z + p0 * (float)e0[2] + p1 * (float)e1[2];
  o.w = xv.w + p0 * (float)e0[3] + p1 * (float)e1[3];
  ((float4*)(x3 + (size_t)n * 1024))[t] = o;
  f16x4 hv; hv[0] = (f16)o.x; hv[1] = (f16)o.y; hv[2] = (f16)o.z; hv[3] = (f16)o.w;
  ((f16x4*)(x3h + (size_t)n * 1024))[t] = hv;
}

// ---------------------------------------------------------------------------
extern "C" void kernel_launch(void* const* d_in, const int* in_sizes, int n_in,
                              void* d_out, int out_size, void* d_ws, size_t ws_size,
                              hipStream_t stream) {
  (void)in_sizes; (void)n_in; (void)out_size; (void)ws_size;
  const float* x     = (const float*)d_in[0];
  const float* g1    = (const float*)d_in[1];
  const float* b1    = (const float*)d_in[2];
  const float* g2    = (const float*)d_in[3];
  const float* b2    = (const float*)d_in[4];
  const float* g3    = (const float*)d_in[5];
  const float* b3    = (const float*)d_in[6];
  const float* Wqkv  = (const float*)d_in[7];
  const float* bqkv  = (const float*)d_in[8];
  const float* Wo    = (const float*)d_in[9];
  const float* bo    = (const float*)d_in[10];
  const float* convw = (const float*)d_in[11];
  const float* convb = (const float*)d_in[12];
  const float* gateW = (const float*)d_in[13];
  const float* gateb = (const float*)d_in[14];
  const float* expW  = (const float*)d_in[15];
  const float* expb  = (const float*)d_in[16];
  const float* ffW1  = (const float*)d_in[17];
  const float* ffb1  = (const float*)d_in[18];
  const float* ffW2  = (const float*)d_in[19];
  const float* ffb2  = (const float*)d_in[20];
  float* out = (float*)d_out;

  char* W = (char*)d_ws;
  f16* wqkvT_h = (f16*)(W + 0);
  f16* wqkvT_l = (f16*)(W + 6291456);
  f16* woT_h   = (f16*)(W + 12582912);
  f16* woT_l   = (f16*)(W + 14680064);
  f16* wcvT_h  = (f16*)(W + 16777216);
  f16* wcvT_l  = (f16*)(W + 23068672);
  f16* wexpT   = (f16*)(W + 29360128);
  f16* wff1T   = (f16*)(W + 46137344);
  f16* wff2T   = (f16*)(W + 54525952);
  char* META   = W + 62914560;
  int* counts    = (int*)(META);
  int* fill      = (int*)(META + 32);
  int* offs      = (int*)(META + 64);
  TileInfo* table = (TileInfo*)(META + 128);
  char* zbuf     = META + 3072;
  int* qkv_rows  = (int*)(META + 4096);
  float* ent     = (float*)(META + 24576);
  float* top2p   = (float*)(META + 57344);
  int* top2i     = (int*)(META + 122880);
  int* moe_rows  = (int*)(META + 188416);
  int* row2slot  = (int*)(META + 253952);
  float* logits  = (float*)(META + 327680);
  char* SA = W + 63963136;
  char* SB = W + 97517568;
  char* SC = W + 164626432;
  char* SD = W + 198180864;
  char* SE = W + 231735296;

  f16* ln1h = (f16*)SA;            f16* ln1l = (f16*)(SA + 16777216);
  f16* ln2h = ln1h;                f16* ln2l = ln1l;
  f16* ln3h = ln1h;                f16* x3h  = (f16*)(SA + 16777216);
  float* qkvbuf = (float*)SB;
  float* x2buf  = (float*)SB;
  f16*   hbuf   = (f16*)SB;
  f16* attnh = (f16*)SC;           f16* attnl = (f16*)(SC + 16777216);
  float* x1 = (float*)SD;
  f16* eobuf = (f16*)SD;
  float* x3 = (float*)SE;

  hipMemsetAsync((void*)META, 0, 4096, stream);

  dim3 blk(256);
  // weight prep
  transpose_kernel<1><<<dim3(96, 32, 1), blk, 0, stream>>>(Wqkv, 1024, 3072, wqkvT_h, wqkvT_l);
  transpose_kernel<1><<<dim3(32, 32, 1), blk, 0, stream>>>(Wo, 1024, 1024, woT_h, woT_l);
  convw_kernel<<<4096, blk, 0, stream>>>(convw, wcvT_h, wcvT_l);
  transpose_kernel<0><<<dim3(32, 32, 8), blk, 0, stream>>>(expW, 1024, 1024, wexpT, nullptr);
  transpose_kernel<0><<<dim3(128, 32, 1), blk, 0, stream>>>(ffW1, 1024, 4096, wff1T, nullptr);
  transpose_kernel<0><<<dim3(32, 128, 1), blk, 0, stream>>>(ffW2, 4096, 1024, wff2T, nullptr);
  qkvrows_kernel<<<17, blk, 0, stream>>>(qkv_rows);

  // LN1 -> split planes
  ln_kernel<1, 0><<<8192, blk, 0, stream>>>(x, g1, b1, ln1h, ln1l, nullptr, nullptr, nullptr);
  // QKV (rows 0..2175 per batch), split GEMM, fp32 out
  gemm_kernel<3, 1, 0><<<dim3(34, 24), blk, 0, stream>>>(ln1h, ln1l, 1024, wqkvT_h, wqkvT_l, 1024,
      bqkv, nullptr, qkvbuf, nullptr, 3072, 1024, qkv_rows, nullptr, nullptr);
  // attention (512 threads)
  attn_kernel<<<512, dim3(512), 0, stream>>>(qkvbuf, attnh, attnl);
  // Wo projection + residual -> x1
  gemm_kernel<3, 0, 1><<<dim3(64, 8), blk, 0, stream>>>(attnh, attnl, 1024, woT_h, woT_l, 1024,
      bo, x, x1, nullptr, 1024, 1024, nullptr, nullptr, nullptr);
  // LN2
  ln_kernel<1, 0><<<8192, blk, 0, stream>>>(x1, g2, b2, ln2h, ln2l, nullptr, nullptr, nullptr);
  // conv (3-tap shifted GEMM, exact zero-pad) + residual -> x2
  gemm_kernel<3, 3, 1><<<dim3(64, 8), blk, 0, stream>>>(ln2h, ln2l, 1024, wcvT_h, wcvT_l, 3072,
      convb, x1, x2buf, nullptr, 1024, 3072, nullptr, nullptr, zbuf);
  // LN3 fused with gate logits
  ln_kernel<0, 1><<<8192, blk, 0, stream>>>(x2buf, g3, b3, ln3h, nullptr, gateW, gateb, logits);
  // gate finalize / scan / scatter
  gatefin_kernel<<<32, blk, 0, stream>>>(logits, top2p, top2i, ent, counts);
  scan_kernel<<<1, blk, 0, stream>>>(ent, counts, offs, table, out + 8388608);
  scatter_kernel<<<64, blk, 0, stream>>>(top2i, offs, fill, moe_rows, row2slot);
  // grouped expert GEMM -> eo (f16)
  gemm_kernel<1, 2, 2><<<dim3(136, 8), blk, 0, stream>>>(ln3h, nullptr, 1024, wexpT, nullptr, 1024,
      expb, nullptr, nullptr, eobuf, 1024, 1024, moe_rows, table, nullptr);
  // combine -> x3 (+f16)
  combine_kernel<<<8192, blk, 0, stream>>>(x2buf, eobuf, top2p, row2slot, x3, x3h);
  // FF1 (gelu) -> h
  gemm_kernel<1, 0, 3><<<dim3(64, 32), blk, 0, stream>>>(x3h, nullptr, 1024, wff1T, nullptr, 1024,
      ffb1, nullptr, nullptr, hbuf, 4096, 1024, nullptr, nullptr, nullptr);
  // FF2 + residual -> final output
  gemm_kernel<1, 0, 1><<<dim3(64, 8), blk, 0, stream>>>(hbuf, nullptr, 4096, wff2T, nullptr, 4096,
      ffb2, x3, out, nullptr, 1024, 4096, nullptr, nullptr, nullptr);
}